// Round 19
// baseline (1751.347 us; speedup 1.0000x reference)
//
#include <hip/hip_runtime.h>
#include <stdint.h>
#include <type_traits>

#define DEVFN static __device__ __forceinline__

typedef __attribute__((ext_vector_type(8))) short bf16x8v;
typedef __attribute__((ext_vector_type(4))) float f32x4v;
typedef __attribute__((ext_vector_type(2))) _Float16 h2;

DEVFN float b2f(short s) {
  union { unsigned u; float f; } c; c.u = ((unsigned)(unsigned short)s) << 16; return c.f;
}
DEVFN short f2b(float f) {
  union { float f; unsigned u; } c; c.f = f;
  unsigned r = c.u + 0x7fffu + ((c.u >> 16) & 1u);
  return (short)(r >> 16);
}
DEVFN short f2h(float f) {
  union { _Float16 h; short s; } c; c.h = (_Float16)f; return c.s;
}
DEVFN void gl_lds16(const void* g, void* l) {
  __builtin_amdgcn_global_load_lds((const __attribute__((address_space(1))) void*)g,
                                   (__attribute__((address_space(3))) void*)l, 16, 0, 0);
}
// exp(x) for |x| < ~0.02 (sim scores): 5-term Taylor in f64.
DEVFN double exp_small(double x) {
  return 1.0 + x * (1.0 + x * (0.5 + x * ((1.0 / 6.0) + x * (1.0 / 24.0))));
}

// ---------------- one-shot prep kernel ----------------

__global__ void prep_all(const float* __restrict__ conv_w, const float* __restrict__ proj_w,
                         const float* __restrict__ merge_w, const float* __restrict__ reg1_w,
                         const float* __restrict__ reg2_w, const float* __restrict__ wq,
                         const float* __restrict__ wk, const float* __restrict__ wv,
                         const float* __restrict__ wm, const float* __restrict__ m1w,
                         const float* __restrict__ m2w,
                         short* __restrict__ convT, short* __restrict__ projT,
                         short* __restrict__ mergeAT, short* __restrict__ mergeBT,
                         short* __restrict__ reg1T, short* __restrict__ reg2T,
                         short* __restrict__ wqkvT, short* __restrict__ wmT,
                         short* __restrict__ m1T, short* __restrict__ m2T,
                         float* __restrict__ pe, short* __restrict__ zp) {
  const int L0 = 32768, L1 = 32768, L2 = 16384, L3 = 16384, L4 = 32768, L5 = 409600;
  const int L6 = 196608, L7 = 65536, L8 = 262144, L9 = 131072, L10 = 3200, L11 = 128;
  const int TOT = L0+L1+L2+L3+L4+L5+L6+L7+L8+L9+L10+L11;
  for (int gi = blockIdx.x * blockDim.x + threadIdx.x; gi < TOT; gi += gridDim.x * blockDim.x) {
    int i = gi;
    if (i < L0) { convT[i] = f2b(conv_w[i]); continue; } i -= L0;
    if (i < L1) { int n = i >> 8, k = i & 255; projT[i] = f2b(proj_w[k * 128 + n]); continue; } i -= L1;
    if (i < L2) { int n = i >> 7, k = i & 127; mergeAT[i] = f2b(merge_w[k * 128 + n]); continue; } i -= L2;
    if (i < L3) { int n = i >> 7, k = i & 127; mergeBT[i] = f2b(merge_w[(128 + k) * 128 + n]); continue; } i -= L3;
    if (i < L4) { int n = i >> 8, k = i & 255; reg1T[i] = f2b(reg1_w[k * 128 + n]); continue; } i -= L4;
    if (i < L5) { int n = i / 3200, k = i - n * 3200; reg2T[i] = f2b(reg2_w[k * 128 + n]); continue; } i -= L5;
    if (i < L6) {
      int l = i / 49152; int r = i - l * 49152; int w = r / 16384; int r2 = r - w * 16384;
      int n = r2 >> 7, k = r2 & 127;
      const float* s = (w == 0) ? wq : (w == 1) ? wk : wv;
      wqkvT[i] = f2b(s[l * 16384 + k * 128 + n]); continue;
    } i -= L6;
    if (i < L7) { int l = i >> 14; int r = i & 16383; int n = r >> 7, k = r & 127;
      wmT[i] = f2b(wm[l * 16384 + k * 128 + n]); continue; } i -= L7;
    if (i < L8) { int l = i >> 16; int r = i & 65535; int n = r >> 8, k = r & 255;
      m1T[i] = f2b(m1w[l * 65536 + k * 256 + n]); continue; } i -= L8;
    if (i < L9) { int l = i >> 15; int r = i & 32767; int n = r >> 8, k = r & 255;
      m2T[i] = f2b(m2w[l * 32768 + k * 128 + n]); continue; } i -= L9;
    if (i < L10) {
      int t = i >> 7, d = i & 127; int i2 = d >> 1;
      float div = expf(((float)(2 * i2)) * (-logf(10000.f) / 128.f));
      float ang = (float)t * div;
      pe[i] = (d & 1) ? cosf(ang) : sinf(ang); continue;
    } i -= L10;
    zp[i] = 0;
  }
}

// ---------------- matching (f32/f64, precision-critical) ----------------

__global__ __launch_bounds__(256) void sim_gemm(const float* __restrict__ A,
                                                const float* __restrict__ Bm,
                                                float* __restrict__ S) {
  int b = blockIdx.z;
  A += (size_t)b * 2304 * 256; Bm += (size_t)b * 2304 * 256; S += (size_t)b * 2304 * 2304;
  __shared__ float As[96][33], Bs[96][33];
  int tid = threadIdx.x;
  int tx = tid & 15, ty = tid >> 4;
  int rb = blockIdx.x * 96, cb = blockIdx.y * 96;
  float acc[6][6] = {};
  for (int k0 = 0; k0 < 256; k0 += 32) {
    #pragma unroll
    for (int s = 0; s < 3; ++s) {
      int slot = s * 256 + tid;
      int r = slot >> 3, cq = slot & 7;
      float4 va = *(const float4*)&A[(size_t)(rb + r) * 256 + k0 + 4 * cq];
      float4 vb = *(const float4*)&Bm[(size_t)(cb + r) * 256 + k0 + 4 * cq];
      As[r][4 * cq] = va.x; As[r][4 * cq + 1] = va.y; As[r][4 * cq + 2] = va.z; As[r][4 * cq + 3] = va.w;
      Bs[r][4 * cq] = vb.x; Bs[r][4 * cq + 1] = vb.y; Bs[r][4 * cq + 2] = vb.z; Bs[r][4 * cq + 3] = vb.w;
    }
    __syncthreads();
    #pragma unroll 4
    for (int k = 0; k < 32; ++k) {
      float av[6], bv[6];
      #pragma unroll
      for (int i = 0; i < 6; ++i) av[i] = As[ty + 16 * i][k];
      #pragma unroll
      for (int j = 0; j < 6; ++j) bv[j] = Bs[tx + 16 * j][k];
      #pragma unroll
      for (int i = 0; i < 6; ++i)
        #pragma unroll
        for (int j = 0; j < 6; ++j) acc[i][j] += av[i] * bv[j];
    }
    __syncthreads();
  }
  #pragma unroll
  for (int i = 0; i < 6; ++i)
    #pragma unroll
    for (int j = 0; j < 6; ++j) {
      float t = acc[i][j] * (1.0f / 65536.0f);
      S[(size_t)(rb + ty + 16 * i) * 2304 + cb + tx + 16 * j] = t / 0.1f;
    }
}

__global__ __launch_bounds__(256) void row_lse(const float* __restrict__ S, double* __restrict__ lnR) {
  int row = blockIdx.x;
  const float* Sp = S + (size_t)row * 2304;
  double a = 0;
  for (int m = threadIdx.x; m < 2304; m += 256) a += exp_small((double)Sp[m]);
  __shared__ double red[256];
  red[threadIdx.x] = a; __syncthreads();
  for (int s = 128; s > 0; s >>= 1) { if (threadIdx.x < (unsigned)s) red[threadIdx.x] += red[threadIdx.x + s]; __syncthreads(); }
  if (!threadIdx.x) lnR[row] = log(red[0]);
}

__global__ __launch_bounds__(256) void col_part(const float* __restrict__ S,
                                                const double* __restrict__ lnR,
                                                double* __restrict__ psum,
                                                double* __restrict__ pkey,
                                                int* __restrict__ pidx) {
  int bb = blockIdx.z;
  int c0 = blockIdx.x * 64;
  int rc = blockIdx.y;
  int col = c0 + (threadIdx.x & 63);
  int g = threadIdx.x >> 6;
  const float* Sp = S + (size_t)bb * 2304 * 2304;
  const double* lr = lnR + bb * 2304;
  double a = 0, best = -1e300; int bi = 1 << 30;
  int l0 = rc * 192;
  for (int t = g; t < 192; t += 4) {
    int l = l0 + t;
    double sv = (double)Sp[(size_t)l * 2304 + col];
    a += exp_small(sv);
    double k = 2.0 * sv - lr[l];
    if (k > best || (k == best && l < bi)) { best = k; bi = l; }
  }
  __shared__ double s_sum[256]; __shared__ double s_key[256]; __shared__ int s_idx[256];
  s_sum[threadIdx.x] = a; s_key[threadIdx.x] = best; s_idx[threadIdx.x] = bi;
  __syncthreads();
  if (g == 0) {
    double ts = a; double tk = best; int ti = bi;
    #pragma unroll
    for (int gg = 1; gg < 4; ++gg) {
      int o = threadIdx.x + gg * 64;
      ts += s_sum[o];
      if (s_key[o] > tk || (s_key[o] == tk && s_idx[o] < ti)) { tk = s_key[o]; ti = s_idx[o]; }
    }
    size_t off = ((size_t)bb * 12 + rc) * 2304 + col;
    psum[off] = ts; pkey[off] = tk; pidx[off] = ti;
  }
}

__global__ void col_reduce(const double* __restrict__ psum, const double* __restrict__ pkey,
                           const int* __restrict__ pidx, double* __restrict__ lnC,
                           int* __restrict__ CB) {
  int i = blockIdx.x * blockDim.x + threadIdx.x;
  if (i >= 4608) return;
  int bb = i / 2304, col = i - bb * 2304;
  double s = 0; double bk = -1e300; int bi = 1 << 30;
  for (int rc = 0; rc < 12; ++rc) {
    size_t off = ((size_t)bb * 12 + rc) * 2304 + col;
    s += psum[off];
    double k = pkey[off]; int ix = pidx[off];
    if (k > bk || (k == bk && ix < bi)) { bk = k; bi = ix; }
  }
  lnC[i] = log(s);
  CB[i] = bi;
}

__global__ __launch_bounds__(256) void row_argmax(const float* __restrict__ S,
                                                  const double* __restrict__ lnC,
                                                  int* __restrict__ J) {
  int row = blockIdx.x; int bb = row / 2304;
  const float* Sp = S + (size_t)row * 2304;
  const double* lc = lnC + bb * 2304;
  double best = -1e300; int bi = 1 << 30;
  for (int m = threadIdx.x; m < 2304; m += 256) {
    double k = 2.0 * (double)Sp[m] - lc[m];
    if (k > best || (k == best && m < bi)) { best = k; bi = m; }
  }
  __shared__ double bvs[256]; __shared__ int bis[256];
  bvs[threadIdx.x] = best; bis[threadIdx.x] = bi; __syncthreads();
  for (int s = 128; s > 0; s >>= 1) {
    if (threadIdx.x < (unsigned)s) {
      double ov = bvs[threadIdx.x + s]; int oi = bis[threadIdx.x + s];
      if (ov > bvs[threadIdx.x] || (ov == bvs[threadIdx.x] && oi < bis[threadIdx.x])) { bvs[threadIdx.x] = ov; bis[threadIdx.x] = oi; }
    }
    __syncthreads();
  }
  if (!threadIdx.x) J[row] = bis[0];
}

// ---------------- fine-feature path ----------------

__global__ __launch_bounds__(256) void transpose_fine(const float* __restrict__ src, short* __restrict__ dst) {
  __shared__ float t[64][65];
  int bb = blockIdx.z, p0 = blockIdx.x * 64, c0 = blockIdx.y * 64;
  for (int i = threadIdx.x; i < 1024; i += 256) {
    int cl = i >> 4, pl = (i & 15) * 4;
    float4 v = *(const float4*)&src[((size_t)(bb * 256 + c0 + cl)) * 36864 + p0 + pl];
    t[cl][pl] = v.x; t[cl][pl + 1] = v.y; t[cl][pl + 2] = v.z; t[cl][pl + 3] = v.w;
  }
  __syncthreads();
  for (int i = threadIdx.x; i < 1024; i += 256) {
    int pl = i >> 4, cg = (i & 15) * 4;
    unsigned w0 = (unsigned short)f2b(t[cg][pl]) | ((unsigned)(unsigned short)f2b(t[cg + 1][pl]) << 16);
    unsigned w1 = (unsigned short)f2b(t[cg + 2][pl]) | ((unsigned)(unsigned short)f2b(t[cg + 3][pl]) << 16);
    int2 v; v.x = (int)w0; v.y = (int)w1;
    *(int2*)&dst[((size_t)(bb * 36864 + p0 + pl)) * 256 + c0 + cg] = v;
  }
}

__global__ void cgather(const float* __restrict__ md0, const float* __restrict__ md1,
                        const int* __restrict__ J, short* __restrict__ cbuf) {
  int total = 9216 * 256;
  for (int i = blockIdx.x * blockDim.x + threadIdx.x; i < total; i += gridDim.x * blockDim.x) {
    int w = i >> 8, c = i & 255;
    const float* src;
    if (w < 4608) src = md0 + (size_t)w * 256;
    else {
      int n = w - 4608; int bb = n / 2304;
      src = md1 + (size_t)(bb * 2304 + J[n]) * 256;
    }
    cbuf[i] = f2b(src[c]);
  }
}

__global__ void build_tab(const int* __restrict__ J, const short* __restrict__ f0c,
                          const short* __restrict__ f1c, const short* __restrict__ zp,
                          unsigned long long* __restrict__ tab) {
  int total = 230400;
  for (int i = blockIdx.x * blockDim.x + threadIdx.x; i < total; i += gridDim.x * blockDim.x) {
    int w = i / 25, t = i - w * 25;
    int bb, cell; const short* fc;
    if (w < 4608) { bb = w / 2304; cell = w - bb * 2304; fc = f0c; }
    else { int n = w - 4608; bb = n / 2304; cell = J[n]; fc = f1c; }
    int cy = cell / 48, cx = cell - cy * 48;
    int y = cy * 4 - 2 + t / 5, x = cx * 4 - 2 + t % 5;
    const short* p = (y >= 0 && y < 192 && x >= 0 && x < 192)
                   ? fc + (size_t)((bb * 192 + y) * 192 + x) * 128 : zp;
    tab[i] = (unsigned long long)(uintptr_t)p;
  }
}

// ---------------- the bf16 MFMA GEMM workhorse (BK=64, 34KB LDS) ----------------

constexpr int AM_LIN = 0, AM_DUAL = 1, AM_TAB = 2, AM_CEN = 3;
constexpr int EP_BIAS = 0, EP_BF32 = 1, EP_RELU = 2, EP_LN = 3, EP_LNRES = 4, EP_MERGE = 5, EP_PART = 6, EP_F16 = 7;

template<int AMODE, int EPI>
__global__ __launch_bounds__(256)
void gemm_bf16(const short* __restrict__ A1, const short* __restrict__ A2,
               const unsigned long long* __restrict__ tab,
               const short* __restrict__ Wt, int M, int Kd, int kstr, int K1,
               const float* __restrict__ bias, int bstride,
               const float* __restrict__ lns, const float* __restrict__ lnb,
               const short* __restrict__ resid,
               const float* __restrict__ ccp, const float* __restrict__ pep,
               short* __restrict__ outb, float* __restrict__ outf, int ldc,
               long wstride, long ostride) {
  __shared__ __align__(16) short As[128 * 64];
  __shared__ __align__(16) short Bs[128 * 64];
  __shared__ float rsum[2][128], rsq[2][128];
  int tid = threadIdx.x, lane = tid & 63, wid = tid >> 6;
  int wr = wid >> 1, wc = wid & 1;
  int nwg = gridDim.x;
  int orig = blockIdx.x;
  int qd = nwg >> 3, rm = nwg & 7;
  int xcd = orig & 7, offx = orig >> 3;
  int bx = (xcd < rm ? xcd * (qd + 1) : rm * (qd + 1) + (xcd - rm) * qd) + offx;
  int rb = bx * 128;
  int by = blockIdx.y;
  int koff = blockIdx.z * Kd;
  const short* Wsel = Wt + (size_t)by * wstride;
  const float* bsel = bias ? bias + (size_t)by * bstride : nullptr;
  short* osel_b = outb ? outb + (size_t)by * ostride : nullptr;
  float* osel_f = outf ? outf + (size_t)by * ostride : nullptr;

  f32x4v acc[4][4];
  #pragma unroll
  for (int i = 0; i < 4; ++i)
    #pragma unroll
    for (int j = 0; j < 4; ++j) acc[i][j] = (f32x4v){0.f, 0.f, 0.f, 0.f};

  for (int k0 = 0; k0 < Kd; k0 += 64) {
    #pragma unroll
    for (int q = 0; q < 4; ++q) {
      int i = (wid * 4 + q) * 64 + lane;
      int r = i >> 3, pch = i & 7;
      int c = pch ^ (r & 7);
      const short* src;
      if (AMODE == AM_LIN) {
        src = A1 + (size_t)(rb + r) * kstr + koff + k0 + c * 8;
      } else if (AMODE == AM_DUAL) {
        if (k0 < K1) src = A1 + (size_t)(rb + r) * K1 + k0 + c * 8;
        else         src = A2 + (size_t)(rb + r) * (Kd - K1) + (k0 - K1) + c * 8;
      } else if (AMODE == AM_CEN) {
        int rg = rb + r;
        if (k0 < K1) src = A1 + (size_t)((rg / 25) * 25 + 12) * K1 + k0 + c * 8;
        else         src = A2 + (size_t)rg * (Kd - K1) + (k0 - K1) + c * 8;
      } else {
        src = (const short*)(uintptr_t)tab[rb + r] + k0 + c * 8;
      }
      gl_lds16(src, &As[(size_t)i * 8]);
    }
    #pragma unroll
    for (int q = 0; q < 4; ++q) {
      int i = (wid * 4 + q) * 64 + lane;
      int r = i >> 3, pch = i & 7;
      int c = pch ^ (r & 7);
      gl_lds16(Wsel + (size_t)r * kstr + koff + k0 + c * 8, &Bs[(size_t)i * 8]);
    }
    __syncthreads();
    #pragma unroll
    for (int kk = 0; kk < 2; ++kk) {
      bf16x8v af[4], bfr[4];
      #pragma unroll
      for (int mi = 0; mi < 4; ++mi) {
        int r = wr * 64 + mi * 16 + (lane & 15);
        int c = kk * 4 + (lane >> 4);
        int pch = c ^ (r & 7);
        af[mi] = *(const bf16x8v*)&As[r * 64 + pch * 8];
      }
      #pragma unroll
      for (int ni = 0; ni < 4; ++ni) {
        int r = wc * 64 + ni * 16 + (lane & 15);
        int c = kk * 4 + (lane >> 4);
        int pch = c ^ (r & 7);
        bfr[ni] = *(const bf16x8v*)&Bs[r * 64 + pch * 8];
      }
      #pragma unroll
      for (int mi = 0; mi < 4; ++mi)
        #pragma unroll
        for (int ni = 0; ni < 4; ++ni)
          acc[mi][ni] = __builtin_amdgcn_mfma_f32_16x16x32_bf16(af[mi], bfr[ni], acc[mi][ni], 0, 0, 0);
    }
    __syncthreads();
  }

  // ---- epilogue ----
  int colloc[4];
  #pragma unroll
  for (int ni = 0; ni < 4; ++ni) colloc[ni] = wc * 64 + ni * 16 + (lane & 15);
  float bv[4];
  #pragma unroll
  for (int ni = 0; ni < 4; ++ni)
    bv[ni] = (EPI == EP_MERGE || EPI == EP_PART) ? 0.f : (bsel ? bsel[colloc[ni]] : 0.f);

  #pragma unroll
  for (int mi = 0; mi < 4; ++mi)
    #pragma unroll
    for (int ni = 0; ni < 4; ++ni)
      #pragma unroll
      for (int q = 0; q < 4; ++q) {
        float v = acc[mi][ni][q] + bv[ni];
        if (EPI == EP_RELU) v = fmaxf(v, 0.f);
        acc[mi][ni][q] = v;
      }

  if (EPI == EP_LN || EPI == EP_LNRES) {
    #pragma unroll
    for (int mi = 0; mi < 4; ++mi)
      #pragma unroll
      for (int q = 0; q < 4; ++q) {
        float s = 0.f, ss = 0.f;
        #pragma unroll
        for (int ni = 0; ni < 4; ++ni) { float v = acc[mi][ni][q]; s += v; ss += v * v; }
        s += __shfl_xor(s, 1, 64); ss += __shfl_xor(ss, 1, 64);
        s += __shfl_xor(s, 2, 64); ss += __shfl_xor(ss, 2, 64);
        s += __shfl_xor(s, 4, 64); ss += __shfl_xor(ss, 4, 64);
        s += __shfl_xor(s, 8, 64); ss += __shfl_xor(ss, 8, 64);
        int rl = wr * 64 + mi * 16 + (lane >> 4) * 4 + q;
        if ((lane & 15) == 0) { rsum[wc][rl] = s; rsq[wc][rl] = ss; }
      }
    __syncthreads();
  }

  #pragma unroll
  for (int mi = 0; mi < 4; ++mi)
    #pragma unroll
    for (int q = 0; q < 4; ++q) {
      int rl = wr * 64 + mi * 16 + (lane >> 4) * 4 + q;
      long rg = rb + rl;
      float mean = 0.f, rstd = 0.f;
      if (EPI == EP_LN || EPI == EP_LNRES) {
        float s = rsum[0][rl] + rsum[1][rl];
        float ss = rsq[0][rl] + rsq[1][rl];
        mean = s * (1.f / 128.f);
        float var = ss * (1.f / 128.f) - mean * mean;
        rstd = 1.f / sqrtf(var + 1e-5f);
      }
      int wv_ = 0, tv_ = 0;
      if (EPI == EP_MERGE) { wv_ = (int)(rg / 25); tv_ = (int)(rg - (long)wv_ * 25); }
      #pragma unroll
      for (int ni = 0; ni < 4; ++ni) {
        int cg = colloc[ni];
        float v = acc[mi][ni][q];
        if (EPI == EP_MERGE) v += ccp[(size_t)wv_ * 128 + cg] + pep[tv_ * 128 + cg];
        if (EPI == EP_LN || EPI == EP_LNRES) {
          v = (v - mean) * rstd * lns[cg] + lnb[cg];
          if (EPI == EP_LNRES) v += b2f(resid[(size_t)rg * 128 + cg]);
        }
        if (EPI == EP_BF32) osel_f[(size_t)rg * ldc + cg] = v;
        else if (EPI == EP_PART) osel_f[((size_t)blockIdx.z * M + rg) * ldc + cg] = v;
        else if (EPI == EP_F16) osel_b[(size_t)rg * ldc + cg] = f2h(v);
        else osel_b[(size_t)rg * ldc + cg] = f2b(v);
      }
    }
}

__global__ void reduce_part(const float* __restrict__ part, const float* __restrict__ bias,
                            short* __restrict__ out) {
  int i = blockIdx.x * blockDim.x + threadIdx.x;
  if (i >= 4608 * 128) return;
  int c = i & 127;
  float s = bias[c];
  #pragma unroll
  for (int z = 0; z < 5; ++z) s += part[(size_t)z * 4608 * 128 + i];
  out[i] = f2b(s);
}

// ---------------- fused QKV: A staged once (BK=128), loop 3 weights, f16 out ----------------

template<bool CROSS>
__global__ __launch_bounds__(256)
void qkv_fused(const short* __restrict__ xq, const short* __restrict__ xkv,
               const short* __restrict__ wqkv, short* __restrict__ out, long ostride) {
  __shared__ __align__(16) short As[128 * 128];   // 32 KB (full K=128)
  __shared__ __align__(16) short Bs[128 * 64];    // 16 KB
  int tid = threadIdx.x, lane = tid & 63, wid = tid >> 6;
  int wr = wid >> 1, wc = wid & 1;
  int nwg = gridDim.x;
  int orig = blockIdx.x;
  int qd = nwg >> 3, rm = nwg & 7;
  int xcd = orig & 7, offx = orig >> 3;
  int bx = (xcd < rm ? xcd * (qd + 1) : rm * (qd + 1) + (xcd - rm) * qd) + offx;
  int rb = bx * 128;

  auto stageA = [&](const short* src) {
    #pragma unroll
    for (int q = 0; q < 8; ++q) {
      int i = (wid * 8 + q) * 64 + lane;
      int r = i >> 4, pch = i & 15;
      int c = pch ^ (r & 15);
      gl_lds16(src + (size_t)(rb + r) * 128 + c * 8, &As[(size_t)i * 8]);
    }
  };
  stageA(xq);

  #pragma unroll
  for (int w = 0; w < 3; ++w) {
    if (CROSS && w == 1) stageA(xkv);
    f32x4v acc[4][4];
    #pragma unroll
    for (int i = 0; i < 4; ++i)
      #pragma unroll
      for (int j = 0; j < 4; ++j) acc[i][j] = (f32x4v){0.f, 0.f, 0.f, 0.f};
    const short* Wsel = wqkv + (size_t)w * 16384;

    #pragma unroll
    for (int kt = 0; kt < 2; ++kt) {
      int k0 = kt * 64;
      #pragma unroll
      for (int q = 0; q < 4; ++q) {
        int i = (wid * 4 + q) * 64 + lane;
        int r = i >> 3, pch = i & 7;
        int c = pch ^ (r & 7);
        gl_lds16(Wsel + (size_t)r * 128 + k0 + c * 8, &Bs[(size_t)i * 8]);
      }
      __syncthreads();
      #pragma unroll
      for (int kk = 0; kk < 2; ++kk) {
        bf16x8v af[4], bfr[4];
        #pragma unroll
        for (int mi = 0; mi < 4; ++mi) {
          int r = wr * 64 + mi * 16 + (lane & 15);
          int cg = kt * 8 + kk * 4 + (lane >> 4);
          int pch = cg ^ (r & 15);
          af[mi] = *(const bf16x8v*)&As[r * 128 + pch * 8];
        }
        #pragma unroll
        for (int ni = 0; ni < 4; ++ni) {
          int r = wc * 64 + ni * 16 + (lane & 15);
          int c = kk * 4 + (lane >> 4);
          int pch = c ^ (r & 7);
          bfr[ni] = *(const bf16x8v*)&Bs[r * 64 + pch * 8];
        }
        #pragma unroll
        for (int mi = 0; mi < 4; ++mi)
          #pragma unroll
          for (int ni = 0; ni < 4; ++ni)
            acc[mi][ni] = __builtin_amdgcn_mfma_f32_16x16x32_bf16(af[mi], bfr[ni], acc[mi][ni], 0, 0, 0);
      }
      __syncthreads();
    }
    short* ow = out + (size_t)w * ostride;
    #pragma unroll
    for (int mi = 0; mi < 4; ++mi)
      #pragma unroll
      for (int q = 0; q < 4; ++q) {
        int rl = wr * 64 + mi * 16 + (lane >> 4) * 4 + q;
        long rg = rb + rl;
        #pragma unroll
        for (int ni = 0; ni < 4; ++ni) {
          int cg = wc * 64 + ni * 16 + (lane & 15);
          ow[(size_t)rg * 128 + cg] = f2h(acc[mi][ni][q]);
        }
      }
  }
}

// ---------------- fully fused block tail v4: M=128 tile (weights staged once per 128 rows) ----
// msg = LN(attnout@wm); h = relu([x,msg]@m1+b1); out = LN(h@m2+b2)+x.
// A/Ms/Hs tiles 128 rows x 128 K ((r&15) orbit); B single-buffered 128(N) x 64(K) halves
// ((r&7) orbit). Wave layout = gemm_bf16 (wr/wc quadrants, acc[4][4]).
// rsum/rsq alias into Bs (dead at both LN points; barrier-separated).
// LDS: 32(AsHs) + 32(Ms) + 16(Bs) = 80 KB exactly -> 2 blocks/CU (163840 B cap).

__global__ __launch_bounds__(256)
void mlp2_fused(const short* __restrict__ x, const short* __restrict__ attnout,
                const short* __restrict__ wmT,
                const short* __restrict__ m1wT, const short* __restrict__ m2wT,
                const float* __restrict__ n1s, const float* __restrict__ n1b,
                const float* __restrict__ b1, const float* __restrict__ b2,
                const float* __restrict__ lns, const float* __restrict__ lnb,
                short* __restrict__ out) {
  __shared__ __align__(16) short AsHs[128 * 128];  // 32 KB: A staging | Hs
  __shared__ __align__(16) short Ms[128 * 128];    // 32 KB
  __shared__ __align__(16) short Bs[128 * 64];     // 16 KB (rsum/rsq alias here)
  short* As = AsHs;
  short* Hs = AsHs;
  float* rsum = (float*)Bs;            // [2][128] -> rsum[wc*128+rl]
  float* rsq  = (float*)Bs + 256;
  int tid = threadIdx.x, lane = tid & 63, wid = tid >> 6;
  int wr = wid >> 1, wc = wid & 1;
  int nwg = gridDim.x;
  int orig = blockIdx.x;
  int qd = nwg >> 3, rm = nwg & 7;
  int xcd = orig & 7, offx = orig >> 3;
  int bx = (xcd < rm ? xcd * (qd + 1) : rm * (qd + 1) + (xcd - rm) * qd) + offx;
  int rb = bx * 128;

  int colloc[4];
  #pragma unroll
  for (int ni = 0; ni < 4; ++ni) colloc[ni] = wc * 64 + ni * 16 + (lane & 15);

  // stage 128x128 A tile, (r&15) orbit, 2048 slots, 8/thread
  auto stageA = [&](const short* src) {
    #pragma unroll
    for (int q = 0; q < 8; ++q) {
      int i = (wid * 8 + q) * 64 + lane;
      int r = i >> 4, pch = i & 15;
      int c = pch ^ (r & 15);
      gl_lds16(src + (size_t)(rb + r) * 128 + c * 8, &As[(size_t)i * 8]);
    }
  };
  // stage 128(N) x 64(K) B half, (r&7) orbit, 1024 slots, 4/thread
  auto stageBh = [&](const short* src, int kstr) {
    #pragma unroll
    for (int q = 0; q < 4; ++q) {
      int i = (wid * 4 + q) * 64 + lane;
      int r = i >> 3, pch = i & 7;
      int c = pch ^ (r & 7);
      gl_lds16(src + (size_t)r * kstr + c * 8, &Bs[(size_t)i * 8]);
    }
  };
  // 32-MFMA region: C[128x128] += A[:, h*64:(h+1)*64] @ Bhalf^T
  auto mfmaH = [&](const short* Atile, int h, f32x4v (*acc)[4]) {
    #pragma unroll
    for (int kk = 0; kk < 2; ++kk) {
      bf16x8v af[4], bfr[4];
      #pragma unroll
      for (int mi = 0; mi < 4; ++mi) {
        int r = wr * 64 + mi * 16 + (lane & 15);
        int cg = h * 8 + kk * 4 + (lane >> 4);
        int pch = cg ^ (r & 15);
        af[mi] = *(const bf16x8v*)&Atile[r * 128 + pch * 8];
      }
      #pragma unroll
      for (int ni = 0; ni < 4; ++ni) {
        int r = wc * 64 + ni * 16 + (lane & 15);
        int c = kk * 4 + (lane >> 4);
        int pch = c ^ (r & 7);
        bfr[ni] = *(const bf16x8v*)&Bs[r * 64 + pch * 8];
      }
      #pragma unroll
      for (int mi = 0; mi < 4; ++mi)
        #pragma unroll
        for (int ni = 0; ni < 4; ++ni)
          acc[mi][ni] = __builtin_amdgcn_mfma_f32_16x16x32_bf16(af[mi], bfr[ni], acc[mi][ni], 0, 0, 0);
    }
  };
  // LN stat reduce from acc into rsum/rsq (call after a sync retiring Bs reads)
  auto lnstats = [&](f32x4v (*acc)[4]) {
    #pragma unroll
    for (int mi = 0; mi < 4; ++mi)
      #pragma unroll
      for (int q = 0; q < 4; ++q) {
        float s = 0.f, ss = 0.f;
        #pragma unroll
        for (int ni = 0; ni < 4; ++ni) { float v = acc[mi][ni][q]; s += v; ss += v * v; }
        s += __shfl_xor(s, 1, 64); ss += __shfl_xor(ss, 1, 64);
        s += __shfl_xor(s, 2, 64); ss += __shfl_xor(ss, 2, 64);
        s += __shfl_xor(s, 4, 64); ss += __shfl_xor(ss, 4, 64);
        s += __shfl_xor(s, 8, 64); ss += __shfl_xor(ss, 8, 64);
        int rl = wr * 64 + mi * 16 + (lane >> 4) * 4 + q;
        if ((lane & 15) == 0) { rsum[wc * 128 + rl] = s; rsq[wc * 128 + rl] = ss; }
      }
  };

  // ---- phase 0: msg = LN(attnout @ wm) -> Ms ----
  {
    f32x4v acc0[4][4];
    #pragma unroll
    for (int i = 0; i < 4; ++i)
      #pragma unroll
      for (int j = 0; j < 4; ++j) acc0[i][j] = (f32x4v){0.f, 0.f, 0.f, 0.f};
    stageA(attnout);
    stageBh(wmT, 128);
    __syncthreads();
    mfmaH(As, 0, acc0);
    __syncthreads();
    stageBh(wmT + 64, 128);
    __syncthreads();
    mfmaH(As, 1, acc0);
    __syncthreads();                 // Bs reads retired -> rsum alias safe
    lnstats(acc0);
    __syncthreads();
    #pragma unroll
    for (int mi = 0; mi < 4; ++mi)
      #pragma unroll
      for (int q = 0; q < 4; ++q) {
        int rl = wr * 64 + mi * 16 + (lane >> 4) * 4 + q;
        float s = rsum[rl] + rsum[128 + rl];
        float ss = rsq[rl] + rsq[128 + rl];
        float mean = s * (1.f / 128.f);
        float var = ss * (1.f / 128.f) - mean * mean;
        float rstd = 1.f / sqrtf(var + 1e-5f);
        #pragma unroll
        for (int ni = 0; ni < 4; ++ni) {
          int cg = colloc[ni];
          float v = (acc0[mi][ni][q] - mean) * rstd * n1s[cg] + n1b[cg];
          int c = cg >> 3, pch = c ^ (rl & 15);
          Ms[rl * 128 + pch * 8 + (cg & 7)] = f2b(v);
        }
      }
    __syncthreads();                 // Ms visible; rsum reads done -> Bs reusable
  }

  // ---- phases 1&2: MLP on [x | Ms] ----
  f32x4v acc2[4][4];
  #pragma unroll
  for (int i = 0; i < 4; ++i)
    #pragma unroll
    for (int j = 0; j < 4; ++j) acc2[i][j] = (f32x4v){0.f, 0.f, 0.f, 0.f};

  #pragma unroll
  for (int nh = 0; nh < 2; ++nh) {
    const short* m1b_ = m1wT + (size_t)(nh * 128) * 256;
    f32x4v acc1[4][4];
    #pragma unroll
    for (int i = 0; i < 4; ++i)
      #pragma unroll
      for (int j = 0; j < 4; ++j) acc1[i][j] = (f32x4v){0.f, 0.f, 0.f, 0.f};

    // m1: 4 K-halves — h0,h1 on As(x); h2,h3 on Ms
    stageA(x);                       // re-stage x (AsHs was Hs in prior nh / attnout in p0)
    stageBh(m1b_, 256);
    __syncthreads();
    mfmaH(As, 0, acc1);
    __syncthreads();
    stageBh(m1b_ + 64, 256);
    __syncthreads();
    mfmaH(As, 1, acc1);              // last As(x) read
    __syncthreads();
    stageBh(m1b_ + 128, 256);
    __syncthreads();
    mfmaH(Ms, 0, acc1);
    __syncthreads();
    stageBh(m1b_ + 192, 256);
    __syncthreads();
    mfmaH(Ms, 1, acc1);
    __syncthreads();
    // bias + relu -> Hs (aliases As; As dead 3 syncs ago)
    #pragma unroll
    for (int mi = 0; mi < 4; ++mi)
      #pragma unroll
      for (int q = 0; q < 4; ++q) {
        int rl = wr * 64 + mi * 16 + (lane >> 4) * 4 + q;
        #pragma unroll
        for (int ni = 0; ni < 4; ++ni) {
          int cg = wc * 64 + ni * 16 + (lane & 15);
          float v = fmaxf(acc1[mi][ni][q] + b1[nh * 128 + cg], 0.f);
          int c = cg >> 3, pch = c ^ (rl & 15);
          Hs[rl * 128 + pch * 8 + (cg & 7)] = f2b(v);
        }
      }
    __syncthreads();
    // m2: 2 K-halves on Hs
    stageBh(m2wT + nh * 128, 256);
    __syncthreads();
    mfmaH(Hs, 0, acc2);
    __syncthreads();
    stageBh(m2wT + nh * 128 + 64, 256);
    __syncthreads();
    mfmaH(Hs, 1, acc2);
    __syncthreads();
  }

  // ---- epilogue: m2 bias + LN(n2) + residual(x) (rsum aliases Bs, reads retired) ----
  #pragma unroll
  for (int mi = 0; mi < 4; ++mi)
    #pragma unroll
    for (int ni = 0; ni < 4; ++ni)
      #pragma unroll
      for (int q = 0; q < 4; ++q)
        acc2[mi][ni][q] += b2[colloc[ni]];

  lnstats(acc2);
  __syncthreads();

  #pragma unroll
  for (int mi = 0; mi < 4; ++mi)
    #pragma unroll
    for (int q = 0; q < 4; ++q) {
      int rl = wr * 64 + mi * 16 + (lane >> 4) * 4 + q;
      long rg = rb + rl;
      float s = rsum[rl] + rsum[128 + rl];
      float ss = rsq[rl] + rsq[128 + rl];
      float mean = s * (1.f / 128.f);
      float var = ss * (1.f / 128.f) - mean * mean;
      float rstd = 1.f / sqrtf(var + 1e-5f);
      #pragma unroll
      for (int ni = 0; ni < 4; ++ni) {
        int cg = colloc[ni];
        float v = (acc2[mi][ni][q] - mean) * rstd * lns[cg] + lnb[cg];
        v += b2f(x[(size_t)rg * 128 + cg]);
        out[(size_t)rg * 128 + cg] = f2b(v);
      }
    }
}

// ---------------- windowed attention v3: raw f16 LDS, fdot2 QK, pk_fma PV ----------------

__global__ __launch_bounds__(256) void attn_win(const short* __restrict__ Q,
                                                const short* __restrict__ K,
                                                const short* __restrict__ V,
                                                short* __restrict__ Mo) {
  int w = blockIdx.x;
  const short* Qg = Q + (size_t)w * 3200;
  const short* Kg = K + (size_t)w * 3200;
  const short* Vg = V + (size_t)w * 3200;
  __shared__ short Qs[25 * 136 + 8], Ks[25 * 136 + 8], Vs[25 * 136 + 8];
  int tid = threadIdx.x;
  for (int s = tid; s < 400; s += 256) {
    int r = s >> 4, ch = s & 15;
    *(int4*)&Qs[r * 136 + ch * 8] = ((const int4*)Qg)[s];
    *(int4*)&Ks[r * 136 + ch * 8] = ((const int4*)Kg)[s];
    *(int4*)&Vs[r * 136 + ch * 8] = ((const int4*)Vg)[s];
  }
  __syncthreads();

  int wid = tid >> 6, lane = tid & 63;
  int half = lane >> 5, li = lane & 31;
  int h = wid * 2 + half;
  if (li < 25) {
    int i = li;
    h2 qr[8];
    #pragma unroll
    for (int t = 0; t < 8; ++t) qr[t] = *(const h2*)&Qs[i * 136 + h * 16 + t * 2];
    float p[25];
    float mx = -1e30f;
    #pragma unroll
    for (int jx = 0; jx < 25; ++jx) {
      const short* kr = &Ks[jx * 136 + h * 16];
      float s = 0.f;
      #pragma unroll
      for (int t = 0; t < 8; ++t)
        s = __builtin_amdgcn_fdot2(qr[t], *(const h2*)&kr[t * 2], s, false);
      s *= 0.25f;
      p[jx] = s;
      mx = fmaxf(mx, s);
    }
    float sum = 0.f;
    #pragma unroll
    for (int jx = 0; jx < 25; ++jx) { float e = expf(p[jx] - mx); p[jx] = e; sum += e; }
    float inv = 1.f / sum;
    h2 o2[8];
    #pragma unroll
    for (int t = 0; t < 8; ++t) { o2[t][0] = (_Float16)0.f; o2[t][1] = (_Float16)0.f; }
    #pragma unroll
    for (int jx = 0; jx < 25; ++jx) {
      _Float16 ph = (_Float16)(p[jx] * inv);
      h2 pv; pv[0] = ph; pv[1] = ph;
      const short* vr = &Vs[jx * 136 + h * 16];
      #pragma unroll
      for (int t = 0; t < 8; ++t) o2[t] += pv * (*(const h2*)&vr[t * 2]);
    }
    int* outp = (int*)(Mo + (size_t)w * 3200 + i * 128 + h * 16);
    #pragma unroll
    for (int t = 0; t < 8; ++t) {
      unsigned lo = (unsigned short)f2b((float)o2[t][0]);
      unsigned hi = (unsigned short)f2b((float)o2[t][1]);
      outp[t] = (int)(lo | (hi << 16));
    }
  }
}

// ---------------- final regression + mask ----------------

__global__ void final_reg(const short* __restrict__ fv, const float* __restrict__ regw,
                          const float* __restrict__ regb, const int* __restrict__ J,
                          const int* __restrict__ CB, float* __restrict__ out) {
  int n = blockIdx.x * blockDim.x + threadIdx.x;
  if (n >= 4608) return;
  const short* f = fv + (size_t)n * 128;
  float c0 = regb[0], c1 = regb[1];
  for (int d = 0; d < 128; ++d) { float v = b2f(f[d]); c0 += v * regw[d * 2]; c1 += v * regw[d * 2 + 1]; }
  int jv = J[n]; int bb = n / 2304;
  int msk = (CB[bb * 2304 + jv] == (n - bb * 2304)) ? 1 : 0;
  float bx = (float)((jv % 48) * 8), by = (float)((jv / 48) * 8);
  out[n * 2] = msk ? (bx + c0) : 0.f;
  out[n * 2 + 1] = msk ? (by + c1) : 0.f;
}

// ---------------- host ----------------

extern "C" void kernel_launch(void* const* d_in, const int* in_sizes, int n_in,
                              void* d_out, int out_size, void* d_ws, size_t ws_size,
                              hipStream_t stream) {
  const float* md0 = (const float*)d_in[0];
  const float* md1 = (const float*)d_in[1];
  const float* fine0 = (const float*)d_in[2];
  const float* fine1 = (const float*)d_in[3];
  const float* conv_w = (const float*)d_in[4];
  const float* conv_b = (const float*)d_in[5];
  const float* proj_w = (const float*)d_in[6];
  const float* proj_b = (const float*)d_in[7];
  const float* merge_w = (const float*)d_in[8];
  const float* merge_b = (const float*)d_in[9];
  const float* reg1_w = (const float*)d_in[10];
  const float* reg1_b = (const float*)d_in[11];
  const float* reg2_w = (const float*)d_in[12];
  const float* reg2_b = (const float*)d_in[13];
  const float* reg_w = (const float*)d_in[14];
  const float* reg_b = (const float*)d_in[15];
  const float* wq_f = (const float*)d_in[16];
  const float* wk_f = (const float*)d_in[17];
  const float* wv_f = (const float*)d_in[18];
  const float* wm_f = (const float*)d_in[19];
  const float* m1w = (const float*)d_in[20];
  const float* m1b = (const float*)d_in[21];
  const float* m2w = (const float*)d_in[22];
  const float* m2b = (const float*)d_in[23];
  const float* n1s = (const float*)d_in[24];
  const float* n1b = (const float*)d_in[25];
  const float* n2s = (const float*)d_in[26];
  const float* n2b = (const float*)d_in[27];

  char* ws = (char*)d_ws;
  const size_t SZX = (size_t)230400 * 128 * 2;
  const size_t TAILSZ = 20 * 1024 * 1024;
  int CHM = 57600;
  if (SZX + 3ull * 230400 * 256 + TAILSZ <= ws_size)      CHM = 230400;
  else if (SZX + 3ull * 115200 * 256 + TAILSZ <= ws_size) CHM = 115200;
  const size_t CHR = (size_t)CHM * 256;

  short* X  = (short*)(ws);
  char*  Rb = ws + SZX;
  short* R0 = (short*)(Rb);
  short* R1 = (short*)(Rb + CHR);
  short* R2 = (short*)(Rb + 2 * CHR);
  float* S    = (float*)Rb;
  short* F0C  = (short*)Rb;
  short* F1C  = (short*)(Rb + (size_t)73728 * 128 * 2);
  short* FT   = X;
  short* FB   = (short*)Rb;
  float* PART = (float*)(Rb + 2 * CHR);

  char* p = ws + SZX + 3 * CHR;
  double* lnR = (double*)p; p += 4608 * 8;
  double* lnC = (double*)p; p += 4608 * 8;
  int* J = (int*)p; p += 4608 * 4;
  int* CBst = (int*)p; p += 4608 * 4;
  double* PSUM = (double*)p; p += (size_t)2 * 12 * 2304 * 8;
  double* PKEY = (double*)p; p += (size_t)2 * 12 * 2304 * 8;
  int* PIDX = (int*)p; p += (size_t)2 * 12 * 2304 * 4;
  short* CBUF = (short*)p; p += (size_t)9216 * 256 * 2;
  short* CEN = (short*)p; p += (size_t)9216 * 128 * 2;
  float* CC = (float*)p; p += (size_t)9216 * 128 * 4;
  unsigned long long* TAB = (unsigned long long*)p; p += (size_t)230400 * 8;
  float* PE = (float*)p; p += 3200 * 4;
  short* ZP = (short*)p; p += 256;
  short* convT = (short*)p; p += 128 * 256 * 2;
  short* projT = (short*)p; p += 128 * 256 * 2;
  short* mergeAT = (short*)p; p += 128 * 128 * 2;
  short* mergeBT = (short*)p; p += 128 * 128 * 2;
  short* reg1T = (short*)p; p += 128 * 256 * 2;
  short* reg2T = (short*)p; p += (size_t)128 * 3200 * 2;
  short* wqkvT = (short*)p; p += (size_t)4 * 3 * 128 * 128 * 2;
  short* wmT = (short*)p; p += 4 * 128 * 128 * 2;
  short* m1T = (short*)p; p += 4 * 256 * 256 * 2;
  short* m2T = (short*)p; p += (size_t)4 * 128 * 256 * 2;
  short* FV = (short*)p; p += (size_t)4608 * 128 * 2;

  const int TQ = 115200;

  prep_all<<<512, 256, 0, stream>>>(conv_w, proj_w, merge_w, reg1_w, reg2_w,
                                    wq_f, wk_f, wv_f, wm_f, m1w, m2w,
                                    convT, projT, mergeAT, mergeBT, reg1T, reg2T,
                                    wqkvT, wmT, m1T, m2T, PE, ZP);

  // matching
  sim_gemm<<<dim3(24, 24, 2), 256, 0, stream>>>(md0, md1, S);
  row_lse<<<4608, 256, 0, stream>>>(S, lnR);
  col_part<<<dim3(36, 12, 2), 256, 0, stream>>>(S, lnR, PSUM, PKEY, PIDX);
  col_reduce<<<18, 256, 0, stream>>>(PSUM, PKEY, PIDX, lnC, CBst);
  row_argmax<<<4608, 256, 0, stream>>>(S, lnC, J);

  auto gemm = [&](auto amode, auto epi, const short* A1, const short* A2,
                  const unsigned long long* tab, const short* Wt, int M, int Kd, int kstr, int K1,
                  const float* bias, int bstride, const float* lns, const float* lnb,
                  const short* resid, const float* cc, const float* pe,
                  short* outb, float* outf, int ldc, int NB, int NZ, long wstride, long ostride) {
    constexpr int AM = decltype(amode)::value, EP = decltype(epi)::value;
    gemm_bf16<AM, EP><<<dim3(M / 128, NB, NZ), 256, 0, stream>>>(
        A1, A2, tab, Wt, M, Kd, kstr, K1, bias, bstride, lns, lnb, resid, cc, pe,
        outb, outf, ldc, wstride, ostride);
  };
  using I0 = std::integral_constant<int, 0>; using I1 = std::integral_constant<int, 1>;
  using I2 = std::integral_constant<int, 2>; using I3 = std::integral_constant<int, 3>;
  using E0 = std::integral_constant<int, 0>; using E1 = std::integral_constant<int, 1>;
  using E5 = std::integral_constant<int, 5>; using E6 = std::integral_constant<int, 6>;

  // fine conv
  transpose_fine<<<dim3(576, 4, 2), 256, 0, stream>>>(fine0, FT);
  gemm(I0{}, E0{}, FT, nullptr, nullptr, convT, 73728, 256, 256, 0, conv_b, 0, nullptr, nullptr, nullptr, nullptr, nullptr, F0C, nullptr, 128, 1, 1, 0, 0);
  transpose_fine<<<dim3(576, 4, 2), 256, 0, stream>>>(fine1, FT);
  gemm(I0{}, E0{}, FT, nullptr, nullptr, convT, 73728, 256, 256, 0, conv_b, 0, nullptr, nullptr, nullptr, nullptr, nullptr, F1C, nullptr, 128, 1, 1, 0, 0);

  // center path + merge
  cgather<<<4608, 256, 0, stream>>>(md0, md1, J, CBUF);
  gemm(I0{}, E0{}, CBUF, nullptr, nullptr, projT, 9216, 256, 256, 0, proj_b, 0, nullptr, nullptr, nullptr, nullptr, nullptr, CEN, nullptr, 128, 1, 1, 0, 0);
  gemm(I0{}, E1{}, CEN, nullptr, nullptr, mergeBT, 9216, 128, 128, 0, merge_b, 0, nullptr, nullptr, nullptr, nullptr, nullptr, nullptr, CC, 128, 1, 1, 0, 0);
  build_tab<<<900, 256, 0, stream>>>(J, F0C, F1C, ZP, TAB);
  gemm(I2{}, E5{}, nullptr, nullptr, TAB, mergeAT, 230400, 128, 128, 0, nullptr, 0, nullptr, nullptr, nullptr, CC, PE, X, nullptr, 128, 1, 1, 0, 0);

  // transformer
  auto pass = [&](int i, const short* xq, const short* xkv, short* xout, int Mtotal, bool cross) {
    const short* wqkv = wqkvT + (size_t)i * 3 * 16384;
    const short* wm = wmT + i * 16384;
    const short* m1 = m1T + i * 65536;
    const short* m2 = m2T + i * 32768;
    for (int off = 0; off < Mtotal; off += CHM) {
      int Mc = (Mtotal - off < CHM) ? (Mtotal - off) : CHM;
      const short* xqc = xq + (size_t)off * 128;
      const short* xkvc = xkv + (size_t)off * 128;
      if (cross)
        qkv_fused<true><<<Mc / 128, 256, 0, stream>>>(xqc, xkvc, wqkv, R0, (long)CHM * 128);
      else
        qkv_fused<false><<<Mc / 128, 256, 0, stream>>>(xqc, xkvc, wqkv, R0, (long)CHM * 128);
      attn_win<<<Mc / 25, 256, 0, stream>>>(R0, R1, R2, R0);
      mlp2_fused<<<Mc / 128, 256, 0, stream>>>(xqc, R0, wm, m1, m2,
                                               n1s + i * 128, n1b + i * 128,
                                               m1b + i * 256, m2b + i * 128,
                                               n2s + i * 128, n2b + i * 128,
                                               xout + (size_t)off * 128);
    }
  };
  short* X1 = X + (size_t)TQ * 128;
  for (int i = 0; i < 4; ++i) {
    if ((i & 1) == 0) {
      pass(i, X, X, X, 230400, false);
    } else {
      pass(i, X, X1, X, TQ, true);
      pass(i, X1, X, X1, TQ, true);
    }
  }

  // regression head
  gemm(I3{}, E0{}, X, X1, nullptr, reg1T, TQ, 256, 256, 128, reg1_b, 0, nullptr, nullptr, nullptr, nullptr, nullptr, FB, nullptr, 128, 1, 1, 0, 0);
  gemm(I0{}, E6{}, FB, nullptr, nullptr, reg2T, 4608, 640, 3200, 0, nullptr, 0, nullptr, nullptr, nullptr, nullptr, nullptr, nullptr, PART, 128, 1, 5, 0, 0);
  reduce_part<<<2304, 256, 0, stream>>>(PART, reg2_b, FV);
  final_reg<<<18, 256, 0, stream>>>(FV, reg_w, reg_b, J, CBst, (float*)d_out);
}

// Round 20
// 1549.200 us; speedup vs baseline: 1.1305x; 1.1305x over previous
//
#include <hip/hip_runtime.h>
#include <stdint.h>
#include <type_traits>

#define DEVFN static __device__ __forceinline__

typedef __attribute__((ext_vector_type(8))) short bf16x8v;
typedef __attribute__((ext_vector_type(4))) float f32x4v;
typedef __attribute__((ext_vector_type(2))) _Float16 h2;

DEVFN float b2f(short s) {
  union { unsigned u; float f; } c; c.u = ((unsigned)(unsigned short)s) << 16; return c.f;
}
DEVFN short f2b(float f) {
  union { float f; unsigned u; } c; c.f = f;
  unsigned r = c.u + 0x7fffu + ((c.u >> 16) & 1u);
  return (short)(r >> 16);
}
DEVFN short f2h(float f) {
  union { _Float16 h; short s; } c; c.h = (_Float16)f; return c.s;
}
DEVFN void gl_lds16(const void* g, void* l) {
  __builtin_amdgcn_global_load_lds((const __attribute__((address_space(1))) void*)g,
                                   (__attribute__((address_space(3))) void*)l, 16, 0, 0);
}
// exp(x) for |x| < ~0.02 (sim scores): 5-term Taylor in f64.
DEVFN double exp_small(double x) {
  return 1.0 + x * (1.0 + x * (0.5 + x * ((1.0 / 6.0) + x * (1.0 / 24.0))));
}

// ---------------- one-shot prep kernel ----------------

__global__ void prep_all(const float* __restrict__ conv_w, const float* __restrict__ proj_w,
                         const float* __restrict__ merge_w, const float* __restrict__ reg1_w,
                         const float* __restrict__ reg2_w, const float* __restrict__ wq,
                         const float* __restrict__ wk, const float* __restrict__ wv,
                         const float* __restrict__ wm, const float* __restrict__ m1w,
                         const float* __restrict__ m2w,
                         short* __restrict__ convT, short* __restrict__ projT,
                         short* __restrict__ mergeAT, short* __restrict__ mergeBT,
                         short* __restrict__ reg1T, short* __restrict__ reg2T,
                         short* __restrict__ wqkvT, short* __restrict__ wmT,
                         short* __restrict__ m1T, short* __restrict__ m2T,
                         float* __restrict__ pe, short* __restrict__ zp) {
  const int L0 = 32768, L1 = 32768, L2 = 16384, L3 = 16384, L4 = 32768, L5 = 409600;
  const int L6 = 196608, L7 = 65536, L8 = 262144, L9 = 131072, L10 = 3200, L11 = 128;
  const int TOT = L0+L1+L2+L3+L4+L5+L6+L7+L8+L9+L10+L11;
  for (int gi = blockIdx.x * blockDim.x + threadIdx.x; gi < TOT; gi += gridDim.x * blockDim.x) {
    int i = gi;
    if (i < L0) { convT[i] = f2b(conv_w[i]); continue; } i -= L0;
    if (i < L1) { int n = i >> 8, k = i & 255; projT[i] = f2b(proj_w[k * 128 + n]); continue; } i -= L1;
    if (i < L2) { int n = i >> 7, k = i & 127; mergeAT[i] = f2b(merge_w[k * 128 + n]); continue; } i -= L2;
    if (i < L3) { int n = i >> 7, k = i & 127; mergeBT[i] = f2b(merge_w[(128 + k) * 128 + n]); continue; } i -= L3;
    if (i < L4) { int n = i >> 8, k = i & 255; reg1T[i] = f2b(reg1_w[k * 128 + n]); continue; } i -= L4;
    if (i < L5) { int n = i / 3200, k = i - n * 3200; reg2T[i] = f2b(reg2_w[k * 128 + n]); continue; } i -= L5;
    if (i < L6) {
      int l = i / 49152; int r = i - l * 49152; int w = r / 16384; int r2 = r - w * 16384;
      int n = r2 >> 7, k = r2 & 127;
      const float* s = (w == 0) ? wq : (w == 1) ? wk : wv;
      wqkvT[i] = f2b(s[l * 16384 + k * 128 + n]); continue;
    } i -= L6;
    if (i < L7) { int l = i >> 14; int r = i & 16383; int n = r >> 7, k = r & 127;
      wmT[i] = f2b(wm[l * 16384 + k * 128 + n]); continue; } i -= L7;
    if (i < L8) { int l = i >> 16; int r = i & 65535; int n = r >> 8, k = r & 255;
      m1T[i] = f2b(m1w[l * 65536 + k * 256 + n]); continue; } i -= L8;
    if (i < L9) { int l = i >> 15; int r = i & 32767; int n = r >> 8, k = r & 255;
      m2T[i] = f2b(m2w[l * 32768 + k * 128 + n]); continue; } i -= L9;
    if (i < L10) {
      int t = i >> 7, d = i & 127; int i2 = d >> 1;
      float div = expf(((float)(2 * i2)) * (-logf(10000.f) / 128.f));
      float ang = (float)t * div;
      pe[i] = (d & 1) ? cosf(ang) : sinf(ang); continue;
    } i -= L10;
    zp[i] = 0;
  }
}

// ---------------- matching (f32/f64, precision-critical) ----------------

__global__ __launch_bounds__(256) void sim_gemm(const float* __restrict__ A,
                                                const float* __restrict__ Bm,
                                                float* __restrict__ S) {
  int b = blockIdx.z;
  A += (size_t)b * 2304 * 256; Bm += (size_t)b * 2304 * 256; S += (size_t)b * 2304 * 2304;
  __shared__ float As[96][33], Bs[96][33];
  int tid = threadIdx.x;
  int tx = tid & 15, ty = tid >> 4;
  int rb = blockIdx.x * 96, cb = blockIdx.y * 96;
  float acc[6][6] = {};
  for (int k0 = 0; k0 < 256; k0 += 32) {
    #pragma unroll
    for (int s = 0; s < 3; ++s) {
      int slot = s * 256 + tid;
      int r = slot >> 3, cq = slot & 7;
      float4 va = *(const float4*)&A[(size_t)(rb + r) * 256 + k0 + 4 * cq];
      float4 vb = *(const float4*)&Bm[(size_t)(cb + r) * 256 + k0 + 4 * cq];
      As[r][4 * cq] = va.x; As[r][4 * cq + 1] = va.y; As[r][4 * cq + 2] = va.z; As[r][4 * cq + 3] = va.w;
      Bs[r][4 * cq] = vb.x; Bs[r][4 * cq + 1] = vb.y; Bs[r][4 * cq + 2] = vb.z; Bs[r][4 * cq + 3] = vb.w;
    }
    __syncthreads();
    #pragma unroll 4
    for (int k = 0; k < 32; ++k) {
      float av[6], bv[6];
      #pragma unroll
      for (int i = 0; i < 6; ++i) av[i] = As[ty + 16 * i][k];
      #pragma unroll
      for (int j = 0; j < 6; ++j) bv[j] = Bs[tx + 16 * j][k];
      #pragma unroll
      for (int i = 0; i < 6; ++i)
        #pragma unroll
        for (int j = 0; j < 6; ++j) acc[i][j] += av[i] * bv[j];
    }
    __syncthreads();
  }
  #pragma unroll
  for (int i = 0; i < 6; ++i)
    #pragma unroll
    for (int j = 0; j < 6; ++j) {
      float t = acc[i][j] * (1.0f / 65536.0f);
      S[(size_t)(rb + ty + 16 * i) * 2304 + cb + tx + 16 * j] = t / 0.1f;
    }
}

__global__ __launch_bounds__(256) void row_lse(const float* __restrict__ S, double* __restrict__ lnR) {
  int row = blockIdx.x;
  const float* Sp = S + (size_t)row * 2304;
  double a = 0;
  for (int m = threadIdx.x; m < 2304; m += 256) a += exp_small((double)Sp[m]);
  __shared__ double red[256];
  red[threadIdx.x] = a; __syncthreads();
  for (int s = 128; s > 0; s >>= 1) { if (threadIdx.x < (unsigned)s) red[threadIdx.x] += red[threadIdx.x + s]; __syncthreads(); }
  if (!threadIdx.x) lnR[row] = log(red[0]);
}

__global__ __launch_bounds__(256) void col_part(const float* __restrict__ S,
                                                const double* __restrict__ lnR,
                                                double* __restrict__ psum,
                                                double* __restrict__ pkey,
                                                int* __restrict__ pidx) {
  int bb = blockIdx.z;
  int c0 = blockIdx.x * 64;
  int rc = blockIdx.y;
  int col = c0 + (threadIdx.x & 63);
  int g = threadIdx.x >> 6;
  const float* Sp = S + (size_t)bb * 2304 * 2304;
  const double* lr = lnR + bb * 2304;
  double a = 0, best = -1e300; int bi = 1 << 30;
  int l0 = rc * 192;
  for (int t = g; t < 192; t += 4) {
    int l = l0 + t;
    double sv = (double)Sp[(size_t)l * 2304 + col];
    a += exp_small(sv);
    double k = 2.0 * sv - lr[l];
    if (k > best || (k == best && l < bi)) { best = k; bi = l; }
  }
  __shared__ double s_sum[256]; __shared__ double s_key[256]; __shared__ int s_idx[256];
  s_sum[threadIdx.x] = a; s_key[threadIdx.x] = best; s_idx[threadIdx.x] = bi;
  __syncthreads();
  if (g == 0) {
    double ts = a; double tk = best; int ti = bi;
    #pragma unroll
    for (int gg = 1; gg < 4; ++gg) {
      int o = threadIdx.x + gg * 64;
      ts += s_sum[o];
      if (s_key[o] > tk || (s_key[o] == tk && s_idx[o] < ti)) { tk = s_key[o]; ti = s_idx[o]; }
    }
    size_t off = ((size_t)bb * 12 + rc) * 2304 + col;
    psum[off] = ts; pkey[off] = tk; pidx[off] = ti;
  }
}

__global__ void col_reduce(const double* __restrict__ psum, const double* __restrict__ pkey,
                           const int* __restrict__ pidx, double* __restrict__ lnC,
                           int* __restrict__ CB) {
  int i = blockIdx.x * blockDim.x + threadIdx.x;
  if (i >= 4608) return;
  int bb = i / 2304, col = i - bb * 2304;
  double s = 0; double bk = -1e300; int bi = 1 << 30;
  for (int rc = 0; rc < 12; ++rc) {
    size_t off = ((size_t)bb * 12 + rc) * 2304 + col;
    s += psum[off];
    double k = pkey[off]; int ix = pidx[off];
    if (k > bk || (k == bk && ix < bi)) { bk = k; bi = ix; }
  }
  lnC[i] = log(s);
  CB[i] = bi;
}

__global__ __launch_bounds__(256) void row_argmax(const float* __restrict__ S,
                                                  const double* __restrict__ lnC,
                                                  int* __restrict__ J) {
  int row = blockIdx.x; int bb = row / 2304;
  const float* Sp = S + (size_t)row * 2304;
  const double* lc = lnC + bb * 2304;
  double best = -1e300; int bi = 1 << 30;
  for (int m = threadIdx.x; m < 2304; m += 256) {
    double k = 2.0 * (double)Sp[m] - lc[m];
    if (k > best || (k == best && m < bi)) { best = k; bi = m; }
  }
  __shared__ double bvs[256]; __shared__ int bis[256];
  bvs[threadIdx.x] = best; bis[threadIdx.x] = bi; __syncthreads();
  for (int s = 128; s > 0; s >>= 1) {
    if (threadIdx.x < (unsigned)s) {
      double ov = bvs[threadIdx.x + s]; int oi = bis[threadIdx.x + s];
      if (ov > bvs[threadIdx.x] || (ov == bvs[threadIdx.x] && oi < bis[threadIdx.x])) { bvs[threadIdx.x] = ov; bis[threadIdx.x] = oi; }
    }
    __syncthreads();
  }
  if (!threadIdx.x) J[row] = bis[0];
}

// ---------------- fine-feature path ----------------

__global__ __launch_bounds__(256) void transpose_fine(const float* __restrict__ src, short* __restrict__ dst) {
  __shared__ float t[64][65];
  int bb = blockIdx.z, p0 = blockIdx.x * 64, c0 = blockIdx.y * 64;
  for (int i = threadIdx.x; i < 1024; i += 256) {
    int cl = i >> 4, pl = (i & 15) * 4;
    float4 v = *(const float4*)&src[((size_t)(bb * 256 + c0 + cl)) * 36864 + p0 + pl];
    t[cl][pl] = v.x; t[cl][pl + 1] = v.y; t[cl][pl + 2] = v.z; t[cl][pl + 3] = v.w;
  }
  __syncthreads();
  for (int i = threadIdx.x; i < 1024; i += 256) {
    int pl = i >> 4, cg = (i & 15) * 4;
    unsigned w0 = (unsigned short)f2b(t[cg][pl]) | ((unsigned)(unsigned short)f2b(t[cg + 1][pl]) << 16);
    unsigned w1 = (unsigned short)f2b(t[cg + 2][pl]) | ((unsigned)(unsigned short)f2b(t[cg + 3][pl]) << 16);
    int2 v; v.x = (int)w0; v.y = (int)w1;
    *(int2*)&dst[((size_t)(bb * 36864 + p0 + pl)) * 256 + c0 + cg] = v;
  }
}

__global__ void cgather(const float* __restrict__ md0, const float* __restrict__ md1,
                        const int* __restrict__ J, short* __restrict__ cbuf) {
  int total = 9216 * 256;
  for (int i = blockIdx.x * blockDim.x + threadIdx.x; i < total; i += gridDim.x * blockDim.x) {
    int w = i >> 8, c = i & 255;
    const float* src;
    if (w < 4608) src = md0 + (size_t)w * 256;
    else {
      int n = w - 4608; int bb = n / 2304;
      src = md1 + (size_t)(bb * 2304 + J[n]) * 256;
    }
    cbuf[i] = f2b(src[c]);
  }
}

__global__ void build_tab(const int* __restrict__ J, const short* __restrict__ f0c,
                          const short* __restrict__ f1c, const short* __restrict__ zp,
                          unsigned long long* __restrict__ tab) {
  int total = 230400;
  for (int i = blockIdx.x * blockDim.x + threadIdx.x; i < total; i += gridDim.x * blockDim.x) {
    int w = i / 25, t = i - w * 25;
    int bb, cell; const short* fc;
    if (w < 4608) { bb = w / 2304; cell = w - bb * 2304; fc = f0c; }
    else { int n = w - 4608; bb = n / 2304; cell = J[n]; fc = f1c; }
    int cy = cell / 48, cx = cell - cy * 48;
    int y = cy * 4 - 2 + t / 5, x = cx * 4 - 2 + t % 5;
    const short* p = (y >= 0 && y < 192 && x >= 0 && x < 192)
                   ? fc + (size_t)((bb * 192 + y) * 192 + x) * 128 : zp;
    tab[i] = (unsigned long long)(uintptr_t)p;
  }
}

// ---------------- the bf16 MFMA GEMM workhorse (BK=64, 34KB LDS) ----------------

constexpr int AM_LIN = 0, AM_DUAL = 1, AM_TAB = 2, AM_CEN = 3;
constexpr int EP_BIAS = 0, EP_BF32 = 1, EP_RELU = 2, EP_LN = 3, EP_LNRES = 4, EP_MERGE = 5, EP_PART = 6, EP_F16 = 7;

template<int AMODE, int EPI>
__global__ __launch_bounds__(256)
void gemm_bf16(const short* __restrict__ A1, const short* __restrict__ A2,
               const unsigned long long* __restrict__ tab,
               const short* __restrict__ Wt, int M, int Kd, int kstr, int K1,
               const float* __restrict__ bias, int bstride,
               const float* __restrict__ lns, const float* __restrict__ lnb,
               const short* __restrict__ resid,
               const float* __restrict__ ccp, const float* __restrict__ pep,
               short* __restrict__ outb, float* __restrict__ outf, int ldc,
               long wstride, long ostride) {
  __shared__ __align__(16) short As[128 * 64];
  __shared__ __align__(16) short Bs[128 * 64];
  __shared__ float rsum[2][128], rsq[2][128];
  int tid = threadIdx.x, lane = tid & 63, wid = tid >> 6;
  int wr = wid >> 1, wc = wid & 1;
  int nwg = gridDim.x;
  int orig = blockIdx.x;
  int qd = nwg >> 3, rm = nwg & 7;
  int xcd = orig & 7, offx = orig >> 3;
  int bx = (xcd < rm ? xcd * (qd + 1) : rm * (qd + 1) + (xcd - rm) * qd) + offx;
  int rb = bx * 128;
  int by = blockIdx.y;
  int koff = blockIdx.z * Kd;
  const short* Wsel = Wt + (size_t)by * wstride;
  const float* bsel = bias ? bias + (size_t)by * bstride : nullptr;
  short* osel_b = outb ? outb + (size_t)by * ostride : nullptr;
  float* osel_f = outf ? outf + (size_t)by * ostride : nullptr;

  f32x4v acc[4][4];
  #pragma unroll
  for (int i = 0; i < 4; ++i)
    #pragma unroll
    for (int j = 0; j < 4; ++j) acc[i][j] = (f32x4v){0.f, 0.f, 0.f, 0.f};

  for (int k0 = 0; k0 < Kd; k0 += 64) {
    #pragma unroll
    for (int q = 0; q < 4; ++q) {
      int i = (wid * 4 + q) * 64 + lane;
      int r = i >> 3, pch = i & 7;
      int c = pch ^ (r & 7);
      const short* src;
      if (AMODE == AM_LIN) {
        src = A1 + (size_t)(rb + r) * kstr + koff + k0 + c * 8;
      } else if (AMODE == AM_DUAL) {
        if (k0 < K1) src = A1 + (size_t)(rb + r) * K1 + k0 + c * 8;
        else         src = A2 + (size_t)(rb + r) * (Kd - K1) + (k0 - K1) + c * 8;
      } else if (AMODE == AM_CEN) {
        int rg = rb + r;
        if (k0 < K1) src = A1 + (size_t)((rg / 25) * 25 + 12) * K1 + k0 + c * 8;
        else         src = A2 + (size_t)rg * (Kd - K1) + (k0 - K1) + c * 8;
      } else {
        src = (const short*)(uintptr_t)tab[rb + r] + k0 + c * 8;
      }
      gl_lds16(src, &As[(size_t)i * 8]);
    }
    #pragma unroll
    for (int q = 0; q < 4; ++q) {
      int i = (wid * 4 + q) * 64 + lane;
      int r = i >> 3, pch = i & 7;
      int c = pch ^ (r & 7);
      gl_lds16(Wsel + (size_t)r * kstr + koff + k0 + c * 8, &Bs[(size_t)i * 8]);
    }
    __syncthreads();
    #pragma unroll
    for (int kk = 0; kk < 2; ++kk) {
      bf16x8v af[4], bfr[4];
      #pragma unroll
      for (int mi = 0; mi < 4; ++mi) {
        int r = wr * 64 + mi * 16 + (lane & 15);
        int c = kk * 4 + (lane >> 4);
        int pch = c ^ (r & 7);
        af[mi] = *(const bf16x8v*)&As[r * 64 + pch * 8];
      }
      #pragma unroll
      for (int ni = 0; ni < 4; ++ni) {
        int r = wc * 64 + ni * 16 + (lane & 15);
        int c = kk * 4 + (lane >> 4);
        int pch = c ^ (r & 7);
        bfr[ni] = *(const bf16x8v*)&Bs[r * 64 + pch * 8];
      }
      #pragma unroll
      for (int mi = 0; mi < 4; ++mi)
        #pragma unroll
        for (int ni = 0; ni < 4; ++ni)
          acc[mi][ni] = __builtin_amdgcn_mfma_f32_16x16x32_bf16(af[mi], bfr[ni], acc[mi][ni], 0, 0, 0);
    }
    __syncthreads();
  }

  // ---- epilogue ----
  int colloc[4];
  #pragma unroll
  for (int ni = 0; ni < 4; ++ni) colloc[ni] = wc * 64 + ni * 16 + (lane & 15);
  float bv[4];
  #pragma unroll
  for (int ni = 0; ni < 4; ++ni)
    bv[ni] = (EPI == EP_MERGE || EPI == EP_PART) ? 0.f : (bsel ? bsel[colloc[ni]] : 0.f);

  #pragma unroll
  for (int mi = 0; mi < 4; ++mi)
    #pragma unroll
    for (int ni = 0; ni < 4; ++ni)
      #pragma unroll
      for (int q = 0; q < 4; ++q) {
        float v = acc[mi][ni][q] + bv[ni];
        if (EPI == EP_RELU) v = fmaxf(v, 0.f);
        acc[mi][ni][q] = v;
      }

  if (EPI == EP_LN || EPI == EP_LNRES) {
    #pragma unroll
    for (int mi = 0; mi < 4; ++mi)
      #pragma unroll
      for (int q = 0; q < 4; ++q) {
        float s = 0.f, ss = 0.f;
        #pragma unroll
        for (int ni = 0; ni < 4; ++ni) { float v = acc[mi][ni][q]; s += v; ss += v * v; }
        s += __shfl_xor(s, 1, 64); ss += __shfl_xor(ss, 1, 64);
        s += __shfl_xor(s, 2, 64); ss += __shfl_xor(ss, 2, 64);
        s += __shfl_xor(s, 4, 64); ss += __shfl_xor(ss, 4, 64);
        s += __shfl_xor(s, 8, 64); ss += __shfl_xor(ss, 8, 64);
        int rl = wr * 64 + mi * 16 + (lane >> 4) * 4 + q;
        if ((lane & 15) == 0) { rsum[wc][rl] = s; rsq[wc][rl] = ss; }
      }
    __syncthreads();
  }

  #pragma unroll
  for (int mi = 0; mi < 4; ++mi)
    #pragma unroll
    for (int q = 0; q < 4; ++q) {
      int rl = wr * 64 + mi * 16 + (lane >> 4) * 4 + q;
      long rg = rb + rl;
      float mean = 0.f, rstd = 0.f;
      if (EPI == EP_LN || EPI == EP_LNRES) {
        float s = rsum[0][rl] + rsum[1][rl];
        float ss = rsq[0][rl] + rsq[1][rl];
        mean = s * (1.f / 128.f);
        float var = ss * (1.f / 128.f) - mean * mean;
        rstd = 1.f / sqrtf(var + 1e-5f);
      }
      int wv_ = 0, tv_ = 0;
      if (EPI == EP_MERGE) { wv_ = (int)(rg / 25); tv_ = (int)(rg - (long)wv_ * 25); }
      #pragma unroll
      for (int ni = 0; ni < 4; ++ni) {
        int cg = colloc[ni];
        float v = acc[mi][ni][q];
        if (EPI == EP_MERGE) v += ccp[(size_t)wv_ * 128 + cg] + pep[tv_ * 128 + cg];
        if (EPI == EP_LN || EPI == EP_LNRES) {
          v = (v - mean) * rstd * lns[cg] + lnb[cg];
          if (EPI == EP_LNRES) v += b2f(resid[(size_t)rg * 128 + cg]);
        }
        if (EPI == EP_BF32) osel_f[(size_t)rg * ldc + cg] = v;
        else if (EPI == EP_PART) osel_f[((size_t)blockIdx.z * M + rg) * ldc + cg] = v;
        else if (EPI == EP_F16) osel_b[(size_t)rg * ldc + cg] = f2h(v);
        else osel_b[(size_t)rg * ldc + cg] = f2b(v);
      }
    }
}

__global__ void reduce_part(const float* __restrict__ part, const float* __restrict__ bias,
                            short* __restrict__ out) {
  int i = blockIdx.x * blockDim.x + threadIdx.x;
  if (i >= 4608 * 128) return;
  int c = i & 127;
  float s = bias[c];
  #pragma unroll
  for (int z = 0; z < 5; ++z) s += part[(size_t)z * 4608 * 128 + i];
  out[i] = f2b(s);
}

// ---------------- fused QKV: A staged once (BK=128), loop 3 weights, f16 out ----------------
// 128-wide As tile uses (r&15) XOR orbit: 16 slots x 16B = 256B = all banks 2x (free).

template<bool CROSS>
__global__ __launch_bounds__(256)
void qkv_fused(const short* __restrict__ xq, const short* __restrict__ xkv,
               const short* __restrict__ wqkv, short* __restrict__ out, long ostride) {
  __shared__ __align__(16) short As[128 * 128];   // 32 KB (full K=128)
  __shared__ __align__(16) short Bs[128 * 64];    // 16 KB
  int tid = threadIdx.x, lane = tid & 63, wid = tid >> 6;
  int wr = wid >> 1, wc = wid & 1;
  int nwg = gridDim.x;
  int orig = blockIdx.x;
  int qd = nwg >> 3, rm = nwg & 7;
  int xcd = orig & 7, offx = orig >> 3;
  int bx = (xcd < rm ? xcd * (qd + 1) : rm * (qd + 1) + (xcd - rm) * qd) + offx;
  int rb = bx * 128;

  auto stageA = [&](const short* src) {
    #pragma unroll
    for (int q = 0; q < 8; ++q) {
      int i = (wid * 8 + q) * 64 + lane;
      int r = i >> 4, pch = i & 15;
      int c = pch ^ (r & 15);
      gl_lds16(src + (size_t)(rb + r) * 128 + c * 8, &As[(size_t)i * 8]);
    }
  };
  stageA(xq);

  #pragma unroll
  for (int w = 0; w < 3; ++w) {
    if (CROSS && w == 1) stageA(xkv);
    f32x4v acc[4][4];
    #pragma unroll
    for (int i = 0; i < 4; ++i)
      #pragma unroll
      for (int j = 0; j < 4; ++j) acc[i][j] = (f32x4v){0.f, 0.f, 0.f, 0.f};
    const short* Wsel = wqkv + (size_t)w * 16384;

    #pragma unroll
    for (int kt = 0; kt < 2; ++kt) {
      int k0 = kt * 64;
      #pragma unroll
      for (int q = 0; q < 4; ++q) {
        int i = (wid * 4 + q) * 64 + lane;
        int r = i >> 3, pch = i & 7;
        int c = pch ^ (r & 7);
        gl_lds16(Wsel + (size_t)r * 128 + k0 + c * 8, &Bs[(size_t)i * 8]);
      }
      __syncthreads();
      #pragma unroll
      for (int kk = 0; kk < 2; ++kk) {
        bf16x8v af[4], bfr[4];
        #pragma unroll
        for (int mi = 0; mi < 4; ++mi) {
          int r = wr * 64 + mi * 16 + (lane & 15);
          int cg = kt * 8 + kk * 4 + (lane >> 4);
          int pch = cg ^ (r & 15);
          af[mi] = *(const bf16x8v*)&As[r * 128 + pch * 8];
        }
        #pragma unroll
        for (int ni = 0; ni < 4; ++ni) {
          int r = wc * 64 + ni * 16 + (lane & 15);
          int c = kk * 4 + (lane >> 4);
          int pch = c ^ (r & 7);
          bfr[ni] = *(const bf16x8v*)&Bs[r * 64 + pch * 8];
        }
        #pragma unroll
        for (int mi = 0; mi < 4; ++mi)
          #pragma unroll
          for (int ni = 0; ni < 4; ++ni)
            acc[mi][ni] = __builtin_amdgcn_mfma_f32_16x16x32_bf16(af[mi], bfr[ni], acc[mi][ni], 0, 0, 0);
      }
      __syncthreads();
    }
    short* ow = out + (size_t)w * ostride;
    #pragma unroll
    for (int mi = 0; mi < 4; ++mi)
      #pragma unroll
      for (int q = 0; q < 4; ++q) {
        int rl = wr * 64 + mi * 16 + (lane >> 4) * 4 + q;
        long rg = rb + rl;
        #pragma unroll
        for (int ni = 0; ni < 4; ++ni) {
          int cg = wc * 64 + ni * 16 + (lane & 15);
          ow[(size_t)rg * 128 + cg] = f2h(acc[mi][ni][q]);
        }
      }
  }
}

// ---------------- fully fused block tail v5: 40 KB LDS -> 3 blocks/CU ----------------
// msg = LN(attnout@wm); h = relu([x,msg]@m1+b1); out = LN(h@m2+b2)+x.
// A staged as 64x64 K-halves in AsH (8 KB, (r&7) orbit); h written into AsH one 64-col
// half at a time (values live in acc1); Bs = [128N][64K] half (16 KB); Ms = 64x128 (16 KB).
// Total 40960 B; 3 x 40960 = 122880 <= measured pool (>=133120) -> 3 blocks/CU.
// MFMA K-order identical to v3 -> bit-identical numerics. LN scratch aliases AsH.

__global__ __launch_bounds__(256)
void mlp2_fused(const short* __restrict__ x, const short* __restrict__ attnout,
                const short* __restrict__ wmT,
                const short* __restrict__ m1wT, const short* __restrict__ m2wT,
                const float* __restrict__ n1s, const float* __restrict__ n1b,
                const float* __restrict__ b1, const float* __restrict__ b2,
                const float* __restrict__ lns, const float* __restrict__ lnb,
                short* __restrict__ out) {
  __shared__ __align__(16) short AsH[64 * 64];    // 8 KB: A K-half | h K-half | LN scratch
  __shared__ __align__(16) short Bs[128 * 64];    // 16 KB
  __shared__ __align__(16) short Ms[64 * 128];    // 16 KB
  float* rsum = (float*)AsH;           // [2][64] -> rsum[wc*64+rl]; live only when AsH dead
  float* rsq  = (float*)AsH + 128;
  int tid = threadIdx.x, lane = tid & 63, wid = tid >> 6;
  int wr = wid >> 1, wc = wid & 1;
  int nwg = gridDim.x;
  int orig = blockIdx.x;
  int qd = nwg >> 3, rm = nwg & 7;
  int xcd = orig & 7, offx = orig >> 3;
  int bx = (xcd < rm ? xcd * (qd + 1) : rm * (qd + 1) + (xcd - rm) * qd) + offx;
  int rb = bx * 64;

  int colloc[4];
  #pragma unroll
  for (int ni = 0; ni < 4; ++ni) colloc[ni] = wc * 64 + ni * 16 + (lane & 15);

  // stage 64x64 A K-half, (r&7) orbit, 512 chunks, 2/thread
  auto stageAh = [&](const short* src, int k0) {
    #pragma unroll
    for (int q = 0; q < 2; ++q) {
      int i = (wid * 2 + q) * 64 + lane;
      int r = i >> 3, pch = i & 7;
      int c = pch ^ (r & 7);
      gl_lds16(src + (size_t)(rb + r) * 128 + k0 + c * 8, &AsH[(size_t)i * 8]);
    }
  };
  // stage 128(N) x 64(K) B half, (r&7) orbit, 1024 chunks, 4/thread
  auto stageBh = [&](const short* src, int kstr) {
    #pragma unroll
    for (int q = 0; q < 4; ++q) {
      int i = (wid * 4 + q) * 64 + lane;
      int r = i >> 3, pch = i & 7;
      int c = pch ^ (r & 7);
      gl_lds16(src + (size_t)r * kstr + c * 8, &Bs[(size_t)i * 8]);
    }
  };
  // 16-MFMA region: C[64x128] += AsH(64x64) @ Bs(128x64)^T
  auto mfmaA = [&](f32x4v (*acc)[4]) {
    #pragma unroll
    for (int kk = 0; kk < 2; ++kk) {
      bf16x8v af[2], bfr[4];
      #pragma unroll
      for (int mi = 0; mi < 2; ++mi) {
        int r = wr * 32 + mi * 16 + (lane & 15);
        int c = kk * 4 + (lane >> 4);
        int pch = c ^ (r & 7);
        af[mi] = *(const bf16x8v*)&AsH[r * 64 + pch * 8];
      }
      #pragma unroll
      for (int ni = 0; ni < 4; ++ni) {
        int r = wc * 64 + ni * 16 + (lane & 15);
        int c = kk * 4 + (lane >> 4);
        int pch = c ^ (r & 7);
        bfr[ni] = *(const bf16x8v*)&Bs[r * 64 + pch * 8];
      }
      #pragma unroll
      for (int mi = 0; mi < 2; ++mi)
        #pragma unroll
        for (int ni = 0; ni < 4; ++ni)
          acc[mi][ni] = __builtin_amdgcn_mfma_f32_16x16x32_bf16(af[mi], bfr[ni], acc[mi][ni], 0, 0, 0);
    }
  };
  // 16-MFMA region: C += Ms[:, mh*64:(mh+1)*64] @ Bs^T  (Ms is 128-wide, (r&15) orbit)
  auto mfmaM = [&](int mh, f32x4v (*acc)[4]) {
    #pragma unroll
    for (int kk = 0; kk < 2; ++kk) {
      bf16x8v af[2], bfr[4];
      #pragma unroll
      for (int mi = 0; mi < 2; ++mi) {
        int r = wr * 32 + mi * 16 + (lane & 15);
        int cg = mh * 8 + kk * 4 + (lane >> 4);
        int pch = cg ^ (r & 15);
        af[mi] = *(const bf16x8v*)&Ms[r * 128 + pch * 8];
      }
      #pragma unroll
      for (int ni = 0; ni < 4; ++ni) {
        int r = wc * 64 + ni * 16 + (lane & 15);
        int c = kk * 4 + (lane >> 4);
        int pch = c ^ (r & 7);
        bfr[ni] = *(const bf16x8v*)&Bs[r * 64 + pch * 8];
      }
      #pragma unroll
      for (int mi = 0; mi < 2; ++mi)
        #pragma unroll
        for (int ni = 0; ni < 4; ++ni)
          acc[mi][ni] = __builtin_amdgcn_mfma_f32_16x16x32_bf16(af[mi], bfr[ni], acc[mi][ni], 0, 0, 0);
    }
  };
  auto lnstats = [&](f32x4v (*acc)[4]) {
    #pragma unroll
    for (int mi = 0; mi < 2; ++mi)
      #pragma unroll
      for (int q = 0; q < 4; ++q) {
        float s = 0.f, ss = 0.f;
        #pragma unroll
        for (int ni = 0; ni < 4; ++ni) { float v = acc[mi][ni][q]; s += v; ss += v * v; }
        s += __shfl_xor(s, 1, 64); ss += __shfl_xor(ss, 1, 64);
        s += __shfl_xor(s, 2, 64); ss += __shfl_xor(ss, 2, 64);
        s += __shfl_xor(s, 4, 64); ss += __shfl_xor(ss, 4, 64);
        s += __shfl_xor(s, 8, 64); ss += __shfl_xor(ss, 8, 64);
        int rl = wr * 32 + mi * 16 + (lane >> 4) * 4 + q;
        if ((lane & 15) == 0) { rsum[wc * 64 + rl] = s; rsq[wc * 64 + rl] = ss; }
      }
  };
  // write h[:, hh*64:(hh+1)*64] (= relu(acc1+b1)) into AsH as an A-half tile.
  // Only waves with wc==hh hold those columns (wave-uniform branch).
  auto writeHh = [&](int hh, int nh, f32x4v (*acc)[4]) {
    if (wc == hh) {
      #pragma unroll
      for (int mi = 0; mi < 2; ++mi)
        #pragma unroll
        for (int q = 0; q < 4; ++q) {
          int rl = wr * 32 + mi * 16 + (lane >> 4) * 4 + q;
          #pragma unroll
          for (int ni = 0; ni < 4; ++ni) {
            int cl = ni * 16 + (lane & 15);
            float v = fmaxf(acc[mi][ni][q] + b1[nh * 128 + hh * 64 + cl], 0.f);
            int c = cl >> 3, pch = c ^ (rl & 7);
            AsH[rl * 64 + pch * 8 + (cl & 7)] = f2b(v);
          }
        }
    }
  };

  // ---- phase 0: msg = LN(attnout @ wm) -> Ms ----
  {
    f32x4v acc0[2][4];
    #pragma unroll
    for (int i = 0; i < 2; ++i)
      #pragma unroll
      for (int j = 0; j < 4; ++j) acc0[i][j] = (f32x4v){0.f, 0.f, 0.f, 0.f};
    stageAh(attnout, 0);
    stageBh(wmT, 128);
    __syncthreads();
    mfmaA(acc0);
    __syncthreads();
    stageAh(attnout, 64);
    stageBh(wmT + 64, 128);
    __syncthreads();
    mfmaA(acc0);
    __syncthreads();                 // AsH reads retired -> rsum alias safe
    lnstats(acc0);
    __syncthreads();
    #pragma unroll
    for (int mi = 0; mi < 2; ++mi)
      #pragma unroll
      for (int q = 0; q < 4; ++q) {
        int rl = wr * 32 + mi * 16 + (lane >> 4) * 4 + q;
        float s = rsum[rl] + rsum[64 + rl];
        float ss = rsq[rl] + rsq[64 + rl];
        float mean = s * (1.f / 128.f);
        float var = ss * (1.f / 128.f) - mean * mean;
        float rstd = 1.f / sqrtf(var + 1e-5f);
        #pragma unroll
        for (int ni = 0; ni < 4; ++ni) {
          int cg = colloc[ni];
          float v = (acc0[mi][ni][q] - mean) * rstd * n1s[cg] + n1b[cg];
          int c = cg >> 3, pch = c ^ (rl & 15);
          Ms[rl * 128 + pch * 8 + (cg & 7)] = f2b(v);
        }
      }
    __syncthreads();                 // Ms visible; rsum reads done -> AsH reusable
  }

  // ---- phases 1&2: MLP on [x | Ms] ----
  f32x4v acc2[2][4];
  #pragma unroll
  for (int i = 0; i < 2; ++i)
    #pragma unroll
    for (int j = 0; j < 4; ++j) acc2[i][j] = (f32x4v){0.f, 0.f, 0.f, 0.f};

  #pragma unroll
  for (int nh = 0; nh < 2; ++nh) {
    const short* m1b_ = m1wT + (size_t)(nh * 128) * 256;
    f32x4v acc1[2][4];
    #pragma unroll
    for (int i = 0; i < 2; ++i)
      #pragma unroll
      for (int j = 0; j < 4; ++j) acc1[i][j] = (f32x4v){0.f, 0.f, 0.f, 0.f};

    // m1 K 0..255 in 4 chunks: x half0, x half1, Ms half0, Ms half1
    stageAh(x, 0);
    stageBh(m1b_, 256);
    __syncthreads();
    mfmaA(acc1);
    __syncthreads();
    stageAh(x, 64);
    stageBh(m1b_ + 64, 256);
    __syncthreads();
    mfmaA(acc1);                     // last AsH(x) read
    __syncthreads();
    stageBh(m1b_ + 128, 256);
    __syncthreads();
    mfmaM(0, acc1);
    __syncthreads();
    stageBh(m1b_ + 192, 256);
    __syncthreads();
    mfmaM(1, acc1);
    __syncthreads();
    // m2 K-half 0: h cols 0..63 -> AsH (AsH dead since x half1 mfma, 3 syncs ago)
    writeHh(0, nh, acc1);
    stageBh(m2wT + nh * 128, 256);
    __syncthreads();
    mfmaA(acc2);
    __syncthreads();
    // m2 K-half 1: h cols 64..127 -> AsH (reads retired by sync above)
    writeHh(1, nh, acc1);
    stageBh(m2wT + nh * 128 + 64, 256);
    __syncthreads();
    mfmaA(acc2);
    __syncthreads();
  }

  // ---- epilogue: m2 bias + LN(n2) + residual(x) (rsum aliases dead AsH) ----
  #pragma unroll
  for (int mi = 0; mi < 2; ++mi)
    #pragma unroll
    for (int ni = 0; ni < 4; ++ni)
      #pragma unroll
      for (int q = 0; q < 4; ++q)
        acc2[mi][ni][q] += b2[colloc[ni]];

  lnstats(acc2);
  __syncthreads();

  #pragma unroll
  for (int mi = 0; mi < 2; ++mi)
    #pragma unroll
    for (int q = 0; q < 4; ++q) {
      int rl = wr * 32 + mi * 16 + (lane >> 4) * 4 + q;
      long rg = rb + rl;
      float s = rsum[rl] + rsum[64 + rl];
      float ss = rsq[rl] + rsq[64 + rl];
      float mean = s * (1.f / 128.f);
      float var = ss * (1.f / 128.f) - mean * mean;
      float rstd = 1.f / sqrtf(var + 1e-5f);
      #pragma unroll
      for (int ni = 0; ni < 4; ++ni) {
        int cg = colloc[ni];
        float v = (acc2[mi][ni][q] - mean) * rstd * lns[cg] + lnb[cg];
        v += b2f(x[(size_t)rg * 128 + cg]);
        out[(size_t)rg * 128 + cg] = f2b(v);
      }
    }
}

// ---------------- windowed attention v3: raw f16 LDS, fdot2 QK, pk_fma PV ----------------

__global__ __launch_bounds__(256) void attn_win(const short* __restrict__ Q,
                                                const short* __restrict__ K,
                                                const short* __restrict__ V,
                                                short* __restrict__ Mo) {
  int w = blockIdx.x;
  const short* Qg = Q + (size_t)w * 3200;
  const short* Kg = K + (size_t)w * 3200;
  const short* Vg = V + (size_t)w * 3200;
  __shared__ short Qs[25 * 136 + 8], Ks[25 * 136 + 8], Vs[25 * 136 + 8];
  int tid = threadIdx.x;
  for (int s = tid; s < 400; s += 256) {
    int r = s >> 4, ch = s & 15;
    *(int4*)&Qs[r * 136 + ch * 8] = ((const int4*)Qg)[s];
    *(int4*)&Ks[r * 136 + ch * 8] = ((const int4*)Kg)[s];
    *(int4*)&Vs[r * 136 + ch * 8] = ((const int4*)Vg)[s];
  }
  __syncthreads();

  int wid = tid >> 6, lane = tid & 63;
  int half = lane >> 5, li = lane & 31;
  int h = wid * 2 + half;
  if (li < 25) {
    int i = li;
    h2 qr[8];
    #pragma unroll
    for (int t = 0; t < 8; ++t) qr[t] = *(const h2*)&Qs[i * 136 + h * 16 + t * 2];
    float p[25];
    float mx = -1e30f;
    #pragma unroll
    for (int jx = 0; jx < 25; ++jx) {
      const short* kr = &Ks[jx * 136 + h * 16];
      float s = 0.f;
      #pragma unroll
      for (int t = 0; t < 8; ++t)
        s = __builtin_amdgcn_fdot2(qr[t], *(const h2*)&kr[t * 2], s, false);
      s *= 0.25f;
      p[jx] = s;
      mx = fmaxf(mx, s);
    }
    float sum = 0.f;
    #pragma unroll
    for (int jx = 0; jx < 25; ++jx) { float e = expf(p[jx] - mx); p[jx] = e; sum += e; }
    float inv = 1.f / sum;
    h2 o2[8];
    #pragma unroll
    for (int t = 0; t < 8; ++t) { o2[t][0] = (_Float16)0.f; o2[t][1] = (_Float16)0.f; }
    #pragma unroll
    for (int jx = 0; jx < 25; ++jx) {
      _Float16 ph = (_Float16)(p[jx] * inv);
      h2 pv; pv[0] = ph; pv[1] = ph;
      const short* vr = &Vs[jx * 136 + h * 16];
      #pragma unroll
      for (int t = 0; t < 8; ++t) o2[t] += pv * (*(const h2*)&vr[t * 2]);
    }
    int* outp = (int*)(Mo + (size_t)w * 3200 + i * 128 + h * 16);
    #pragma unroll
    for (int t = 0; t < 8; ++t) {
      unsigned lo = (unsigned short)f2b((float)o2[t][0]);
      unsigned hi = (unsigned short)f2b((float)o2[t][1]);
      outp[t] = (int)(lo | (hi << 16));
    }
  }
}

// ---------------- final regression + mask ----------------

__global__ void final_reg(const short* __restrict__ fv, const float* __restrict__ regw,
                          const float* __restrict__ regb, const int* __restrict__ J,
                          const int* __restrict__ CB, float* __restrict__ out) {
  int n = blockIdx.x * blockDim.x + threadIdx.x;
  if (n >= 4608) return;
  const short* f = fv + (size_t)n * 128;
  float c0 = regb[0], c1 = regb[1];
  for (int d = 0; d < 128; ++d) { float v = b2f(f[d]); c0 += v * regw[d * 2]; c1 += v * regw[d * 2 + 1]; }
  int jv = J[n]; int bb = n / 2304;
  int msk = (CB[bb * 2304 + jv] == (n - bb * 2304)) ? 1 : 0;
  float bx = (float)((jv % 48) * 8), by = (float)((jv / 48) * 8);
  out[n * 2] = msk ? (bx + c0) : 0.f;
  out[n * 2 + 1] = msk ? (by + c1) : 0.f;
}

// ---------------- host ----------------

extern "C" void kernel_launch(void* const* d_in, const int* in_sizes, int n_in,
                              void* d_out, int out_size, void* d_ws, size_t ws_size,
                              hipStream_t stream) {
  const float* md0 = (const float*)d_in[0];
  const float* md1 = (const float*)d_in[1];
  const float* fine0 = (const float*)d_in[2];
  const float* fine1 = (const float*)d_in[3];
  const float* conv_w = (const float*)d_in[4];
  const float* conv_b = (const float*)d_in[5];
  const float* proj_w = (const float*)d_in[6];
  const float* proj_b = (const float*)d_in[7];
  const float* merge_w = (const float*)d_in[8];
  const float* merge_b = (const float*)d_in[9];
  const float* reg1_w = (const float*)d_in[10];
  const float* reg1_b = (const float*)d_in[11];
  const float* reg2_w = (const float*)d_in[12];
  const float* reg2_b = (const float*)d_in[13];
  const float* reg_w = (const float*)d_in[14];
  const float* reg_b = (const float*)d_in[15];
  const float* wq_f = (const float*)d_in[16];
  const float* wk_f = (const float*)d_in[17];
  const float* wv_f = (const float*)d_in[18];
  const float* wm_f = (const float*)d_in[19];
  const float* m1w = (const float*)d_in[20];
  const float* m1b = (const float*)d_in[21];
  const float* m2w = (const float*)d_in[22];
  const float* m2b = (const float*)d_in[23];
  const float* n1s = (const float*)d_in[24];
  const float* n1b = (const float*)d_in[25];
  const float* n2s = (const float*)d_in[26];
  const float* n2b = (const float*)d_in[27];

  char* ws = (char*)d_ws;
  const size_t SZX = (size_t)230400 * 128 * 2;
  const size_t TAILSZ = 20 * 1024 * 1024;
  int CHM = 57600;
  if (SZX + 3ull * 230400 * 256 + TAILSZ <= ws_size)      CHM = 230400;
  else if (SZX + 3ull * 115200 * 256 + TAILSZ <= ws_size) CHM = 115200;
  const size_t CHR = (size_t)CHM * 256;

  short* X  = (short*)(ws);
  char*  Rb = ws + SZX;
  short* R0 = (short*)(Rb);
  short* R1 = (short*)(Rb + CHR);
  short* R2 = (short*)(Rb + 2 * CHR);
  float* S    = (float*)Rb;
  short* F0C  = (short*)Rb;
  short* F1C  = (short*)(Rb + (size_t)73728 * 128 * 2);
  short* FT   = X;
  short* FB   = (short*)Rb;
  float* PART = (float*)(Rb + 2 * CHR);

  char* p = ws + SZX + 3 * CHR;
  double* lnR = (double*)p; p += 4608 * 8;
  double* lnC = (double*)p; p += 4608 * 8;
  int* J = (int*)p; p += 4608 * 4;
  int* CBst = (int*)p; p += 4608 * 4;
  double* PSUM = (double*)p; p += (size_t)2 * 12 * 2304 * 8;
  double* PKEY = (double*)p; p += (size_t)2 * 12 * 2304 * 8;
  int* PIDX = (int*)p; p += (size_t)2 * 12 * 2304 * 4;
  short* CBUF = (short*)p; p += (size_t)9216 * 256 * 2;
  short* CEN = (short*)p; p += (size_t)9216 * 128 * 2;
  float* CC = (float*)p; p += (size_t)9216 * 128 * 4;
  unsigned long long* TAB = (unsigned long long*)p; p += (size_t)230400 * 8;
  float* PE = (float*)p; p += 3200 * 4;
  short* ZP = (short*)p; p += 256;
  short* convT = (short*)p; p += 128 * 256 * 2;
  short* projT = (short*)p; p += 128 * 256 * 2;
  short* mergeAT = (short*)p; p += 128 * 128 * 2;
  short* mergeBT = (short*)p; p += 128 * 128 * 2;
  short* reg1T = (short*)p; p += 128 * 256 * 2;
  short* reg2T = (short*)p; p += (size_t)128 * 3200 * 2;
  short* wqkvT = (short*)p; p += (size_t)4 * 3 * 128 * 128 * 2;
  short* wmT = (short*)p; p += 4 * 128 * 128 * 2;
  short* m1T = (short*)p; p += 4 * 256 * 256 * 2;
  short* m2T = (short*)p; p += (size_t)4 * 128 * 256 * 2;
  short* FV = (short*)p; p += (size_t)4608 * 128 * 2;

  const int TQ = 115200;

  prep_all<<<512, 256, 0, stream>>>(conv_w, proj_w, merge_w, reg1_w, reg2_w,
                                    wq_f, wk_f, wv_f, wm_f, m1w, m2w,
                                    convT, projT, mergeAT, mergeBT, reg1T, reg2T,
                                    wqkvT, wmT, m1T, m2T, PE, ZP);

  // matching
  sim_gemm<<<dim3(24, 24, 2), 256, 0, stream>>>(md0, md1, S);
  row_lse<<<4608, 256, 0, stream>>>(S, lnR);
  col_part<<<dim3(36, 12, 2), 256, 0, stream>>>(S, lnR, PSUM, PKEY, PIDX);
  col_reduce<<<18, 256, 0, stream>>>(PSUM, PKEY, PIDX, lnC, CBst);
  row_argmax<<<4608, 256, 0, stream>>>(S, lnC, J);

  auto gemm = [&](auto amode, auto epi, const short* A1, const short* A2,
                  const unsigned long long* tab, const short* Wt, int M, int Kd, int kstr, int K1,
                  const float* bias, int bstride, const float* lns, const float* lnb,
                  const short* resid, const float* cc, const float* pe,
                  short* outb, float* outf, int ldc, int NB, int NZ, long wstride, long ostride) {
    constexpr int AM = decltype(amode)::value, EP = decltype(epi)::value;
    gemm_bf16<AM, EP><<<dim3(M / 128, NB, NZ), 256, 0, stream>>>(
        A1, A2, tab, Wt, M, Kd, kstr, K1, bias, bstride, lns, lnb, resid, cc, pe,
        outb, outf, ldc, wstride, ostride);
  };
  using I0 = std::integral_constant<int, 0>; using I1 = std::integral_constant<int, 1>;
  using I2 = std::integral_constant<int, 2>; using I3 = std::integral_constant<int, 3>;
  using E0 = std::integral_constant<int, 0>; using E1 = std::integral_constant<int, 1>;
  using E5 = std::integral_constant<int, 5>; using E6 = std::integral_constant<int, 6>;

  // fine conv
  transpose_fine<<<dim3(576, 4, 2), 256, 0, stream>>>(fine0, FT);
  gemm(I0{}, E0{}, FT, nullptr, nullptr, convT, 73728, 256, 256, 0, conv_b, 0, nullptr, nullptr, nullptr, nullptr, nullptr, F0C, nullptr, 128, 1, 1, 0, 0);
  transpose_fine<<<dim3(576, 4, 2), 256, 0, stream>>>(fine1, FT);
  gemm(I0{}, E0{}, FT, nullptr, nullptr, convT, 73728, 256, 256, 0, conv_b, 0, nullptr, nullptr, nullptr, nullptr, nullptr, F1C, nullptr, 128, 1, 1, 0, 0);

  // center path + merge
  cgather<<<4608, 256, 0, stream>>>(md0, md1, J, CBUF);
  gemm(I0{}, E0{}, CBUF, nullptr, nullptr, projT, 9216, 256, 256, 0, proj_b, 0, nullptr, nullptr, nullptr, nullptr, nullptr, CEN, nullptr, 128, 1, 1, 0, 0);
  gemm(I0{}, E1{}, CEN, nullptr, nullptr, mergeBT, 9216, 128, 128, 0, merge_b, 0, nullptr, nullptr, nullptr, nullptr, nullptr, nullptr, CC, 128, 1, 1, 0, 0);
  build_tab<<<900, 256, 0, stream>>>(J, F0C, F1C, ZP, TAB);
  gemm(I2{}, E5{}, nullptr, nullptr, TAB, mergeAT, 230400, 128, 128, 0, nullptr, 0, nullptr, nullptr, nullptr, CC, PE, X, nullptr, 128, 1, 1, 0, 0);

  // transformer
  auto pass = [&](int i, const short* xq, const short* xkv, short* xout, int Mtotal, bool cross) {
    const short* wqkv = wqkvT + (size_t)i * 3 * 16384;
    const short* wm = wmT + i * 16384;
    const short* m1 = m1T + i * 65536;
    const short* m2 = m2T + i * 32768;
    for (int off = 0; off < Mtotal; off += CHM) {
      int Mc = (Mtotal - off < CHM) ? (Mtotal - off) : CHM;
      const short* xqc = xq + (size_t)off * 128;
      const short* xkvc = xkv + (size_t)off * 128;
      if (cross)
        qkv_fused<true><<<Mc / 128, 256, 0, stream>>>(xqc, xkvc, wqkv, R0, (long)CHM * 128);
      else
        qkv_fused<false><<<Mc / 128, 256, 0, stream>>>(xqc, xkvc, wqkv, R0, (long)CHM * 128);
      attn_win<<<Mc / 25, 256, 0, stream>>>(R0, R1, R2, R0);
      mlp2_fused<<<Mc / 64, 256, 0, stream>>>(xqc, R0, wm, m1, m2,
                                              n1s + i * 128, n1b + i * 128,
                                              m1b + i * 256, m2b + i * 128,
                                              n2s + i * 128, n2b + i * 128,
                                              xout + (size_t)off * 128);
    }
  };
  short* X1 = X + (size_t)TQ * 128;
  for (int i = 0; i < 4; ++i) {
    if ((i & 1) == 0) {
      pass(i, X, X, X, 230400, false);
    } else {
      pass(i, X, X1, X, TQ, true);
      pass(i, X1, X, X1, TQ, true);
    }
  }

  // regression head
  gemm(I3{}, E0{}, X, X1, nullptr, reg1T, TQ, 256, 256, 128, reg1_b, 0, nullptr, nullptr, nullptr, nullptr, nullptr, FB, nullptr, 128, 1, 1, 0, 0);
  gemm(I0{}, E6{}, FB, nullptr, nullptr, reg2T, 4608, 640, 3200, 0, nullptr, 0, nullptr, nullptr, nullptr, nullptr, nullptr, nullptr, PART, 128, 1, 5, 0, 0);
  reduce_part<<<2304, 256, 0, stream>>>(PART, reg2_b, FV);
  final_reg<<<18, 256, 0, stream>>>(FV, reg_w, reg_b, J, CBst, (float*)d_out);
}

// Round 21
// 1471.737 us; speedup vs baseline: 1.1900x; 1.0526x over previous
//
#include <hip/hip_runtime.h>
#include <stdint.h>
#include <type_traits>

#define DEVFN static __device__ __forceinline__

typedef __attribute__((ext_vector_type(8))) short bf16x8v;
typedef __attribute__((ext_vector_type(4))) float f32x4v;
typedef __attribute__((ext_vector_type(2))) _Float16 h2;

DEVFN float b2f(short s) {
  union { unsigned u; float f; } c; c.u = ((unsigned)(unsigned short)s) << 16; return c.f;
}
DEVFN short f2b(float f) {
  union { float f; unsigned u; } c; c.f = f;
  unsigned r = c.u + 0x7fffu + ((c.u >> 16) & 1u);
  return (short)(r >> 16);
}
DEVFN short f2h(float f) {
  union { _Float16 h; short s; } c; c.h = (_Float16)f; return c.s;
}
DEVFN void gl_lds16(const void* g, void* l) {
  __builtin_amdgcn_global_load_lds((const __attribute__((address_space(1))) void*)g,
                                   (__attribute__((address_space(3))) void*)l, 16, 0, 0);
}
// exp(x) for |x| < ~0.02 (sim scores): 5-term Taylor in f64.
DEVFN double exp_small(double x) {
  return 1.0 + x * (1.0 + x * (0.5 + x * ((1.0 / 6.0) + x * (1.0 / 24.0))));
}

// ---------------- one-shot prep kernel ----------------

__global__ void prep_all(const float* __restrict__ conv_w, const float* __restrict__ proj_w,
                         const float* __restrict__ merge_w, const float* __restrict__ reg1_w,
                         const float* __restrict__ reg2_w, const float* __restrict__ wq,
                         const float* __restrict__ wk, const float* __restrict__ wv,
                         const float* __restrict__ wm, const float* __restrict__ m1w,
                         const float* __restrict__ m2w,
                         short* __restrict__ convT, short* __restrict__ projT,
                         short* __restrict__ mergeAT, short* __restrict__ mergeBT,
                         short* __restrict__ reg1T, short* __restrict__ reg2T,
                         short* __restrict__ wqkvT, short* __restrict__ wmT,
                         short* __restrict__ m1T, short* __restrict__ m2T,
                         float* __restrict__ pe, short* __restrict__ zp) {
  const int L0 = 32768, L1 = 32768, L2 = 16384, L3 = 16384, L4 = 32768, L5 = 409600;
  const int L6 = 196608, L7 = 65536, L8 = 262144, L9 = 131072, L10 = 3200, L11 = 128;
  const int TOT = L0+L1+L2+L3+L4+L5+L6+L7+L8+L9+L10+L11;
  for (int gi = blockIdx.x * blockDim.x + threadIdx.x; gi < TOT; gi += gridDim.x * blockDim.x) {
    int i = gi;
    if (i < L0) { convT[i] = f2b(conv_w[i]); continue; } i -= L0;
    if (i < L1) { int n = i >> 8, k = i & 255; projT[i] = f2b(proj_w[k * 128 + n]); continue; } i -= L1;
    if (i < L2) { int n = i >> 7, k = i & 127; mergeAT[i] = f2b(merge_w[k * 128 + n]); continue; } i -= L2;
    if (i < L3) { int n = i >> 7, k = i & 127; mergeBT[i] = f2b(merge_w[(128 + k) * 128 + n]); continue; } i -= L3;
    if (i < L4) { int n = i >> 8, k = i & 255; reg1T[i] = f2b(reg1_w[k * 128 + n]); continue; } i -= L4;
    if (i < L5) { int n = i / 3200, k = i - n * 3200; reg2T[i] = f2b(reg2_w[k * 128 + n]); continue; } i -= L5;
    if (i < L6) {
      int l = i / 49152; int r = i - l * 49152; int w = r / 16384; int r2 = r - w * 16384;
      int n = r2 >> 7, k = r2 & 127;
      const float* s = (w == 0) ? wq : (w == 1) ? wk : wv;
      wqkvT[i] = f2b(s[l * 16384 + k * 128 + n]); continue;
    } i -= L6;
    if (i < L7) { int l = i >> 14; int r = i & 16383; int n = r >> 7, k = r & 127;
      wmT[i] = f2b(wm[l * 16384 + k * 128 + n]); continue; } i -= L7;
    if (i < L8) { int l = i >> 16; int r = i & 65535; int n = r >> 8, k = r & 255;
      m1T[i] = f2b(m1w[l * 65536 + k * 256 + n]); continue; } i -= L8;
    if (i < L9) { int l = i >> 15; int r = i & 32767; int n = r >> 8, k = r & 255;
      m2T[i] = f2b(m2w[l * 32768 + k * 128 + n]); continue; } i -= L9;
    if (i < L10) {
      int t = i >> 7, d = i & 127; int i2 = d >> 1;
      float div = expf(((float)(2 * i2)) * (-logf(10000.f) / 128.f));
      float ang = (float)t * div;
      pe[i] = (d & 1) ? cosf(ang) : sinf(ang); continue;
    } i -= L10;
    zp[i] = 0;
  }
}

// ---------------- matching (f32/f64, precision-critical) ----------------

__global__ __launch_bounds__(256) void sim_gemm(const float* __restrict__ A,
                                                const float* __restrict__ Bm,
                                                float* __restrict__ S) {
  int b = blockIdx.z;
  A += (size_t)b * 2304 * 256; Bm += (size_t)b * 2304 * 256; S += (size_t)b * 2304 * 2304;
  __shared__ float As[96][33], Bs[96][33];
  int tid = threadIdx.x;
  int tx = tid & 15, ty = tid >> 4;
  int rb = blockIdx.x * 96, cb = blockIdx.y * 96;
  float acc[6][6] = {};
  for (int k0 = 0; k0 < 256; k0 += 32) {
    #pragma unroll
    for (int s = 0; s < 3; ++s) {
      int slot = s * 256 + tid;
      int r = slot >> 3, cq = slot & 7;
      float4 va = *(const float4*)&A[(size_t)(rb + r) * 256 + k0 + 4 * cq];
      float4 vb = *(const float4*)&Bm[(size_t)(cb + r) * 256 + k0 + 4 * cq];
      As[r][4 * cq] = va.x; As[r][4 * cq + 1] = va.y; As[r][4 * cq + 2] = va.z; As[r][4 * cq + 3] = va.w;
      Bs[r][4 * cq] = vb.x; Bs[r][4 * cq + 1] = vb.y; Bs[r][4 * cq + 2] = vb.z; Bs[r][4 * cq + 3] = vb.w;
    }
    __syncthreads();
    #pragma unroll 4
    for (int k = 0; k < 32; ++k) {
      float av[6], bv[6];
      #pragma unroll
      for (int i = 0; i < 6; ++i) av[i] = As[ty + 16 * i][k];
      #pragma unroll
      for (int j = 0; j < 6; ++j) bv[j] = Bs[tx + 16 * j][k];
      #pragma unroll
      for (int i = 0; i < 6; ++i)
        #pragma unroll
        for (int j = 0; j < 6; ++j) acc[i][j] += av[i] * bv[j];
    }
    __syncthreads();
  }
  #pragma unroll
  for (int i = 0; i < 6; ++i)
    #pragma unroll
    for (int j = 0; j < 6; ++j) {
      float t = acc[i][j] * (1.0f / 65536.0f);
      S[(size_t)(rb + ty + 16 * i) * 2304 + cb + tx + 16 * j] = t / 0.1f;
    }
}

__global__ __launch_bounds__(256) void row_lse(const float* __restrict__ S, double* __restrict__ lnR) {
  int row = blockIdx.x;
  const float* Sp = S + (size_t)row * 2304;
  double a = 0;
  for (int m = threadIdx.x; m < 2304; m += 256) a += exp_small((double)Sp[m]);
  __shared__ double red[256];
  red[threadIdx.x] = a; __syncthreads();
  for (int s = 128; s > 0; s >>= 1) { if (threadIdx.x < (unsigned)s) red[threadIdx.x] += red[threadIdx.x + s]; __syncthreads(); }
  if (!threadIdx.x) lnR[row] = log(red[0]);
}

__global__ __launch_bounds__(256) void col_part(const float* __restrict__ S,
                                                const double* __restrict__ lnR,
                                                double* __restrict__ psum,
                                                double* __restrict__ pkey,
                                                int* __restrict__ pidx) {
  int bb = blockIdx.z;
  int c0 = blockIdx.x * 64;
  int rc = blockIdx.y;
  int col = c0 + (threadIdx.x & 63);
  int g = threadIdx.x >> 6;
  const float* Sp = S + (size_t)bb * 2304 * 2304;
  const double* lr = lnR + bb * 2304;
  double a = 0, best = -1e300; int bi = 1 << 30;
  int l0 = rc * 192;
  for (int t = g; t < 192; t += 4) {
    int l = l0 + t;
    double sv = (double)Sp[(size_t)l * 2304 + col];
    a += exp_small(sv);
    double k = 2.0 * sv - lr[l];
    if (k > best || (k == best && l < bi)) { best = k; bi = l; }
  }
  __shared__ double s_sum[256]; __shared__ double s_key[256]; __shared__ int s_idx[256];
  s_sum[threadIdx.x] = a; s_key[threadIdx.x] = best; s_idx[threadIdx.x] = bi;
  __syncthreads();
  if (g == 0) {
    double ts = a; double tk = best; int ti = bi;
    #pragma unroll
    for (int gg = 1; gg < 4; ++gg) {
      int o = threadIdx.x + gg * 64;
      ts += s_sum[o];
      if (s_key[o] > tk || (s_key[o] == tk && s_idx[o] < ti)) { tk = s_key[o]; ti = s_idx[o]; }
    }
    size_t off = ((size_t)bb * 12 + rc) * 2304 + col;
    psum[off] = ts; pkey[off] = tk; pidx[off] = ti;
  }
}

__global__ void col_reduce(const double* __restrict__ psum, const double* __restrict__ pkey,
                           const int* __restrict__ pidx, double* __restrict__ lnC,
                           int* __restrict__ CB) {
  int i = blockIdx.x * blockDim.x + threadIdx.x;
  if (i >= 4608) return;
  int bb = i / 2304, col = i - bb * 2304;
  double s = 0; double bk = -1e300; int bi = 1 << 30;
  for (int rc = 0; rc < 12; ++rc) {
    size_t off = ((size_t)bb * 12 + rc) * 2304 + col;
    s += psum[off];
    double k = pkey[off]; int ix = pidx[off];
    if (k > bk || (k == bk && ix < bi)) { bk = k; bi = ix; }
  }
  lnC[i] = log(s);
  CB[i] = bi;
}

__global__ __launch_bounds__(256) void row_argmax(const float* __restrict__ S,
                                                  const double* __restrict__ lnC,
                                                  int* __restrict__ J) {
  int row = blockIdx.x; int bb = row / 2304;
  const float* Sp = S + (size_t)row * 2304;
  const double* lc = lnC + bb * 2304;
  double best = -1e300; int bi = 1 << 30;
  for (int m = threadIdx.x; m < 2304; m += 256) {
    double k = 2.0 * (double)Sp[m] - lc[m];
    if (k > best || (k == best && m < bi)) { best = k; bi = m; }
  }
  __shared__ double bvs[256]; __shared__ int bis[256];
  bvs[threadIdx.x] = best; bis[threadIdx.x] = bi; __syncthreads();
  for (int s = 128; s > 0; s >>= 1) {
    if (threadIdx.x < (unsigned)s) {
      double ov = bvs[threadIdx.x + s]; int oi = bis[threadIdx.x + s];
      if (ov > bvs[threadIdx.x] || (ov == bvs[threadIdx.x] && oi < bis[threadIdx.x])) { bvs[threadIdx.x] = ov; bis[threadIdx.x] = oi; }
    }
    __syncthreads();
  }
  if (!threadIdx.x) J[row] = bis[0];
}

// ---------------- fine-feature path ----------------

__global__ __launch_bounds__(256) void transpose_fine(const float* __restrict__ src, short* __restrict__ dst) {
  __shared__ float t[64][65];
  int bb = blockIdx.z, p0 = blockIdx.x * 64, c0 = blockIdx.y * 64;
  for (int i = threadIdx.x; i < 1024; i += 256) {
    int cl = i >> 4, pl = (i & 15) * 4;
    float4 v = *(const float4*)&src[((size_t)(bb * 256 + c0 + cl)) * 36864 + p0 + pl];
    t[cl][pl] = v.x; t[cl][pl + 1] = v.y; t[cl][pl + 2] = v.z; t[cl][pl + 3] = v.w;
  }
  __syncthreads();
  for (int i = threadIdx.x; i < 1024; i += 256) {
    int pl = i >> 4, cg = (i & 15) * 4;
    unsigned w0 = (unsigned short)f2b(t[cg][pl]) | ((unsigned)(unsigned short)f2b(t[cg + 1][pl]) << 16);
    unsigned w1 = (unsigned short)f2b(t[cg + 2][pl]) | ((unsigned)(unsigned short)f2b(t[cg + 3][pl]) << 16);
    int2 v; v.x = (int)w0; v.y = (int)w1;
    *(int2*)&dst[((size_t)(bb * 36864 + p0 + pl)) * 256 + c0 + cg] = v;
  }
}

__global__ void cgather(const float* __restrict__ md0, const float* __restrict__ md1,
                        const int* __restrict__ J, short* __restrict__ cbuf) {
  int total = 9216 * 256;
  for (int i = blockIdx.x * blockDim.x + threadIdx.x; i < total; i += gridDim.x * blockDim.x) {
    int w = i >> 8, c = i & 255;
    const float* src;
    if (w < 4608) src = md0 + (size_t)w * 256;
    else {
      int n = w - 4608; int bb = n / 2304;
      src = md1 + (size_t)(bb * 2304 + J[n]) * 256;
    }
    cbuf[i] = f2b(src[c]);
  }
}

__global__ void build_tab(const int* __restrict__ J, const short* __restrict__ f0c,
                          const short* __restrict__ f1c, const short* __restrict__ zp,
                          unsigned long long* __restrict__ tab) {
  int total = 230400;
  for (int i = blockIdx.x * blockDim.x + threadIdx.x; i < total; i += gridDim.x * blockDim.x) {
    int w = i / 25, t = i - w * 25;
    int bb, cell; const short* fc;
    if (w < 4608) { bb = w / 2304; cell = w - bb * 2304; fc = f0c; }
    else { int n = w - 4608; bb = n / 2304; cell = J[n]; fc = f1c; }
    int cy = cell / 48, cx = cell - cy * 48;
    int y = cy * 4 - 2 + t / 5, x = cx * 4 - 2 + t % 5;
    const short* p = (y >= 0 && y < 192 && x >= 0 && x < 192)
                   ? fc + (size_t)((bb * 192 + y) * 192 + x) * 128 : zp;
    tab[i] = (unsigned long long)(uintptr_t)p;
  }
}

// ---------------- the bf16 MFMA GEMM workhorse (BK=64, 34KB LDS) ----------------

constexpr int AM_LIN = 0, AM_DUAL = 1, AM_TAB = 2, AM_CEN = 3;
constexpr int EP_BIAS = 0, EP_BF32 = 1, EP_RELU = 2, EP_LN = 3, EP_LNRES = 4, EP_MERGE = 5, EP_PART = 6, EP_F16 = 7;

template<int AMODE, int EPI>
__global__ __launch_bounds__(256)
void gemm_bf16(const short* __restrict__ A1, const short* __restrict__ A2,
               const unsigned long long* __restrict__ tab,
               const short* __restrict__ Wt, int M, int Kd, int kstr, int K1,
               const float* __restrict__ bias, int bstride,
               const float* __restrict__ lns, const float* __restrict__ lnb,
               const short* __restrict__ resid,
               const float* __restrict__ ccp, const float* __restrict__ pep,
               short* __restrict__ outb, float* __restrict__ outf, int ldc,
               long wstride, long ostride) {
  __shared__ __align__(16) short As[128 * 64];
  __shared__ __align__(16) short Bs[128 * 64];
  __shared__ float rsum[2][128], rsq[2][128];
  int tid = threadIdx.x, lane = tid & 63, wid = tid >> 6;
  int wr = wid >> 1, wc = wid & 1;
  int nwg = gridDim.x;
  int orig = blockIdx.x;
  int qd = nwg >> 3, rm = nwg & 7;
  int xcd = orig & 7, offx = orig >> 3;
  int bx = (xcd < rm ? xcd * (qd + 1) : rm * (qd + 1) + (xcd - rm) * qd) + offx;
  int rb = bx * 128;
  int by = blockIdx.y;
  int koff = blockIdx.z * Kd;
  const short* Wsel = Wt + (size_t)by * wstride;
  const float* bsel = bias ? bias + (size_t)by * bstride : nullptr;
  short* osel_b = outb ? outb + (size_t)by * ostride : nullptr;
  float* osel_f = outf ? outf + (size_t)by * ostride : nullptr;

  f32x4v acc[4][4];
  #pragma unroll
  for (int i = 0; i < 4; ++i)
    #pragma unroll
    for (int j = 0; j < 4; ++j) acc[i][j] = (f32x4v){0.f, 0.f, 0.f, 0.f};

  for (int k0 = 0; k0 < Kd; k0 += 64) {
    #pragma unroll
    for (int q = 0; q < 4; ++q) {
      int i = (wid * 4 + q) * 64 + lane;
      int r = i >> 3, pch = i & 7;
      int c = pch ^ (r & 7);
      const short* src;
      if (AMODE == AM_LIN) {
        src = A1 + (size_t)(rb + r) * kstr + koff + k0 + c * 8;
      } else if (AMODE == AM_DUAL) {
        if (k0 < K1) src = A1 + (size_t)(rb + r) * K1 + k0 + c * 8;
        else         src = A2 + (size_t)(rb + r) * (Kd - K1) + (k0 - K1) + c * 8;
      } else if (AMODE == AM_CEN) {
        int rg = rb + r;
        if (k0 < K1) src = A1 + (size_t)((rg / 25) * 25 + 12) * K1 + k0 + c * 8;
        else         src = A2 + (size_t)rg * (Kd - K1) + (k0 - K1) + c * 8;
      } else {
        src = (const short*)(uintptr_t)tab[rb + r] + k0 + c * 8;
      }
      gl_lds16(src, &As[(size_t)i * 8]);
    }
    #pragma unroll
    for (int q = 0; q < 4; ++q) {
      int i = (wid * 4 + q) * 64 + lane;
      int r = i >> 3, pch = i & 7;
      int c = pch ^ (r & 7);
      gl_lds16(Wsel + (size_t)r * kstr + koff + k0 + c * 8, &Bs[(size_t)i * 8]);
    }
    __syncthreads();
    #pragma unroll
    for (int kk = 0; kk < 2; ++kk) {
      bf16x8v af[4], bfr[4];
      #pragma unroll
      for (int mi = 0; mi < 4; ++mi) {
        int r = wr * 64 + mi * 16 + (lane & 15);
        int c = kk * 4 + (lane >> 4);
        int pch = c ^ (r & 7);
        af[mi] = *(const bf16x8v*)&As[r * 64 + pch * 8];
      }
      #pragma unroll
      for (int ni = 0; ni < 4; ++ni) {
        int r = wc * 64 + ni * 16 + (lane & 15);
        int c = kk * 4 + (lane >> 4);
        int pch = c ^ (r & 7);
        bfr[ni] = *(const bf16x8v*)&Bs[r * 64 + pch * 8];
      }
      #pragma unroll
      for (int mi = 0; mi < 4; ++mi)
        #pragma unroll
        for (int ni = 0; ni < 4; ++ni)
          acc[mi][ni] = __builtin_amdgcn_mfma_f32_16x16x32_bf16(af[mi], bfr[ni], acc[mi][ni], 0, 0, 0);
    }
    __syncthreads();
  }

  // ---- epilogue ----
  int colloc[4];
  #pragma unroll
  for (int ni = 0; ni < 4; ++ni) colloc[ni] = wc * 64 + ni * 16 + (lane & 15);
  float bv[4];
  #pragma unroll
  for (int ni = 0; ni < 4; ++ni)
    bv[ni] = (EPI == EP_MERGE || EPI == EP_PART) ? 0.f : (bsel ? bsel[colloc[ni]] : 0.f);

  #pragma unroll
  for (int mi = 0; mi < 4; ++mi)
    #pragma unroll
    for (int ni = 0; ni < 4; ++ni)
      #pragma unroll
      for (int q = 0; q < 4; ++q) {
        float v = acc[mi][ni][q] + bv[ni];
        if (EPI == EP_RELU) v = fmaxf(v, 0.f);
        acc[mi][ni][q] = v;
      }

  if (EPI == EP_LN || EPI == EP_LNRES) {
    #pragma unroll
    for (int mi = 0; mi < 4; ++mi)
      #pragma unroll
      for (int q = 0; q < 4; ++q) {
        float s = 0.f, ss = 0.f;
        #pragma unroll
        for (int ni = 0; ni < 4; ++ni) { float v = acc[mi][ni][q]; s += v; ss += v * v; }
        s += __shfl_xor(s, 1, 64); ss += __shfl_xor(ss, 1, 64);
        s += __shfl_xor(s, 2, 64); ss += __shfl_xor(ss, 2, 64);
        s += __shfl_xor(s, 4, 64); ss += __shfl_xor(ss, 4, 64);
        s += __shfl_xor(s, 8, 64); ss += __shfl_xor(ss, 8, 64);
        int rl = wr * 64 + mi * 16 + (lane >> 4) * 4 + q;
        if ((lane & 15) == 0) { rsum[wc][rl] = s; rsq[wc][rl] = ss; }
      }
    __syncthreads();
  }

  #pragma unroll
  for (int mi = 0; mi < 4; ++mi)
    #pragma unroll
    for (int q = 0; q < 4; ++q) {
      int rl = wr * 64 + mi * 16 + (lane >> 4) * 4 + q;
      long rg = rb + rl;
      float mean = 0.f, rstd = 0.f;
      if (EPI == EP_LN || EPI == EP_LNRES) {
        float s = rsum[0][rl] + rsum[1][rl];
        float ss = rsq[0][rl] + rsq[1][rl];
        mean = s * (1.f / 128.f);
        float var = ss * (1.f / 128.f) - mean * mean;
        rstd = 1.f / sqrtf(var + 1e-5f);
      }
      int wv_ = 0, tv_ = 0;
      if (EPI == EP_MERGE) { wv_ = (int)(rg / 25); tv_ = (int)(rg - (long)wv_ * 25); }
      #pragma unroll
      for (int ni = 0; ni < 4; ++ni) {
        int cg = colloc[ni];
        float v = acc[mi][ni][q];
        if (EPI == EP_MERGE) v += ccp[(size_t)wv_ * 128 + cg] + pep[tv_ * 128 + cg];
        if (EPI == EP_LN || EPI == EP_LNRES) {
          v = (v - mean) * rstd * lns[cg] + lnb[cg];
          if (EPI == EP_LNRES) v += b2f(resid[(size_t)rg * 128 + cg]);
        }
        if (EPI == EP_BF32) osel_f[(size_t)rg * ldc + cg] = v;
        else if (EPI == EP_PART) osel_f[((size_t)blockIdx.z * M + rg) * ldc + cg] = v;
        else if (EPI == EP_F16) osel_b[(size_t)rg * ldc + cg] = f2h(v);
        else osel_b[(size_t)rg * ldc + cg] = f2b(v);
      }
    }
}

__global__ void reduce_part(const float* __restrict__ part, const float* __restrict__ bias,
                            short* __restrict__ out) {
  int i = blockIdx.x * blockDim.x + threadIdx.x;
  if (i >= 4608 * 128) return;
  int c = i & 127;
  float s = bias[c];
  #pragma unroll
  for (int z = 0; z < 5; ++z) s += part[(size_t)z * 4608 * 128 + i];
  out[i] = f2b(s);
}

// ---------------- fused QKV v2: A staged once, FULL 128x128 B tile per weight ----------------
// Fat phases (r15->r16 measured-positive transform): per weight w, one 32KB B stage ->
// sync -> 64-MFMA region -> sync. Syncs per block 13 -> 7. MFMA K-order identical
// (cg = kt*8+kk*4 == kk2*4) -> bit-identical numerics. Both tiles (r&15) orbit.
// LDS 32+32 = 64 KB (2 blocks/CU is the cap regardless, per r13-r20).

template<bool CROSS>
__global__ __launch_bounds__(256)
void qkv_fused(const short* __restrict__ xq, const short* __restrict__ xkv,
               const short* __restrict__ wqkv, short* __restrict__ out, long ostride) {
  __shared__ __align__(16) short As[128 * 128];   // 32 KB (full K=128)
  __shared__ __align__(16) short Bs[128 * 128];   // 32 KB (full K=128)
  int tid = threadIdx.x, lane = tid & 63, wid = tid >> 6;
  int wr = wid >> 1, wc = wid & 1;
  int nwg = gridDim.x;
  int orig = blockIdx.x;
  int qd = nwg >> 3, rm = nwg & 7;
  int xcd = orig & 7, offx = orig >> 3;
  int bx = (xcd < rm ? xcd * (qd + 1) : rm * (qd + 1) + (xcd - rm) * qd) + offx;
  int rb = bx * 128;

  auto stageA = [&](const short* src) {
    #pragma unroll
    for (int q = 0; q < 8; ++q) {
      int i = (wid * 8 + q) * 64 + lane;
      int r = i >> 4, pch = i & 15;
      int c = pch ^ (r & 15);
      gl_lds16(src + (size_t)(rb + r) * 128 + c * 8, &As[(size_t)i * 8]);
    }
  };
  auto stageB = [&](const short* src) {
    #pragma unroll
    for (int q = 0; q < 8; ++q) {
      int i = (wid * 8 + q) * 64 + lane;
      int r = i >> 4, pch = i & 15;
      int c = pch ^ (r & 15);
      gl_lds16(src + (size_t)r * 128 + c * 8, &Bs[(size_t)i * 8]);
    }
  };
  stageA(xq);

  #pragma unroll
  for (int w = 0; w < 3; ++w) {
    if (CROSS && w == 1) stageA(xkv);
    f32x4v acc[4][4];
    #pragma unroll
    for (int i = 0; i < 4; ++i)
      #pragma unroll
      for (int j = 0; j < 4; ++j) acc[i][j] = (f32x4v){0.f, 0.f, 0.f, 0.f};
    stageB(wqkv + (size_t)w * 16384);
    __syncthreads();
    #pragma unroll
    for (int kk = 0; kk < 4; ++kk) {
      bf16x8v af[4], bfr[4];
      #pragma unroll
      for (int mi = 0; mi < 4; ++mi) {
        int r = wr * 64 + mi * 16 + (lane & 15);
        int cg = kk * 4 + (lane >> 4);
        int pch = cg ^ (r & 15);
        af[mi] = *(const bf16x8v*)&As[r * 128 + pch * 8];
      }
      #pragma unroll
      for (int ni = 0; ni < 4; ++ni) {
        int r = wc * 64 + ni * 16 + (lane & 15);
        int cg = kk * 4 + (lane >> 4);
        int pch = cg ^ (r & 15);
        bfr[ni] = *(const bf16x8v*)&Bs[r * 128 + pch * 8];
      }
      #pragma unroll
      for (int mi = 0; mi < 4; ++mi)
        #pragma unroll
        for (int ni = 0; ni < 4; ++ni)
          acc[mi][ni] = __builtin_amdgcn_mfma_f32_16x16x32_bf16(af[mi], bfr[ni], acc[mi][ni], 0, 0, 0);
    }
    // C-write (registers only) before the trailing sync
    short* ow = out + (size_t)w * ostride;
    #pragma unroll
    for (int mi = 0; mi < 4; ++mi)
      #pragma unroll
      for (int q = 0; q < 4; ++q) {
        int rl = wr * 64 + mi * 16 + (lane >> 4) * 4 + q;
        long rg = rb + rl;
        #pragma unroll
        for (int ni = 0; ni < 4; ++ni) {
          int cg = wc * 64 + ni * 16 + (lane & 15);
          ow[(size_t)rg * 128 + cg] = f2h(acc[mi][ni][q]);
        }
      }
    __syncthreads();   // retire As/Bs reads before next w's restage
  }
}

// ---------------- fully fused block tail v2 (r17 best): fat phases, (r&15) XOR ----------------
// msg = LN(attnout@wm); h = relu([x,msg]@m1+b1); out = LN(h@m2+b2)+x.
// LDS: 16(AsHs) + 32(Bs) + 16(Ms) = 64 KB (2 blocks/CU pinned).

__global__ __launch_bounds__(256)
void mlp2_fused(const short* __restrict__ x, const short* __restrict__ attnout,
                const short* __restrict__ wmT,
                const short* __restrict__ m1wT, const short* __restrict__ m2wT,
                const float* __restrict__ n1s, const float* __restrict__ n1b,
                const float* __restrict__ b1, const float* __restrict__ b2,
                const float* __restrict__ lns, const float* __restrict__ lnb,
                short* __restrict__ out) {
  __shared__ __align__(16) short AsHs[64 * 128];  // 16 KB: A staging | Hs | LN scratch
  __shared__ __align__(16) short Bs[128 * 128];   // 32 KB: full-K weight tile
  __shared__ __align__(16) short Ms[64 * 128];    // 16 KB
  short* As = AsHs;
  short* Hs = AsHs;
  float* rsum = (float*)AsHs;          // [2][64], live only when staging region dead
  float* rsq  = (float*)AsHs + 128;
  int tid = threadIdx.x, lane = tid & 63, wid = tid >> 6;
  int wr = wid >> 1, wc = wid & 1;
  int nwg = gridDim.x;
  int orig = blockIdx.x;
  int qd = nwg >> 3, rm = nwg & 7;
  int xcd = orig & 7, offx = orig >> 3;
  int bx = (xcd < rm ? xcd * (qd + 1) : rm * (qd + 1) + (xcd - rm) * qd) + offx;
  int rb = bx * 64;

  int colloc[4];
  #pragma unroll
  for (int ni = 0; ni < 4; ++ni) colloc[ni] = wc * 64 + ni * 16 + (lane & 15);

  // stage 64x128 A tile (full K), 1024 slots, 4/thread
  auto stageA = [&](const short* src) {
    #pragma unroll
    for (int q = 0; q < 4; ++q) {
      int i = (wid * 4 + q) * 64 + lane;
      int r = i >> 4, pch = i & 15;
      int c = pch ^ (r & 15);
      gl_lds16(src + (size_t)(rb + r) * 128 + c * 8, &As[(size_t)i * 8]);
    }
  };
  // stage 128x128 B tile, 2048 slots, 8/thread
  auto stageB = [&](const short* src, int kstr) {
    #pragma unroll
    for (int q = 0; q < 8; ++q) {
      int i = (wid * 8 + q) * 64 + lane;
      int r = i >> 4, pch = i & 15;
      int c = pch ^ (r & 15);
      gl_lds16(src + (size_t)r * kstr + c * 8, &Bs[(size_t)i * 8]);
    }
  };
  // 32-MFMA region: C[64x128] += A64x128 @ B128x128^T (A from any 64x128 swizzled tile)
  auto mfmaAB = [&](const short* Atile, f32x4v (*acc)[4]) {
    #pragma unroll
    for (int kk = 0; kk < 4; ++kk) {
      bf16x8v af[2], bfr[4];
      #pragma unroll
      for (int mi = 0; mi < 2; ++mi) {
        int r = wr * 32 + mi * 16 + (lane & 15);
        int c = kk * 4 + (lane >> 4);
        int pch = c ^ (r & 15);
        af[mi] = *(const bf16x8v*)&Atile[r * 128 + pch * 8];
      }
      #pragma unroll
      for (int ni = 0; ni < 4; ++ni) {
        int r = wc * 64 + ni * 16 + (lane & 15);
        int c = kk * 4 + (lane >> 4);
        int pch = c ^ (r & 15);
        bfr[ni] = *(const bf16x8v*)&Bs[r * 128 + pch * 8];
      }
      #pragma unroll
      for (int mi = 0; mi < 2; ++mi)
        #pragma unroll
        for (int ni = 0; ni < 4; ++ni)
          acc[mi][ni] = __builtin_amdgcn_mfma_f32_16x16x32_bf16(af[mi], bfr[ni], acc[mi][ni], 0, 0, 0);
    }
  };

  // ---- phase 0: msg = LN(attnout @ wm) -> Ms ----
  {
    f32x4v acc0[2][4];
    #pragma unroll
    for (int i = 0; i < 2; ++i)
      #pragma unroll
      for (int j = 0; j < 4; ++j) acc0[i][j] = (f32x4v){0.f, 0.f, 0.f, 0.f};
    stageA(attnout);
    stageB(wmT, 128);
    __syncthreads();
    mfmaAB(As, acc0);
    __syncthreads();
    // LN stats (rsum aliases dead attnout staging)
    #pragma unroll
    for (int mi = 0; mi < 2; ++mi)
      #pragma unroll
      for (int q = 0; q < 4; ++q) {
        float s = 0.f, ss = 0.f;
        #pragma unroll
        for (int ni = 0; ni < 4; ++ni) { float v = acc0[mi][ni][q]; s += v; ss += v * v; }
        s += __shfl_xor(s, 1, 64); ss += __shfl_xor(ss, 1, 64);
        s += __shfl_xor(s, 2, 64); ss += __shfl_xor(ss, 2, 64);
        s += __shfl_xor(s, 4, 64); ss += __shfl_xor(ss, 4, 64);
        s += __shfl_xor(s, 8, 64); ss += __shfl_xor(ss, 8, 64);
        int rl = wr * 32 + mi * 16 + (lane >> 4) * 4 + q;
        if ((lane & 15) == 0) { rsum[wc * 64 + rl] = s; rsq[wc * 64 + rl] = ss; }
      }
    __syncthreads();
    #pragma unroll
    for (int mi = 0; mi < 2; ++mi)
      #pragma unroll
      for (int q = 0; q < 4; ++q) {
        int rl = wr * 32 + mi * 16 + (lane >> 4) * 4 + q;
        float s = rsum[rl] + rsum[64 + rl];
        float ss = rsq[rl] + rsq[64 + rl];
        float mean = s * (1.f / 128.f);
        float var = ss * (1.f / 128.f) - mean * mean;
        float rstd = 1.f / sqrtf(var + 1e-5f);
        #pragma unroll
        for (int ni = 0; ni < 4; ++ni) {
          int cg = colloc[ni];
          float v = (acc0[mi][ni][q] - mean) * rstd * n1s[cg] + n1b[cg];
          int c = cg >> 3, pch = c ^ (rl & 15);
          Ms[rl * 128 + pch * 8 + (cg & 7)] = f2b(v);
        }
      }
    __syncthreads();
  }

  // ---- phases 1&2: MLP on [x | Ms] ----
  f32x4v acc2[2][4];
  #pragma unroll
  for (int i = 0; i < 2; ++i)
    #pragma unroll
    for (int j = 0; j < 4; ++j) acc2[i][j] = (f32x4v){0.f, 0.f, 0.f, 0.f};

  #pragma unroll
  for (int nh = 0; nh < 2; ++nh) {
    f32x4v acc1[2][4];
    #pragma unroll
    for (int i = 0; i < 2; ++i)
      #pragma unroll
      for (int j = 0; j < 4; ++j) acc1[i][j] = (f32x4v){0.f, 0.f, 0.f, 0.f};

    // pair 1: A = x (K 0..127), B = m1[nh rows][K 0..127]
    stageA(x);
    stageB(m1wT + (size_t)(nh * 128) * 256, 256);
    __syncthreads();
    mfmaAB(As, acc1);
    __syncthreads();
    // pair 2: A = Ms (msg, K 128..255), B = m1[nh rows][K 128..255]
    stageB(m1wT + (size_t)(nh * 128) * 256 + 128, 256);
    __syncthreads();
    mfmaAB(Ms, acc1);
    __syncthreads();
    // bias + relu -> Hs (aliases As; x dead since pair-1 MFMA)
    #pragma unroll
    for (int mi = 0; mi < 2; ++mi)
      #pragma unroll
      for (int q = 0; q < 4; ++q) {
        int rl = wr * 32 + mi * 16 + (lane >> 4) * 4 + q;
        #pragma unroll
        for (int ni = 0; ni < 4; ++ni) {
          int cg = wc * 64 + ni * 16 + (lane & 15);
          float v = fmaxf(acc1[mi][ni][q] + b1[nh * 128 + cg], 0.f);
          int c = cg >> 3, pch = c ^ (rl & 15);
          Hs[rl * 128 + pch * 8 + (cg & 7)] = f2b(v);
        }
      }
    __syncthreads();
    // phase 2: acc2 += h_half @ m2[nh K-slice]
    stageB(m2wT + nh * 128, 256);
    __syncthreads();
    mfmaAB(Hs, acc2);
    __syncthreads();
  }

  // ---- epilogue: m2 bias + LN(n2) + residual(x) (rsum aliases dead Hs) ----
  #pragma unroll
  for (int mi = 0; mi < 2; ++mi)
    #pragma unroll
    for (int ni = 0; ni < 4; ++ni)
      #pragma unroll
      for (int q = 0; q < 4; ++q)
        acc2[mi][ni][q] += b2[colloc[ni]];

  #pragma unroll
  for (int mi = 0; mi < 2; ++mi)
    #pragma unroll
    for (int q = 0; q < 4; ++q) {
      float s = 0.f, ss = 0.f;
      #pragma unroll
      for (int ni = 0; ni < 4; ++ni) { float v = acc2[mi][ni][q]; s += v; ss += v * v; }
      s += __shfl_xor(s, 1, 64); ss += __shfl_xor(ss, 1, 64);
      s += __shfl_xor(s, 2, 64); ss += __shfl_xor(ss, 2, 64);
      s += __shfl_xor(s, 4, 64); ss += __shfl_xor(ss, 4, 64);
      s += __shfl_xor(s, 8, 64); ss += __shfl_xor(ss, 8, 64);
      int rl = wr * 32 + mi * 16 + (lane >> 4) * 4 + q;
      if ((lane & 15) == 0) { rsum[wc * 64 + rl] = s; rsq[wc * 64 + rl] = ss; }
    }
  __syncthreads();

  #pragma unroll
  for (int mi = 0; mi < 2; ++mi)
    #pragma unroll
    for (int q = 0; q < 4; ++q) {
      int rl = wr * 32 + mi * 16 + (lane >> 4) * 4 + q;
      long rg = rb + rl;
      float s = rsum[rl] + rsum[64 + rl];
      float ss = rsq[rl] + rsq[64 + rl];
      float mean = s * (1.f / 128.f);
      float var = ss * (1.f / 128.f) - mean * mean;
      float rstd = 1.f / sqrtf(var + 1e-5f);
      #pragma unroll
      for (int ni = 0; ni < 4; ++ni) {
        int cg = colloc[ni];
        float v = (acc2[mi][ni][q] - mean) * rstd * lns[cg] + lnb[cg];
        v += b2f(x[(size_t)rg * 128 + cg]);
        out[(size_t)rg * 128 + cg] = f2b(v);
      }
    }
}

// ---------------- windowed attention v3: raw f16 LDS, fdot2 QK, pk_fma PV ----------------

__global__ __launch_bounds__(256) void attn_win(const short* __restrict__ Q,
                                                const short* __restrict__ K,
                                                const short* __restrict__ V,
                                                short* __restrict__ Mo) {
  int w = blockIdx.x;
  const short* Qg = Q + (size_t)w * 3200;
  const short* Kg = K + (size_t)w * 3200;
  const short* Vg = V + (size_t)w * 3200;
  __shared__ short Qs[25 * 136 + 8], Ks[25 * 136 + 8], Vs[25 * 136 + 8];
  int tid = threadIdx.x;
  for (int s = tid; s < 400; s += 256) {
    int r = s >> 4, ch = s & 15;
    *(int4*)&Qs[r * 136 + ch * 8] = ((const int4*)Qg)[s];
    *(int4*)&Ks[r * 136 + ch * 8] = ((const int4*)Kg)[s];
    *(int4*)&Vs[r * 136 + ch * 8] = ((const int4*)Vg)[s];
  }
  __syncthreads();

  int wid = tid >> 6, lane = tid & 63;
  int half = lane >> 5, li = lane & 31;
  int h = wid * 2 + half;
  if (li < 25) {
    int i = li;
    h2 qr[8];
    #pragma unroll
    for (int t = 0; t < 8; ++t) qr[t] = *(const h2*)&Qs[i * 136 + h * 16 + t * 2];
    float p[25];
    float mx = -1e30f;
    #pragma unroll
    for (int jx = 0; jx < 25; ++jx) {
      const short* kr = &Ks[jx * 136 + h * 16];
      float s = 0.f;
      #pragma unroll
      for (int t = 0; t < 8; ++t)
        s = __builtin_amdgcn_fdot2(qr[t], *(const h2*)&kr[t * 2], s, false);
      s *= 0.25f;
      p[jx] = s;
      mx = fmaxf(mx, s);
    }
    float sum = 0.f;
    #pragma unroll
    for (int jx = 0; jx < 25; ++jx) { float e = expf(p[jx] - mx); p[jx] = e; sum += e; }
    float inv = 1.f / sum;
    h2 o2[8];
    #pragma unroll
    for (int t = 0; t < 8; ++t) { o2[t][0] = (_Float16)0.f; o2[t][1] = (_Float16)0.f; }
    #pragma unroll
    for (int jx = 0; jx < 25; ++jx) {
      _Float16 ph = (_Float16)(p[jx] * inv);
      h2 pv; pv[0] = ph; pv[1] = ph;
      const short* vr = &Vs[jx * 136 + h * 16];
      #pragma unroll
      for (int t = 0; t < 8; ++t) o2[t] += pv * (*(const h2*)&vr[t * 2]);
    }
    int* outp = (int*)(Mo + (size_t)w * 3200 + i * 128 + h * 16);
    #pragma unroll
    for (int t = 0; t < 8; ++t) {
      unsigned lo = (unsigned short)f2b((float)o2[t][0]);
      unsigned hi = (unsigned short)f2b((float)o2[t][1]);
      outp[t] = (int)(lo | (hi << 16));
    }
  }
}

// ---------------- final regression + mask ----------------

__global__ void final_reg(const short* __restrict__ fv, const float* __restrict__ regw,
                          const float* __restrict__ regb, const int* __restrict__ J,
                          const int* __restrict__ CB, float* __restrict__ out) {
  int n = blockIdx.x * blockDim.x + threadIdx.x;
  if (n >= 4608) return;
  const short* f = fv + (size_t)n * 128;
  float c0 = regb[0], c1 = regb[1];
  for (int d = 0; d < 128; ++d) { float v = b2f(f[d]); c0 += v * regw[d * 2]; c1 += v * regw[d * 2 + 1]; }
  int jv = J[n]; int bb = n / 2304;
  int msk = (CB[bb * 2304 + jv] == (n - bb * 2304)) ? 1 : 0;
  float bx = (float)((jv % 48) * 8), by = (float)((jv / 48) * 8);
  out[n * 2] = msk ? (bx + c0) : 0.f;
  out[n * 2 + 1] = msk ? (by + c1) : 0.f;
}

// ---------------- host ----------------

extern "C" void kernel_launch(void* const* d_in, const int* in_sizes, int n_in,
                              void* d_out, int out_size, void* d_ws, size_t ws_size,
                              hipStream_t stream) {
  const float* md0 = (const float*)d_in[0];
  const float* md1 = (const float*)d_in[1];
  const float* fine0 = (const float*)d_in[2];
  const float* fine1 = (const float*)d_in[3];
  const float* conv_w = (const float*)d_in[4];
  const float* conv_b = (const float*)d_in[5];
  const float* proj_w = (const float*)d_in[6];
  const float* proj_b = (const float*)d_in[7];
  const float* merge_w = (const float*)d_in[8];
  const float* merge_b = (const float*)d_in[9];
  const float* reg1_w = (const float*)d_in[10];
  const float* reg1_b = (const float*)d_in[11];
  const float* reg2_w = (const float*)d_in[12];
  const float* reg2_b = (const float*)d_in[13];
  const float* reg_w = (const float*)d_in[14];
  const float* reg_b = (const float*)d_in[15];
  const float* wq_f = (const float*)d_in[16];
  const float* wk_f = (const float*)d_in[17];
  const float* wv_f = (const float*)d_in[18];
  const float* wm_f = (const float*)d_in[19];
  const float* m1w = (const float*)d_in[20];
  const float* m1b = (const float*)d_in[21];
  const float* m2w = (const float*)d_in[22];
  const float* m2b = (const float*)d_in[23];
  const float* n1s = (const float*)d_in[24];
  const float* n1b = (const float*)d_in[25];
  const float* n2s = (const float*)d_in[26];
  const float* n2b = (const float*)d_in[27];

  char* ws = (char*)d_ws;
  const size_t SZX = (size_t)230400 * 128 * 2;
  const size_t TAILSZ = 20 * 1024 * 1024;
  int CHM = 57600;
  if (SZX + 3ull * 230400 * 256 + TAILSZ <= ws_size)      CHM = 230400;
  else if (SZX + 3ull * 115200 * 256 + TAILSZ <= ws_size) CHM = 115200;
  const size_t CHR = (size_t)CHM * 256;

  short* X  = (short*)(ws);
  char*  Rb = ws + SZX;
  short* R0 = (short*)(Rb);
  short* R1 = (short*)(Rb + CHR);
  short* R2 = (short*)(Rb + 2 * CHR);
  float* S    = (float*)Rb;
  short* F0C  = (short*)Rb;
  short* F1C  = (short*)(Rb + (size_t)73728 * 128 * 2);
  short* FT   = X;
  short* FB   = (short*)Rb;
  float* PART = (float*)(Rb + 2 * CHR);

  char* p = ws + SZX + 3 * CHR;
  double* lnR = (double*)p; p += 4608 * 8;
  double* lnC = (double*)p; p += 4608 * 8;
  int* J = (int*)p; p += 4608 * 4;
  int* CBst = (int*)p; p += 4608 * 4;
  double* PSUM = (double*)p; p += (size_t)2 * 12 * 2304 * 8;
  double* PKEY = (double*)p; p += (size_t)2 * 12 * 2304 * 8;
  int* PIDX = (int*)p; p += (size_t)2 * 12 * 2304 * 4;
  short* CBUF = (short*)p; p += (size_t)9216 * 256 * 2;
  short* CEN = (short*)p; p += (size_t)9216 * 128 * 2;
  float* CC = (float*)p; p += (size_t)9216 * 128 * 4;
  unsigned long long* TAB = (unsigned long long*)p; p += (size_t)230400 * 8;
  float* PE = (float*)p; p += 3200 * 4;
  short* ZP = (short*)p; p += 256;
  short* convT = (short*)p; p += 128 * 256 * 2;
  short* projT = (short*)p; p += 128 * 256 * 2;
  short* mergeAT = (short*)p; p += 128 * 128 * 2;
  short* mergeBT = (short*)p; p += 128 * 128 * 2;
  short* reg1T = (short*)p; p += 128 * 256 * 2;
  short* reg2T = (short*)p; p += (size_t)128 * 3200 * 2;
  short* wqkvT = (short*)p; p += (size_t)4 * 3 * 128 * 128 * 2;
  short* wmT = (short*)p; p += 4 * 128 * 128 * 2;
  short* m1T = (short*)p; p += 4 * 256 * 256 * 2;
  short* m2T = (short*)p; p += (size_t)4 * 128 * 256 * 2;
  short* FV = (short*)p; p += (size_t)4608 * 128 * 2;

  const int TQ = 115200;

  prep_all<<<512, 256, 0, stream>>>(conv_w, proj_w, merge_w, reg1_w, reg2_w,
                                    wq_f, wk_f, wv_f, wm_f, m1w, m2w,
                                    convT, projT, mergeAT, mergeBT, reg1T, reg2T,
                                    wqkvT, wmT, m1T, m2T, PE, ZP);

  // matching
  sim_gemm<<<dim3(24, 24, 2), 256, 0, stream>>>(md0, md1, S);
  row_lse<<<4608, 256, 0, stream>>>(S, lnR);
  col_part<<<dim3(36, 12, 2), 256, 0, stream>>>(S, lnR, PSUM, PKEY, PIDX);
  col_reduce<<<18, 256, 0, stream>>>(PSUM, PKEY, PIDX, lnC, CBst);
  row_argmax<<<4608, 256, 0, stream>>>(S, lnC, J);

  auto gemm = [&](auto amode, auto epi, const short* A1, const short* A2,
                  const unsigned long long* tab, const short* Wt, int M, int Kd, int kstr, int K1,
                  const float* bias, int bstride, const float* lns, const float* lnb,
                  const short* resid, const float* cc, const float* pe,
                  short* outb, float* outf, int ldc, int NB, int NZ, long wstride, long ostride) {
    constexpr int AM = decltype(amode)::value, EP = decltype(epi)::value;
    gemm_bf16<AM, EP><<<dim3(M / 128, NB, NZ), 256, 0, stream>>>(
        A1, A2, tab, Wt, M, Kd, kstr, K1, bias, bstride, lns, lnb, resid, cc, pe,
        outb, outf, ldc, wstride, ostride);
  };
  using I0 = std::integral_constant<int, 0>; using I1 = std::integral_constant<int, 1>;
  using I2 = std::integral_constant<int, 2>; using I3 = std::integral_constant<int, 3>;
  using E0 = std::integral_constant<int, 0>; using E1 = std::integral_constant<int, 1>;
  using E5 = std::integral_constant<int, 5>; using E6 = std::integral_constant<int, 6>;

  // fine conv
  transpose_fine<<<dim3(576, 4, 2), 256, 0, stream>>>(fine0, FT);
  gemm(I0{}, E0{}, FT, nullptr, nullptr, convT, 73728, 256, 256, 0, conv_b, 0, nullptr, nullptr, nullptr, nullptr, nullptr, F0C, nullptr, 128, 1, 1, 0, 0);
  transpose_fine<<<dim3(576, 4, 2), 256, 0, stream>>>(fine1, FT);
  gemm(I0{}, E0{}, FT, nullptr, nullptr, convT, 73728, 256, 256, 0, conv_b, 0, nullptr, nullptr, nullptr, nullptr, nullptr, F1C, nullptr, 128, 1, 1, 0, 0);

  // center path + merge
  cgather<<<4608, 256, 0, stream>>>(md0, md1, J, CBUF);
  gemm(I0{}, E0{}, CBUF, nullptr, nullptr, projT, 9216, 256, 256, 0, proj_b, 0, nullptr, nullptr, nullptr, nullptr, nullptr, CEN, nullptr, 128, 1, 1, 0, 0);
  gemm(I0{}, E1{}, CEN, nullptr, nullptr, mergeBT, 9216, 128, 128, 0, merge_b, 0, nullptr, nullptr, nullptr, nullptr, nullptr, nullptr, CC, 128, 1, 1, 0, 0);
  build_tab<<<900, 256, 0, stream>>>(J, F0C, F1C, ZP, TAB);
  gemm(I2{}, E5{}, nullptr, nullptr, TAB, mergeAT, 230400, 128, 128, 0, nullptr, 0, nullptr, nullptr, nullptr, CC, PE, X, nullptr, 128, 1, 1, 0, 0);

  // transformer
  auto pass = [&](int i, const short* xq, const short* xkv, short* xout, int Mtotal, bool cross) {
    const short* wqkv = wqkvT + (size_t)i * 3 * 16384;
    const short* wm = wmT + i * 16384;
    const short* m1 = m1T + i * 65536;
    const short* m2 = m2T + i * 32768;
    for (int off = 0; off < Mtotal; off += CHM) {
      int Mc = (Mtotal - off < CHM) ? (Mtotal - off) : CHM;
      const short* xqc = xq + (size_t)off * 128;
      const short* xkvc = xkv + (size_t)off * 128;
      if (cross)
        qkv_fused<true><<<Mc / 128, 256, 0, stream>>>(xqc, xkvc, wqkv, R0, (long)CHM * 128);
      else
        qkv_fused<false><<<Mc / 128, 256, 0, stream>>>(xqc, xkvc, wqkv, R0, (long)CHM * 128);
      attn_win<<<Mc / 25, 256, 0, stream>>>(R0, R1, R2, R0);
      mlp2_fused<<<Mc / 64, 256, 0, stream>>>(xqc, R0, wm, m1, m2,
                                              n1s + i * 128, n1b + i * 128,
                                              m1b + i * 256, m2b + i * 128,
                                              n2s + i * 128, n2b + i * 128,
                                              xout + (size_t)off * 128);
    }
  };
  short* X1 = X + (size_t)TQ * 128;
  for (int i = 0; i < 4; ++i) {
    if ((i & 1) == 0) {
      pass(i, X, X, X, 230400, false);
    } else {
      pass(i, X, X1, X, TQ, true);
      pass(i, X1, X, X1, TQ, true);
    }
  }

  // regression head
  gemm(I3{}, E0{}, X, X1, nullptr, reg1T, TQ, 256, 256, 128, reg1_b, 0, nullptr, nullptr, nullptr, nullptr, nullptr, FB, nullptr, 128, 1, 1, 0, 0);
  gemm(I0{}, E6{}, FB, nullptr, nullptr, reg2T, 4608, 640, 3200, 0, nullptr, 0, nullptr, nullptr, nullptr, nullptr, nullptr, nullptr, PART, 128, 1, 5, 0, 0);
  reduce_part<<<2304, 256, 0, stream>>>(PART, reg2_b, FV);
  final_reg<<<18, 256, 0, stream>>>(FV, reg_w, reg_b, J, CBst, (float*)d_out);
}

// Round 22
// 1467.285 us; speedup vs baseline: 1.1936x; 1.0030x over previous
//
#include <hip/hip_runtime.h>
#include <stdint.h>
#include <type_traits>

#define DEVFN static __device__ __forceinline__

typedef __attribute__((ext_vector_type(8))) short bf16x8v;
typedef __attribute__((ext_vector_type(4))) float f32x4v;
typedef __attribute__((ext_vector_type(2))) _Float16 h2;

DEVFN float b2f(short s) {
  union { unsigned u; float f; } c; c.u = ((unsigned)(unsigned short)s) << 16; return c.f;
}
DEVFN short f2b(float f) {
  union { float f; unsigned u; } c; c.f = f;
  unsigned r = c.u + 0x7fffu + ((c.u >> 16) & 1u);
  return (short)(r >> 16);
}
DEVFN short f2h(float f) {
  union { _Float16 h; short s; } c; c.h = (_Float16)f; return c.s;
}
DEVFN void gl_lds16(const void* g, void* l) {
  __builtin_amdgcn_global_load_lds((const __attribute__((address_space(1))) void*)g,
                                   (__attribute__((address_space(3))) void*)l, 16, 0, 0);
}
// exp(x) for |x| < ~0.02 (sim scores): 5-term Taylor in f64.
DEVFN double exp_small(double x) {
  return 1.0 + x * (1.0 + x * (0.5 + x * ((1.0 / 6.0) + x * (1.0 / 24.0))));
}

// ---------------- one-shot prep kernel ----------------

__global__ void prep_all(const float* __restrict__ conv_w, const float* __restrict__ proj_w,
                         const float* __restrict__ merge_w, const float* __restrict__ reg1_w,
                         const float* __restrict__ reg2_w, const float* __restrict__ wq,
                         const float* __restrict__ wk, const float* __restrict__ wv,
                         const float* __restrict__ wm, const float* __restrict__ m1w,
                         const float* __restrict__ m2w,
                         short* __restrict__ convT, short* __restrict__ projT,
                         short* __restrict__ mergeAT, short* __restrict__ mergeBT,
                         short* __restrict__ reg1T, short* __restrict__ reg2T,
                         short* __restrict__ wqkvT, short* __restrict__ wmT,
                         short* __restrict__ m1T, short* __restrict__ m2T,
                         float* __restrict__ pe, short* __restrict__ zp) {
  const int L0 = 32768, L1 = 32768, L2 = 16384, L3 = 16384, L4 = 32768, L5 = 409600;
  const int L6 = 196608, L7 = 65536, L8 = 262144, L9 = 131072, L10 = 3200, L11 = 128;
  const int TOT = L0+L1+L2+L3+L4+L5+L6+L7+L8+L9+L10+L11;
  for (int gi = blockIdx.x * blockDim.x + threadIdx.x; gi < TOT; gi += gridDim.x * blockDim.x) {
    int i = gi;
    if (i < L0) { convT[i] = f2b(conv_w[i]); continue; } i -= L0;
    if (i < L1) { int n = i >> 8, k = i & 255; projT[i] = f2b(proj_w[k * 128 + n]); continue; } i -= L1;
    if (i < L2) { int n = i >> 7, k = i & 127; mergeAT[i] = f2b(merge_w[k * 128 + n]); continue; } i -= L2;
    if (i < L3) { int n = i >> 7, k = i & 127; mergeBT[i] = f2b(merge_w[(128 + k) * 128 + n]); continue; } i -= L3;
    if (i < L4) { int n = i >> 8, k = i & 255; reg1T[i] = f2b(reg1_w[k * 128 + n]); continue; } i -= L4;
    if (i < L5) { int n = i / 3200, k = i - n * 3200; reg2T[i] = f2b(reg2_w[k * 128 + n]); continue; } i -= L5;
    if (i < L6) {
      int l = i / 49152; int r = i - l * 49152; int w = r / 16384; int r2 = r - w * 16384;
      int n = r2 >> 7, k = r2 & 127;
      const float* s = (w == 0) ? wq : (w == 1) ? wk : wv;
      wqkvT[i] = f2b(s[l * 16384 + k * 128 + n]); continue;
    } i -= L6;
    if (i < L7) { int l = i >> 14; int r = i & 16383; int n = r >> 7, k = r & 127;
      wmT[i] = f2b(wm[l * 16384 + k * 128 + n]); continue; } i -= L7;
    if (i < L8) { int l = i >> 16; int r = i & 65535; int n = r >> 8, k = r & 255;
      m1T[i] = f2b(m1w[l * 65536 + k * 256 + n]); continue; } i -= L8;
    if (i < L9) { int l = i >> 15; int r = i & 32767; int n = r >> 8, k = r & 255;
      m2T[i] = f2b(m2w[l * 32768 + k * 128 + n]); continue; } i -= L9;
    if (i < L10) {
      int t = i >> 7, d = i & 127; int i2 = d >> 1;
      float div = expf(((float)(2 * i2)) * (-logf(10000.f) / 128.f));
      float ang = (float)t * div;
      pe[i] = (d & 1) ? cosf(ang) : sinf(ang); continue;
    } i -= L10;
    zp[i] = 0;
  }
}

// ---------------- matching (f32/f64, precision-critical) ----------------

__global__ __launch_bounds__(256) void sim_gemm(const float* __restrict__ A,
                                                const float* __restrict__ Bm,
                                                float* __restrict__ S) {
  int b = blockIdx.z;
  A += (size_t)b * 2304 * 256; Bm += (size_t)b * 2304 * 256; S += (size_t)b * 2304 * 2304;
  __shared__ float As[96][33], Bs[96][33];
  int tid = threadIdx.x;
  int tx = tid & 15, ty = tid >> 4;
  int rb = blockIdx.x * 96, cb = blockIdx.y * 96;
  float acc[6][6] = {};
  for (int k0 = 0; k0 < 256; k0 += 32) {
    #pragma unroll
    for (int s = 0; s < 3; ++s) {
      int slot = s * 256 + tid;
      int r = slot >> 3, cq = slot & 7;
      float4 va = *(const float4*)&A[(size_t)(rb + r) * 256 + k0 + 4 * cq];
      float4 vb = *(const float4*)&Bm[(size_t)(cb + r) * 256 + k0 + 4 * cq];
      As[r][4 * cq] = va.x; As[r][4 * cq + 1] = va.y; As[r][4 * cq + 2] = va.z; As[r][4 * cq + 3] = va.w;
      Bs[r][4 * cq] = vb.x; Bs[r][4 * cq + 1] = vb.y; Bs[r][4 * cq + 2] = vb.z; Bs[r][4 * cq + 3] = vb.w;
    }
    __syncthreads();
    #pragma unroll 4
    for (int k = 0; k < 32; ++k) {
      float av[6], bv[6];
      #pragma unroll
      for (int i = 0; i < 6; ++i) av[i] = As[ty + 16 * i][k];
      #pragma unroll
      for (int j = 0; j < 6; ++j) bv[j] = Bs[tx + 16 * j][k];
      #pragma unroll
      for (int i = 0; i < 6; ++i)
        #pragma unroll
        for (int j = 0; j < 6; ++j) acc[i][j] += av[i] * bv[j];
    }
    __syncthreads();
  }
  #pragma unroll
  for (int i = 0; i < 6; ++i)
    #pragma unroll
    for (int j = 0; j < 6; ++j) {
      float t = acc[i][j] * (1.0f / 65536.0f);
      S[(size_t)(rb + ty + 16 * i) * 2304 + cb + tx + 16 * j] = t / 0.1f;
    }
}

__global__ __launch_bounds__(256) void row_lse(const float* __restrict__ S, double* __restrict__ lnR) {
  int row = blockIdx.x;
  const float* Sp = S + (size_t)row * 2304;
  double a = 0;
  for (int m = threadIdx.x; m < 2304; m += 256) a += exp_small((double)Sp[m]);
  __shared__ double red[256];
  red[threadIdx.x] = a; __syncthreads();
  for (int s = 128; s > 0; s >>= 1) { if (threadIdx.x < (unsigned)s) red[threadIdx.x] += red[threadIdx.x + s]; __syncthreads(); }
  if (!threadIdx.x) lnR[row] = log(red[0]);
}

__global__ __launch_bounds__(256) void col_part(const float* __restrict__ S,
                                                const double* __restrict__ lnR,
                                                double* __restrict__ psum,
                                                double* __restrict__ pkey,
                                                int* __restrict__ pidx) {
  int bb = blockIdx.z;
  int c0 = blockIdx.x * 64;
  int rc = blockIdx.y;
  int col = c0 + (threadIdx.x & 63);
  int g = threadIdx.x >> 6;
  const float* Sp = S + (size_t)bb * 2304 * 2304;
  const double* lr = lnR + bb * 2304;
  double a = 0, best = -1e300; int bi = 1 << 30;
  int l0 = rc * 192;
  for (int t = g; t < 192; t += 4) {
    int l = l0 + t;
    double sv = (double)Sp[(size_t)l * 2304 + col];
    a += exp_small(sv);
    double k = 2.0 * sv - lr[l];
    if (k > best || (k == best && l < bi)) { best = k; bi = l; }
  }
  __shared__ double s_sum[256]; __shared__ double s_key[256]; __shared__ int s_idx[256];
  s_sum[threadIdx.x] = a; s_key[threadIdx.x] = best; s_idx[threadIdx.x] = bi;
  __syncthreads();
  if (g == 0) {
    double ts = a; double tk = best; int ti = bi;
    #pragma unroll
    for (int gg = 1; gg < 4; ++gg) {
      int o = threadIdx.x + gg * 64;
      ts += s_sum[o];
      if (s_key[o] > tk || (s_key[o] == tk && s_idx[o] < ti)) { tk = s_key[o]; ti = s_idx[o]; }
    }
    size_t off = ((size_t)bb * 12 + rc) * 2304 + col;
    psum[off] = ts; pkey[off] = tk; pidx[off] = ti;
  }
}

__global__ void col_reduce(const double* __restrict__ psum, const double* __restrict__ pkey,
                           const int* __restrict__ pidx, double* __restrict__ lnC,
                           int* __restrict__ CB) {
  int i = blockIdx.x * blockDim.x + threadIdx.x;
  if (i >= 4608) return;
  int bb = i / 2304, col = i - bb * 2304;
  double s = 0; double bk = -1e300; int bi = 1 << 30;
  for (int rc = 0; rc < 12; ++rc) {
    size_t off = ((size_t)bb * 12 + rc) * 2304 + col;
    s += psum[off];
    double k = pkey[off]; int ix = pidx[off];
    if (k > bk || (k == bk && ix < bi)) { bk = k; bi = ix; }
  }
  lnC[i] = log(s);
  CB[i] = bi;
}

__global__ __launch_bounds__(256) void row_argmax(const float* __restrict__ S,
                                                  const double* __restrict__ lnC,
                                                  int* __restrict__ J) {
  int row = blockIdx.x; int bb = row / 2304;
  const float* Sp = S + (size_t)row * 2304;
  const double* lc = lnC + bb * 2304;
  double best = -1e300; int bi = 1 << 30;
  for (int m = threadIdx.x; m < 2304; m += 256) {
    double k = 2.0 * (double)Sp[m] - lc[m];
    if (k > best || (k == best && m < bi)) { best = k; bi = m; }
  }
  __shared__ double bvs[256]; __shared__ int bis[256];
  bvs[threadIdx.x] = best; bis[threadIdx.x] = bi; __syncthreads();
  for (int s = 128; s > 0; s >>= 1) {
    if (threadIdx.x < (unsigned)s) {
      double ov = bvs[threadIdx.x + s]; int oi = bis[threadIdx.x + s];
      if (ov > bvs[threadIdx.x] || (ov == bvs[threadIdx.x] && oi < bis[threadIdx.x])) { bvs[threadIdx.x] = ov; bis[threadIdx.x] = oi; }
    }
    __syncthreads();
  }
  if (!threadIdx.x) J[row] = bis[0];
}

// ---------------- fine-feature path ----------------

__global__ __launch_bounds__(256) void transpose_fine(const float* __restrict__ src, short* __restrict__ dst) {
  __shared__ float t[64][65];
  int bb = blockIdx.z, p0 = blockIdx.x * 64, c0 = blockIdx.y * 64;
  for (int i = threadIdx.x; i < 1024; i += 256) {
    int cl = i >> 4, pl = (i & 15) * 4;
    float4 v = *(const float4*)&src[((size_t)(bb * 256 + c0 + cl)) * 36864 + p0 + pl];
    t[cl][pl] = v.x; t[cl][pl + 1] = v.y; t[cl][pl + 2] = v.z; t[cl][pl + 3] = v.w;
  }
  __syncthreads();
  for (int i = threadIdx.x; i < 1024; i += 256) {
    int pl = i >> 4, cg = (i & 15) * 4;
    unsigned w0 = (unsigned short)f2b(t[cg][pl]) | ((unsigned)(unsigned short)f2b(t[cg + 1][pl]) << 16);
    unsigned w1 = (unsigned short)f2b(t[cg + 2][pl]) | ((unsigned)(unsigned short)f2b(t[cg + 3][pl]) << 16);
    int2 v; v.x = (int)w0; v.y = (int)w1;
    *(int2*)&dst[((size_t)(bb * 36864 + p0 + pl)) * 256 + c0 + cg] = v;
  }
}

__global__ void cgather(const float* __restrict__ md0, const float* __restrict__ md1,
                        const int* __restrict__ J, short* __restrict__ cbuf) {
  int total = 9216 * 256;
  for (int i = blockIdx.x * blockDim.x + threadIdx.x; i < total; i += gridDim.x * blockDim.x) {
    int w = i >> 8, c = i & 255;
    const float* src;
    if (w < 4608) src = md0 + (size_t)w * 256;
    else {
      int n = w - 4608; int bb = n / 2304;
      src = md1 + (size_t)(bb * 2304 + J[n]) * 256;
    }
    cbuf[i] = f2b(src[c]);
  }
}

__global__ void build_tab(const int* __restrict__ J, const short* __restrict__ f0c,
                          const short* __restrict__ f1c, const short* __restrict__ zp,
                          unsigned long long* __restrict__ tab) {
  int total = 230400;
  for (int i = blockIdx.x * blockDim.x + threadIdx.x; i < total; i += gridDim.x * blockDim.x) {
    int w = i / 25, t = i - w * 25;
    int bb, cell; const short* fc;
    if (w < 4608) { bb = w / 2304; cell = w - bb * 2304; fc = f0c; }
    else { int n = w - 4608; bb = n / 2304; cell = J[n]; fc = f1c; }
    int cy = cell / 48, cx = cell - cy * 48;
    int y = cy * 4 - 2 + t / 5, x = cx * 4 - 2 + t % 5;
    const short* p = (y >= 0 && y < 192 && x >= 0 && x < 192)
                   ? fc + (size_t)((bb * 192 + y) * 192 + x) * 128 : zp;
    tab[i] = (unsigned long long)(uintptr_t)p;
  }
}

// ---------------- the bf16 MFMA GEMM workhorse (BK=64, 34KB LDS) ----------------

constexpr int AM_LIN = 0, AM_DUAL = 1, AM_TAB = 2, AM_CEN = 3;
constexpr int EP_BIAS = 0, EP_BF32 = 1, EP_RELU = 2, EP_LN = 3, EP_LNRES = 4, EP_MERGE = 5, EP_PART = 6, EP_F16 = 7;

template<int AMODE, int EPI>
__global__ __launch_bounds__(256)
void gemm_bf16(const short* __restrict__ A1, const short* __restrict__ A2,
               const unsigned long long* __restrict__ tab,
               const short* __restrict__ Wt, int M, int Kd, int kstr, int K1,
               const float* __restrict__ bias, int bstride,
               const float* __restrict__ lns, const float* __restrict__ lnb,
               const short* __restrict__ resid,
               const float* __restrict__ ccp, const float* __restrict__ pep,
               short* __restrict__ outb, float* __restrict__ outf, int ldc,
               long wstride, long ostride) {
  __shared__ __align__(16) short As[128 * 64];
  __shared__ __align__(16) short Bs[128 * 64];
  __shared__ float rsum[2][128], rsq[2][128];
  int tid = threadIdx.x, lane = tid & 63, wid = tid >> 6;
  int wr = wid >> 1, wc = wid & 1;
  int nwg = gridDim.x;
  int orig = blockIdx.x;
  int qd = nwg >> 3, rm = nwg & 7;
  int xcd = orig & 7, offx = orig >> 3;
  int bx = (xcd < rm ? xcd * (qd + 1) : rm * (qd + 1) + (xcd - rm) * qd) + offx;
  int rb = bx * 128;
  int by = blockIdx.y;
  int koff = blockIdx.z * Kd;
  const short* Wsel = Wt + (size_t)by * wstride;
  const float* bsel = bias ? bias + (size_t)by * bstride : nullptr;
  short* osel_b = outb ? outb + (size_t)by * ostride : nullptr;
  float* osel_f = outf ? outf + (size_t)by * ostride : nullptr;

  f32x4v acc[4][4];
  #pragma unroll
  for (int i = 0; i < 4; ++i)
    #pragma unroll
    for (int j = 0; j < 4; ++j) acc[i][j] = (f32x4v){0.f, 0.f, 0.f, 0.f};

  for (int k0 = 0; k0 < Kd; k0 += 64) {
    #pragma unroll
    for (int q = 0; q < 4; ++q) {
      int i = (wid * 4 + q) * 64 + lane;
      int r = i >> 3, pch = i & 7;
      int c = pch ^ (r & 7);
      const short* src;
      if (AMODE == AM_LIN) {
        src = A1 + (size_t)(rb + r) * kstr + koff + k0 + c * 8;
      } else if (AMODE == AM_DUAL) {
        if (k0 < K1) src = A1 + (size_t)(rb + r) * K1 + k0 + c * 8;
        else         src = A2 + (size_t)(rb + r) * (Kd - K1) + (k0 - K1) + c * 8;
      } else if (AMODE == AM_CEN) {
        int rg = rb + r;
        if (k0 < K1) src = A1 + (size_t)((rg / 25) * 25 + 12) * K1 + k0 + c * 8;
        else         src = A2 + (size_t)rg * (Kd - K1) + (k0 - K1) + c * 8;
      } else {
        src = (const short*)(uintptr_t)tab[rb + r] + k0 + c * 8;
      }
      gl_lds16(src, &As[(size_t)i * 8]);
    }
    #pragma unroll
    for (int q = 0; q < 4; ++q) {
      int i = (wid * 4 + q) * 64 + lane;
      int r = i >> 3, pch = i & 7;
      int c = pch ^ (r & 7);
      gl_lds16(Wsel + (size_t)r * kstr + koff + k0 + c * 8, &Bs[(size_t)i * 8]);
    }
    __syncthreads();
    #pragma unroll
    for (int kk = 0; kk < 2; ++kk) {
      bf16x8v af[4], bfr[4];
      #pragma unroll
      for (int mi = 0; mi < 4; ++mi) {
        int r = wr * 64 + mi * 16 + (lane & 15);
        int c = kk * 4 + (lane >> 4);
        int pch = c ^ (r & 7);
        af[mi] = *(const bf16x8v*)&As[r * 64 + pch * 8];
      }
      #pragma unroll
      for (int ni = 0; ni < 4; ++ni) {
        int r = wc * 64 + ni * 16 + (lane & 15);
        int c = kk * 4 + (lane >> 4);
        int pch = c ^ (r & 7);
        bfr[ni] = *(const bf16x8v*)&Bs[r * 64 + pch * 8];
      }
      #pragma unroll
      for (int mi = 0; mi < 4; ++mi)
        #pragma unroll
        for (int ni = 0; ni < 4; ++ni)
          acc[mi][ni] = __builtin_amdgcn_mfma_f32_16x16x32_bf16(af[mi], bfr[ni], acc[mi][ni], 0, 0, 0);
    }
    __syncthreads();
  }

  // ---- epilogue ----
  int colloc[4];
  #pragma unroll
  for (int ni = 0; ni < 4; ++ni) colloc[ni] = wc * 64 + ni * 16 + (lane & 15);
  float bv[4];
  #pragma unroll
  for (int ni = 0; ni < 4; ++ni)
    bv[ni] = (EPI == EP_MERGE || EPI == EP_PART) ? 0.f : (bsel ? bsel[colloc[ni]] : 0.f);

  #pragma unroll
  for (int mi = 0; mi < 4; ++mi)
    #pragma unroll
    for (int ni = 0; ni < 4; ++ni)
      #pragma unroll
      for (int q = 0; q < 4; ++q) {
        float v = acc[mi][ni][q] + bv[ni];
        if (EPI == EP_RELU) v = fmaxf(v, 0.f);
        acc[mi][ni][q] = v;
      }

  if (EPI == EP_LN || EPI == EP_LNRES) {
    #pragma unroll
    for (int mi = 0; mi < 4; ++mi)
      #pragma unroll
      for (int q = 0; q < 4; ++q) {
        float s = 0.f, ss = 0.f;
        #pragma unroll
        for (int ni = 0; ni < 4; ++ni) { float v = acc[mi][ni][q]; s += v; ss += v * v; }
        s += __shfl_xor(s, 1, 64); ss += __shfl_xor(ss, 1, 64);
        s += __shfl_xor(s, 2, 64); ss += __shfl_xor(ss, 2, 64);
        s += __shfl_xor(s, 4, 64); ss += __shfl_xor(ss, 4, 64);
        s += __shfl_xor(s, 8, 64); ss += __shfl_xor(ss, 8, 64);
        int rl = wr * 64 + mi * 16 + (lane >> 4) * 4 + q;
        if ((lane & 15) == 0) { rsum[wc][rl] = s; rsq[wc][rl] = ss; }
      }
    __syncthreads();
  }

  #pragma unroll
  for (int mi = 0; mi < 4; ++mi)
    #pragma unroll
    for (int q = 0; q < 4; ++q) {
      int rl = wr * 64 + mi * 16 + (lane >> 4) * 4 + q;
      long rg = rb + rl;
      float mean = 0.f, rstd = 0.f;
      if (EPI == EP_LN || EPI == EP_LNRES) {
        float s = rsum[0][rl] + rsum[1][rl];
        float ss = rsq[0][rl] + rsq[1][rl];
        mean = s * (1.f / 128.f);
        float var = ss * (1.f / 128.f) - mean * mean;
        rstd = 1.f / sqrtf(var + 1e-5f);
      }
      int wv_ = 0, tv_ = 0;
      if (EPI == EP_MERGE) { wv_ = (int)(rg / 25); tv_ = (int)(rg - (long)wv_ * 25); }
      #pragma unroll
      for (int ni = 0; ni < 4; ++ni) {
        int cg = colloc[ni];
        float v = acc[mi][ni][q];
        if (EPI == EP_MERGE) v += ccp[(size_t)wv_ * 128 + cg] + pep[tv_ * 128 + cg];
        if (EPI == EP_LN || EPI == EP_LNRES) {
          v = (v - mean) * rstd * lns[cg] + lnb[cg];
          if (EPI == EP_LNRES) v += b2f(resid[(size_t)rg * 128 + cg]);
        }
        if (EPI == EP_BF32) osel_f[(size_t)rg * ldc + cg] = v;
        else if (EPI == EP_PART) osel_f[((size_t)blockIdx.z * M + rg) * ldc + cg] = v;
        else if (EPI == EP_F16) osel_b[(size_t)rg * ldc + cg] = f2h(v);
        else osel_b[(size_t)rg * ldc + cg] = f2b(v);
      }
    }
}

__global__ void reduce_part(const float* __restrict__ part, const float* __restrict__ bias,
                            short* __restrict__ out) {
  int i = blockIdx.x * blockDim.x + threadIdx.x;
  if (i >= 4608 * 128) return;
  int c = i & 127;
  float s = bias[c];
  #pragma unroll
  for (int z = 0; z < 5; ++z) s += part[(size_t)z * 4608 * 128 + i];
  out[i] = f2b(s);
}

// ---------------- fused QKV v2: A staged once, FULL 128x128 B tile per weight ----------------
// __launch_bounds__(256,3): register-cap hypothesis — force <=~170 unified VGPR+AGPR
// so 3 blocks/CU fit (r13-r21: occupancy pinned at 2 blocks regardless of LDS; 120 VGPR
// + 64 AGPR = 184 = exactly 2 waves/SIMD).

template<bool CROSS>
__global__ __launch_bounds__(256, 3)
void qkv_fused(const short* __restrict__ xq, const short* __restrict__ xkv,
               const short* __restrict__ wqkv, short* __restrict__ out, long ostride) {
  __shared__ __align__(16) short As[128 * 128];   // 32 KB (full K=128)
  __shared__ __align__(16) short Bs[128 * 128];   // 32 KB (full K=128)
  int tid = threadIdx.x, lane = tid & 63, wid = tid >> 6;
  int wr = wid >> 1, wc = wid & 1;
  int nwg = gridDim.x;
  int orig = blockIdx.x;
  int qd = nwg >> 3, rm = nwg & 7;
  int xcd = orig & 7, offx = orig >> 3;
  int bx = (xcd < rm ? xcd * (qd + 1) : rm * (qd + 1) + (xcd - rm) * qd) + offx;
  int rb = bx * 128;

  auto stageA = [&](const short* src) {
    #pragma unroll
    for (int q = 0; q < 8; ++q) {
      int i = (wid * 8 + q) * 64 + lane;
      int r = i >> 4, pch = i & 15;
      int c = pch ^ (r & 15);
      gl_lds16(src + (size_t)(rb + r) * 128 + c * 8, &As[(size_t)i * 8]);
    }
  };
  auto stageB = [&](const short* src) {
    #pragma unroll
    for (int q = 0; q < 8; ++q) {
      int i = (wid * 8 + q) * 64 + lane;
      int r = i >> 4, pch = i & 15;
      int c = pch ^ (r & 15);
      gl_lds16(src + (size_t)r * 128 + c * 8, &Bs[(size_t)i * 8]);
    }
  };
  stageA(xq);

  #pragma unroll
  for (int w = 0; w < 3; ++w) {
    if (CROSS && w == 1) stageA(xkv);
    f32x4v acc[4][4];
    #pragma unroll
    for (int i = 0; i < 4; ++i)
      #pragma unroll
      for (int j = 0; j < 4; ++j) acc[i][j] = (f32x4v){0.f, 0.f, 0.f, 0.f};
    stageB(wqkv + (size_t)w * 16384);
    __syncthreads();
    #pragma unroll
    for (int kk = 0; kk < 4; ++kk) {
      bf16x8v af[4], bfr[4];
      #pragma unroll
      for (int mi = 0; mi < 4; ++mi) {
        int r = wr * 64 + mi * 16 + (lane & 15);
        int cg = kk * 4 + (lane >> 4);
        int pch = cg ^ (r & 15);
        af[mi] = *(const bf16x8v*)&As[r * 128 + pch * 8];
      }
      #pragma unroll
      for (int ni = 0; ni < 4; ++ni) {
        int r = wc * 64 + ni * 16 + (lane & 15);
        int cg = kk * 4 + (lane >> 4);
        int pch = cg ^ (r & 15);
        bfr[ni] = *(const bf16x8v*)&Bs[r * 128 + pch * 8];
      }
      #pragma unroll
      for (int mi = 0; mi < 4; ++mi)
        #pragma unroll
        for (int ni = 0; ni < 4; ++ni)
          acc[mi][ni] = __builtin_amdgcn_mfma_f32_16x16x32_bf16(af[mi], bfr[ni], acc[mi][ni], 0, 0, 0);
    }
    // C-write (registers only) before the trailing sync
    short* ow = out + (size_t)w * ostride;
    #pragma unroll
    for (int mi = 0; mi < 4; ++mi)
      #pragma unroll
      for (int q = 0; q < 4; ++q) {
        int rl = wr * 64 + mi * 16 + (lane >> 4) * 4 + q;
        long rg = rb + rl;
        #pragma unroll
        for (int ni = 0; ni < 4; ++ni) {
          int cg = wc * 64 + ni * 16 + (lane & 15);
          ow[(size_t)rg * 128 + cg] = f2h(acc[mi][ni][q]);
        }
      }
    __syncthreads();   // retire As/Bs reads before next w's restage
  }
}

// ---------------- fully fused block tail v2 (r17 best) + launch_bounds(256,3) ----------------
// msg = LN(attnout@wm); h = relu([x,msg]@m1+b1); out = LN(h@m2+b2)+x.
// LDS: 16(AsHs) + 32(Bs) + 16(Ms) = 64 KB. Register-cap test: force 3 blocks/CU.

__global__ __launch_bounds__(256, 3)
void mlp2_fused(const short* __restrict__ x, const short* __restrict__ attnout,
                const short* __restrict__ wmT,
                const short* __restrict__ m1wT, const short* __restrict__ m2wT,
                const float* __restrict__ n1s, const float* __restrict__ n1b,
                const float* __restrict__ b1, const float* __restrict__ b2,
                const float* __restrict__ lns, const float* __restrict__ lnb,
                short* __restrict__ out) {
  __shared__ __align__(16) short AsHs[64 * 128];  // 16 KB: A staging | Hs | LN scratch
  __shared__ __align__(16) short Bs[128 * 128];   // 32 KB: full-K weight tile
  __shared__ __align__(16) short Ms[64 * 128];    // 16 KB
  short* As = AsHs;
  short* Hs = AsHs;
  float* rsum = (float*)AsHs;          // [2][64], live only when staging region dead
  float* rsq  = (float*)AsHs + 128;
  int tid = threadIdx.x, lane = tid & 63, wid = tid >> 6;
  int wr = wid >> 1, wc = wid & 1;
  int nwg = gridDim.x;
  int orig = blockIdx.x;
  int qd = nwg >> 3, rm = nwg & 7;
  int xcd = orig & 7, offx = orig >> 3;
  int bx = (xcd < rm ? xcd * (qd + 1) : rm * (qd + 1) + (xcd - rm) * qd) + offx;
  int rb = bx * 64;

  int colloc[4];
  #pragma unroll
  for (int ni = 0; ni < 4; ++ni) colloc[ni] = wc * 64 + ni * 16 + (lane & 15);

  // stage 64x128 A tile (full K), 1024 slots, 4/thread
  auto stageA = [&](const short* src) {
    #pragma unroll
    for (int q = 0; q < 4; ++q) {
      int i = (wid * 4 + q) * 64 + lane;
      int r = i >> 4, pch = i & 15;
      int c = pch ^ (r & 15);
      gl_lds16(src + (size_t)(rb + r) * 128 + c * 8, &As[(size_t)i * 8]);
    }
  };
  // stage 128x128 B tile, 2048 slots, 8/thread
  auto stageB = [&](const short* src, int kstr) {
    #pragma unroll
    for (int q = 0; q < 8; ++q) {
      int i = (wid * 8 + q) * 64 + lane;
      int r = i >> 4, pch = i & 15;
      int c = pch ^ (r & 15);
      gl_lds16(src + (size_t)r * kstr + c * 8, &Bs[(size_t)i * 8]);
    }
  };
  // 32-MFMA region: C[64x128] += A64x128 @ B128x128^T (A from any 64x128 swizzled tile)
  auto mfmaAB = [&](const short* Atile, f32x4v (*acc)[4]) {
    #pragma unroll
    for (int kk = 0; kk < 4; ++kk) {
      bf16x8v af[2], bfr[4];
      #pragma unroll
      for (int mi = 0; mi < 2; ++mi) {
        int r = wr * 32 + mi * 16 + (lane & 15);
        int c = kk * 4 + (lane >> 4);
        int pch = c ^ (r & 15);
        af[mi] = *(const bf16x8v*)&Atile[r * 128 + pch * 8];
      }
      #pragma unroll
      for (int ni = 0; ni < 4; ++ni) {
        int r = wc * 64 + ni * 16 + (lane & 15);
        int c = kk * 4 + (lane >> 4);
        int pch = c ^ (r & 15);
        bfr[ni] = *(const bf16x8v*)&Bs[r * 128 + pch * 8];
      }
      #pragma unroll
      for (int mi = 0; mi < 2; ++mi)
        #pragma unroll
        for (int ni = 0; ni < 4; ++ni)
          acc[mi][ni] = __builtin_amdgcn_mfma_f32_16x16x32_bf16(af[mi], bfr[ni], acc[mi][ni], 0, 0, 0);
    }
  };

  // ---- phase 0: msg = LN(attnout @ wm) -> Ms ----
  {
    f32x4v acc0[2][4];
    #pragma unroll
    for (int i = 0; i < 2; ++i)
      #pragma unroll
      for (int j = 0; j < 4; ++j) acc0[i][j] = (f32x4v){0.f, 0.f, 0.f, 0.f};
    stageA(attnout);
    stageB(wmT, 128);
    __syncthreads();
    mfmaAB(As, acc0);
    __syncthreads();
    // LN stats (rsum aliases dead attnout staging)
    #pragma unroll
    for (int mi = 0; mi < 2; ++mi)
      #pragma unroll
      for (int q = 0; q < 4; ++q) {
        float s = 0.f, ss = 0.f;
        #pragma unroll
        for (int ni = 0; ni < 4; ++ni) { float v = acc0[mi][ni][q]; s += v; ss += v * v; }
        s += __shfl_xor(s, 1, 64); ss += __shfl_xor(ss, 1, 64);
        s += __shfl_xor(s, 2, 64); ss += __shfl_xor(ss, 2, 64);
        s += __shfl_xor(s, 4, 64); ss += __shfl_xor(ss, 4, 64);
        s += __shfl_xor(s, 8, 64); ss += __shfl_xor(ss, 8, 64);
        int rl = wr * 32 + mi * 16 + (lane >> 4) * 4 + q;
        if ((lane & 15) == 0) { rsum[wc * 64 + rl] = s; rsq[wc * 64 + rl] = ss; }
      }
    __syncthreads();
    #pragma unroll
    for (int mi = 0; mi < 2; ++mi)
      #pragma unroll
      for (int q = 0; q < 4; ++q) {
        int rl = wr * 32 + mi * 16 + (lane >> 4) * 4 + q;
        float s = rsum[rl] + rsum[64 + rl];
        float ss = rsq[rl] + rsq[64 + rl];
        float mean = s * (1.f / 128.f);
        float var = ss * (1.f / 128.f) - mean * mean;
        float rstd = 1.f / sqrtf(var + 1e-5f);
        #pragma unroll
        for (int ni = 0; ni < 4; ++ni) {
          int cg = colloc[ni];
          float v = (acc0[mi][ni][q] - mean) * rstd * n1s[cg] + n1b[cg];
          int c = cg >> 3, pch = c ^ (rl & 15);
          Ms[rl * 128 + pch * 8 + (cg & 7)] = f2b(v);
        }
      }
    __syncthreads();
  }

  // ---- phases 1&2: MLP on [x | Ms] ----
  f32x4v acc2[2][4];
  #pragma unroll
  for (int i = 0; i < 2; ++i)
    #pragma unroll
    for (int j = 0; j < 4; ++j) acc2[i][j] = (f32x4v){0.f, 0.f, 0.f, 0.f};

  #pragma unroll
  for (int nh = 0; nh < 2; ++nh) {
    f32x4v acc1[2][4];
    #pragma unroll
    for (int i = 0; i < 2; ++i)
      #pragma unroll
      for (int j = 0; j < 4; ++j) acc1[i][j] = (f32x4v){0.f, 0.f, 0.f, 0.f};

    // pair 1: A = x (K 0..127), B = m1[nh rows][K 0..127]
    stageA(x);
    stageB(m1wT + (size_t)(nh * 128) * 256, 256);
    __syncthreads();
    mfmaAB(As, acc1);
    __syncthreads();
    // pair 2: A = Ms (msg, K 128..255), B = m1[nh rows][K 128..255]
    stageB(m1wT + (size_t)(nh * 128) * 256 + 128, 256);
    __syncthreads();
    mfmaAB(Ms, acc1);
    __syncthreads();
    // bias + relu -> Hs (aliases As; x dead since pair-1 MFMA)
    #pragma unroll
    for (int mi = 0; mi < 2; ++mi)
      #pragma unroll
      for (int q = 0; q < 4; ++q) {
        int rl = wr * 32 + mi * 16 + (lane >> 4) * 4 + q;
        #pragma unroll
        for (int ni = 0; ni < 4; ++ni) {
          int cg = wc * 64 + ni * 16 + (lane & 15);
          float v = fmaxf(acc1[mi][ni][q] + b1[nh * 128 + cg], 0.f);
          int c = cg >> 3, pch = c ^ (rl & 15);
          Hs[rl * 128 + pch * 8 + (cg & 7)] = f2b(v);
        }
      }
    __syncthreads();
    // phase 2: acc2 += h_half @ m2[nh K-slice]
    stageB(m2wT + nh * 128, 256);
    __syncthreads();
    mfmaAB(Hs, acc2);
    __syncthreads();
  }

  // ---- epilogue: m2 bias + LN(n2) + residual(x) (rsum aliases dead Hs) ----
  #pragma unroll
  for (int mi = 0; mi < 2; ++mi)
    #pragma unroll
    for (int ni = 0; ni < 4; ++ni)
      #pragma unroll
      for (int q = 0; q < 4; ++q)
        acc2[mi][ni][q] += b2[colloc[ni]];

  #pragma unroll
  for (int mi = 0; mi < 2; ++mi)
    #pragma unroll
    for (int q = 0; q < 4; ++q) {
      float s = 0.f, ss = 0.f;
      #pragma unroll
      for (int ni = 0; ni < 4; ++ni) { float v = acc2[mi][ni][q]; s += v; ss += v * v; }
      s += __shfl_xor(s, 1, 64); ss += __shfl_xor(ss, 1, 64);
      s += __shfl_xor(s, 2, 64); ss += __shfl_xor(ss, 2, 64);
      s += __shfl_xor(s, 4, 64); ss += __shfl_xor(ss, 4, 64);
      s += __shfl_xor(s, 8, 64); ss += __shfl_xor(ss, 8, 64);
      int rl = wr * 32 + mi * 16 + (lane >> 4) * 4 + q;
      if ((lane & 15) == 0) { rsum[wc * 64 + rl] = s; rsq[wc * 64 + rl] = ss; }
    }
  __syncthreads();

  #pragma unroll
  for (int mi = 0; mi < 2; ++mi)
    #pragma unroll
    for (int q = 0; q < 4; ++q) {
      int rl = wr * 32 + mi * 16 + (lane >> 4) * 4 + q;
      long rg = rb + rl;
      float s = rsum[rl] + rsum[64 + rl];
      float ss = rsq[rl] + rsq[64 + rl];
      float mean = s * (1.f / 128.f);
      float var = ss * (1.f / 128.f) - mean * mean;
      float rstd = 1.f / sqrtf(var + 1e-5f);
      #pragma unroll
      for (int ni = 0; ni < 4; ++ni) {
        int cg = colloc[ni];
        float v = (acc2[mi][ni][q] - mean) * rstd * lns[cg] + lnb[cg];
        v += b2f(x[(size_t)rg * 128 + cg]);
        out[(size_t)rg * 128 + cg] = f2b(v);
      }
    }
}

// ---------------- windowed attention v3: raw f16 LDS, fdot2 QK, pk_fma PV ----------------

__global__ __launch_bounds__(256) void attn_win(const short* __restrict__ Q,
                                                const short* __restrict__ K,
                                                const short* __restrict__ V,
                                                short* __restrict__ Mo) {
  int w = blockIdx.x;
  const short* Qg = Q + (size_t)w * 3200;
  const short* Kg = K + (size_t)w * 3200;
  const short* Vg = V + (size_t)w * 3200;
  __shared__ short Qs[25 * 136 + 8], Ks[25 * 136 + 8], Vs[25 * 136 + 8];
  int tid = threadIdx.x;
  for (int s = tid; s < 400; s += 256) {
    int r = s >> 4, ch = s & 15;
    *(int4*)&Qs[r * 136 + ch * 8] = ((const int4*)Qg)[s];
    *(int4*)&Ks[r * 136 + ch * 8] = ((const int4*)Kg)[s];
    *(int4*)&Vs[r * 136 + ch * 8] = ((const int4*)Vg)[s];
  }
  __syncthreads();

  int wid = tid >> 6, lane = tid & 63;
  int half = lane >> 5, li = lane & 31;
  int h = wid * 2 + half;
  if (li < 25) {
    int i = li;
    h2 qr[8];
    #pragma unroll
    for (int t = 0; t < 8; ++t) qr[t] = *(const h2*)&Qs[i * 136 + h * 16 + t * 2];
    float p[25];
    float mx = -1e30f;
    #pragma unroll
    for (int jx = 0; jx < 25; ++jx) {
      const short* kr = &Ks[jx * 136 + h * 16];
      float s = 0.f;
      #pragma unroll
      for (int t = 0; t < 8; ++t)
        s = __builtin_amdgcn_fdot2(qr[t], *(const h2*)&kr[t * 2], s, false);
      s *= 0.25f;
      p[jx] = s;
      mx = fmaxf(mx, s);
    }
    float sum = 0.f;
    #pragma unroll
    for (int jx = 0; jx < 25; ++jx) { float e = expf(p[jx] - mx); p[jx] = e; sum += e; }
    float inv = 1.f / sum;
    h2 o2[8];
    #pragma unroll
    for (int t = 0; t < 8; ++t) { o2[t][0] = (_Float16)0.f; o2[t][1] = (_Float16)0.f; }
    #pragma unroll
    for (int jx = 0; jx < 25; ++jx) {
      _Float16 ph = (_Float16)(p[jx] * inv);
      h2 pv; pv[0] = ph; pv[1] = ph;
      const short* vr = &Vs[jx * 136 + h * 16];
      #pragma unroll
      for (int t = 0; t < 8; ++t) o2[t] += pv * (*(const h2*)&vr[t * 2]);
    }
    int* outp = (int*)(Mo + (size_t)w * 3200 + i * 128 + h * 16);
    #pragma unroll
    for (int t = 0; t < 8; ++t) {
      unsigned lo = (unsigned short)f2b((float)o2[t][0]);
      unsigned hi = (unsigned short)f2b((float)o2[t][1]);
      outp[t] = (int)(lo | (hi << 16));
    }
  }
}

// ---------------- final regression + mask ----------------

__global__ void final_reg(const short* __restrict__ fv, const float* __restrict__ regw,
                          const float* __restrict__ regb, const int* __restrict__ J,
                          const int* __restrict__ CB, float* __restrict__ out) {
  int n = blockIdx.x * blockDim.x + threadIdx.x;
  if (n >= 4608) return;
  const short* f = fv + (size_t)n * 128;
  float c0 = regb[0], c1 = regb[1];
  for (int d = 0; d < 128; ++d) { float v = b2f(f[d]); c0 += v * regw[d * 2]; c1 += v * regw[d * 2 + 1]; }
  int jv = J[n]; int bb = n / 2304;
  int msk = (CB[bb * 2304 + jv] == (n - bb * 2304)) ? 1 : 0;
  float bx = (float)((jv % 48) * 8), by = (float)((jv / 48) * 8);
  out[n * 2] = msk ? (bx + c0) : 0.f;
  out[n * 2 + 1] = msk ? (by + c1) : 0.f;
}

// ---------------- host ----------------

extern "C" void kernel_launch(void* const* d_in, const int* in_sizes, int n_in,
                              void* d_out, int out_size, void* d_ws, size_t ws_size,
                              hipStream_t stream) {
  const float* md0 = (const float*)d_in[0];
  const float* md1 = (const float*)d_in[1];
  const float* fine0 = (const float*)d_in[2];
  const float* fine1 = (const float*)d_in[3];
  const float* conv_w = (const float*)d_in[4];
  const float* conv_b = (const float*)d_in[5];
  const float* proj_w = (const float*)d_in[6];
  const float* proj_b = (const float*)d_in[7];
  const float* merge_w = (const float*)d_in[8];
  const float* merge_b = (const float*)d_in[9];
  const float* reg1_w = (const float*)d_in[10];
  const float* reg1_b = (const float*)d_in[11];
  const float* reg2_w = (const float*)d_in[12];
  const float* reg2_b = (const float*)d_in[13];
  const float* reg_w = (const float*)d_in[14];
  const float* reg_b = (const float*)d_in[15];
  const float* wq_f = (const float*)d_in[16];
  const float* wk_f = (const float*)d_in[17];
  const float* wv_f = (const float*)d_in[18];
  const float* wm_f = (const float*)d_in[19];
  const float* m1w = (const float*)d_in[20];
  const float* m1b = (const float*)d_in[21];
  const float* m2w = (const float*)d_in[22];
  const float* m2b = (const float*)d_in[23];
  const float* n1s = (const float*)d_in[24];
  const float* n1b = (const float*)d_in[25];
  const float* n2s = (const float*)d_in[26];
  const float* n2b = (const float*)d_in[27];

  char* ws = (char*)d_ws;
  const size_t SZX = (size_t)230400 * 128 * 2;
  const size_t TAILSZ = 20 * 1024 * 1024;
  int CHM = 57600;
  if (SZX + 3ull * 230400 * 256 + TAILSZ <= ws_size)      CHM = 230400;
  else if (SZX + 3ull * 115200 * 256 + TAILSZ <= ws_size) CHM = 115200;
  const size_t CHR = (size_t)CHM * 256;

  short* X  = (short*)(ws);
  char*  Rb = ws + SZX;
  short* R0 = (short*)(Rb);
  short* R1 = (short*)(Rb + CHR);
  short* R2 = (short*)(Rb + 2 * CHR);
  float* S    = (float*)Rb;
  short* F0C  = (short*)Rb;
  short* F1C  = (short*)(Rb + (size_t)73728 * 128 * 2);
  short* FT   = X;
  short* FB   = (short*)Rb;
  float* PART = (float*)(Rb + 2 * CHR);

  char* p = ws + SZX + 3 * CHR;
  double* lnR = (double*)p; p += 4608 * 8;
  double* lnC = (double*)p; p += 4608 * 8;
  int* J = (int*)p; p += 4608 * 4;
  int* CBst = (int*)p; p += 4608 * 4;
  double* PSUM = (double*)p; p += (size_t)2 * 12 * 2304 * 8;
  double* PKEY = (double*)p; p += (size_t)2 * 12 * 2304 * 8;
  int* PIDX = (int*)p; p += (size_t)2 * 12 * 2304 * 4;
  short* CBUF = (short*)p; p += (size_t)9216 * 256 * 2;
  short* CEN = (short*)p; p += (size_t)9216 * 128 * 2;
  float* CC = (float*)p; p += (size_t)9216 * 128 * 4;
  unsigned long long* TAB = (unsigned long long*)p; p += (size_t)230400 * 8;
  float* PE = (float*)p; p += 3200 * 4;
  short* ZP = (short*)p; p += 256;
  short* convT = (short*)p; p += 128 * 256 * 2;
  short* projT = (short*)p; p += 128 * 256 * 2;
  short* mergeAT = (short*)p; p += 128 * 128 * 2;
  short* mergeBT = (short*)p; p += 128 * 128 * 2;
  short* reg1T = (short*)p; p += 128 * 256 * 2;
  short* reg2T = (short*)p; p += (size_t)128 * 3200 * 2;
  short* wqkvT = (short*)p; p += (size_t)4 * 3 * 128 * 128 * 2;
  short* wmT = (short*)p; p += 4 * 128 * 128 * 2;
  short* m1T = (short*)p; p += 4 * 256 * 256 * 2;
  short* m2T = (short*)p; p += (size_t)4 * 128 * 256 * 2;
  short* FV = (short*)p; p += (size_t)4608 * 128 * 2;

  const int TQ = 115200;

  prep_all<<<512, 256, 0, stream>>>(conv_w, proj_w, merge_w, reg1_w, reg2_w,
                                    wq_f, wk_f, wv_f, wm_f, m1w, m2w,
                                    convT, projT, mergeAT, mergeBT, reg1T, reg2T,
                                    wqkvT, wmT, m1T, m2T, PE, ZP);

  // matching
  sim_gemm<<<dim3(24, 24, 2), 256, 0, stream>>>(md0, md1, S);
  row_lse<<<4608, 256, 0, stream>>>(S, lnR);
  col_part<<<dim3(36, 12, 2), 256, 0, stream>>>(S, lnR, PSUM, PKEY, PIDX);
  col_reduce<<<18, 256, 0, stream>>>(PSUM, PKEY, PIDX, lnC, CBst);
  row_argmax<<<4608, 256, 0, stream>>>(S, lnC, J);

  auto gemm = [&](auto amode, auto epi, const short* A1, const short* A2,
                  const unsigned long long* tab, const short* Wt, int M, int Kd, int kstr, int K1,
                  const float* bias, int bstride, const float* lns, const float* lnb,
                  const short* resid, const float* cc, const float* pe,
                  short* outb, float* outf, int ldc, int NB, int NZ, long wstride, long ostride) {
    constexpr int AM = decltype(amode)::value, EP = decltype(epi)::value;
    gemm_bf16<AM, EP><<<dim3(M / 128, NB, NZ), 256, 0, stream>>>(
        A1, A2, tab, Wt, M, Kd, kstr, K1, bias, bstride, lns, lnb, resid, cc, pe,
        outb, outf, ldc, wstride, ostride);
  };
  using I0 = std::integral_constant<int, 0>; using I1 = std::integral_constant<int, 1>;
  using I2 = std::integral_constant<int, 2>; using I3 = std::integral_constant<int, 3>;
  using E0 = std::integral_constant<int, 0>; using E1 = std::integral_constant<int, 1>;
  using E5 = std::integral_constant<int, 5>; using E6 = std::integral_constant<int, 6>;

  // fine conv
  transpose_fine<<<dim3(576, 4, 2), 256, 0, stream>>>(fine0, FT);
  gemm(I0{}, E0{}, FT, nullptr, nullptr, convT, 73728, 256, 256, 0, conv_b, 0, nullptr, nullptr, nullptr, nullptr, nullptr, F0C, nullptr, 128, 1, 1, 0, 0);
  transpose_fine<<<dim3(576, 4, 2), 256, 0, stream>>>(fine1, FT);
  gemm(I0{}, E0{}, FT, nullptr, nullptr, convT, 73728, 256, 256, 0, conv_b, 0, nullptr, nullptr, nullptr, nullptr, nullptr, F1C, nullptr, 128, 1, 1, 0, 0);

  // center path + merge
  cgather<<<4608, 256, 0, stream>>>(md0, md1, J, CBUF);
  gemm(I0{}, E0{}, CBUF, nullptr, nullptr, projT, 9216, 256, 256, 0, proj_b, 0, nullptr, nullptr, nullptr, nullptr, nullptr, CEN, nullptr, 128, 1, 1, 0, 0);
  gemm(I0{}, E1{}, CEN, nullptr, nullptr, mergeBT, 9216, 128, 128, 0, merge_b, 0, nullptr, nullptr, nullptr, nullptr, nullptr, nullptr, CC, 128, 1, 1, 0, 0);
  build_tab<<<900, 256, 0, stream>>>(J, F0C, F1C, ZP, TAB);
  gemm(I2{}, E5{}, nullptr, nullptr, TAB, mergeAT, 230400, 128, 128, 0, nullptr, 0, nullptr, nullptr, nullptr, CC, PE, X, nullptr, 128, 1, 1, 0, 0);

  // transformer
  auto pass = [&](int i, const short* xq, const short* xkv, short* xout, int Mtotal, bool cross) {
    const short* wqkv = wqkvT + (size_t)i * 3 * 16384;
    const short* wm = wmT + i * 16384;
    const short* m1 = m1T + i * 65536;
    const short* m2 = m2T + i * 32768;
    for (int off = 0; off < Mtotal; off += CHM) {
      int Mc = (Mtotal - off < CHM) ? (Mtotal - off) : CHM;
      const short* xqc = xq + (size_t)off * 128;
      const short* xkvc = xkv + (size_t)off * 128;
      if (cross)
        qkv_fused<true><<<Mc / 128, 256, 0, stream>>>(xqc, xkvc, wqkv, R0, (long)CHM * 128);
      else
        qkv_fused<false><<<Mc / 128, 256, 0, stream>>>(xqc, xkvc, wqkv, R0, (long)CHM * 128);
      attn_win<<<Mc / 25, 256, 0, stream>>>(R0, R1, R2, R0);
      mlp2_fused<<<Mc / 64, 256, 0, stream>>>(xqc, R0, wm, m1, m2,
                                              n1s + i * 128, n1b + i * 128,
                                              m1b + i * 256, m2b + i * 128,
                                              n2s + i * 128, n2b + i * 128,
                                              xout + (size_t)off * 128);
    }
  };
  short* X1 = X + (size_t)TQ * 128;
  for (int i = 0; i < 4; ++i) {
    if ((i & 1) == 0) {
      pass(i, X, X, X, 230400, false);
    } else {
      pass(i, X, X1, X, TQ, true);
      pass(i, X1, X, X1, TQ, true);
    }
  }

  // regression head
  gemm(I3{}, E0{}, X, X1, nullptr, reg1T, TQ, 256, 256, 128, reg1_b, 0, nullptr, nullptr, nullptr, nullptr, nullptr, FB, nullptr, 128, 1, 1, 0, 0);
  gemm(I0{}, E6{}, FB, nullptr, nullptr, reg2T, 4608, 640, 3200, 0, nullptr, 0, nullptr, nullptr, nullptr, nullptr, nullptr, nullptr, PART, 128, 1, 5, 0, 0);
  reduce_part<<<2304, 256, 0, stream>>>(PART, reg2_b, FV);
  final_reg<<<18, 256, 0, stream>>>(FV, reg_w, reg_b, J, CBst, (float*)d_out);
}

// Round 23
// 1459.635 us; speedup vs baseline: 1.1999x; 1.0052x over previous
//
#include <hip/hip_runtime.h>
#include <stdint.h>
#include <type_traits>

#define DEVFN static __device__ __forceinline__

typedef __attribute__((ext_vector_type(8))) short bf16x8v;
typedef __attribute__((ext_vector_type(4))) float f32x4v;
typedef __attribute__((ext_vector_type(2))) _Float16 h2;

DEVFN float b2f(short s) {
  union { unsigned u; float f; } c; c.u = ((unsigned)(unsigned short)s) << 16; return c.f;
}
DEVFN short f2b(float f) {
  union { float f; unsigned u; } c; c.f = f;
  unsigned r = c.u + 0x7fffu + ((c.u >> 16) & 1u);
  return (short)(r >> 16);
}
DEVFN short f2h(float f) {
  union { _Float16 h; short s; } c; c.h = (_Float16)f; return c.s;
}
DEVFN void gl_lds16(const void* g, void* l) {
  __builtin_amdgcn_global_load_lds((const __attribute__((address_space(1))) void*)g,
                                   (__attribute__((address_space(3))) void*)l, 16, 0, 0);
}
// exp(x) for |x| < ~0.02 (sim scores): 5-term Taylor in f64.
DEVFN double exp_small(double x) {
  return 1.0 + x * (1.0 + x * (0.5 + x * ((1.0 / 6.0) + x * (1.0 / 24.0))));
}

// ---------------- one-shot prep kernel ----------------

__global__ void prep_all(const float* __restrict__ conv_w, const float* __restrict__ proj_w,
                         const float* __restrict__ merge_w, const float* __restrict__ reg1_w,
                         const float* __restrict__ reg2_w, const float* __restrict__ wq,
                         const float* __restrict__ wk, const float* __restrict__ wv,
                         const float* __restrict__ wm, const float* __restrict__ m1w,
                         const float* __restrict__ m2w,
                         short* __restrict__ convT, short* __restrict__ projT,
                         short* __restrict__ mergeAT, short* __restrict__ mergeBT,
                         short* __restrict__ reg1T, short* __restrict__ reg2T,
                         short* __restrict__ wqkvT, short* __restrict__ wmT,
                         short* __restrict__ m1T, short* __restrict__ m2T,
                         float* __restrict__ pe, short* __restrict__ zp) {
  const int L0 = 32768, L1 = 32768, L2 = 16384, L3 = 16384, L4 = 32768, L5 = 409600;
  const int L6 = 196608, L7 = 65536, L8 = 262144, L9 = 131072, L10 = 3200, L11 = 128;
  const int TOT = L0+L1+L2+L3+L4+L5+L6+L7+L8+L9+L10+L11;
  for (int gi = blockIdx.x * blockDim.x + threadIdx.x; gi < TOT; gi += gridDim.x * blockDim.x) {
    int i = gi;
    if (i < L0) { convT[i] = f2b(conv_w[i]); continue; } i -= L0;
    if (i < L1) { int n = i >> 8, k = i & 255; projT[i] = f2b(proj_w[k * 128 + n]); continue; } i -= L1;
    if (i < L2) { int n = i >> 7, k = i & 127; mergeAT[i] = f2b(merge_w[k * 128 + n]); continue; } i -= L2;
    if (i < L3) { int n = i >> 7, k = i & 127; mergeBT[i] = f2b(merge_w[(128 + k) * 128 + n]); continue; } i -= L3;
    if (i < L4) { int n = i >> 8, k = i & 255; reg1T[i] = f2b(reg1_w[k * 128 + n]); continue; } i -= L4;
    if (i < L5) { int n = i / 3200, k = i - n * 3200; reg2T[i] = f2b(reg2_w[k * 128 + n]); continue; } i -= L5;
    if (i < L6) {
      int l = i / 49152; int r = i - l * 49152; int w = r / 16384; int r2 = r - w * 16384;
      int n = r2 >> 7, k = r2 & 127;
      const float* s = (w == 0) ? wq : (w == 1) ? wk : wv;
      wqkvT[i] = f2b(s[l * 16384 + k * 128 + n]); continue;
    } i -= L6;
    if (i < L7) { int l = i >> 14; int r = i & 16383; int n = r >> 7, k = r & 127;
      wmT[i] = f2b(wm[l * 16384 + k * 128 + n]); continue; } i -= L7;
    if (i < L8) { int l = i >> 16; int r = i & 65535; int n = r >> 8, k = r & 255;
      m1T[i] = f2b(m1w[l * 65536 + k * 256 + n]); continue; } i -= L8;
    if (i < L9) { int l = i >> 15; int r = i & 32767; int n = r >> 8, k = r & 255;
      m2T[i] = f2b(m2w[l * 32768 + k * 128 + n]); continue; } i -= L9;
    if (i < L10) {
      int t = i >> 7, d = i & 127; int i2 = d >> 1;
      float div = expf(((float)(2 * i2)) * (-logf(10000.f) / 128.f));
      float ang = (float)t * div;
      pe[i] = (d & 1) ? cosf(ang) : sinf(ang); continue;
    } i -= L10;
    zp[i] = 0;
  }
}

// ---------------- matching (f32/f64, precision-critical) ----------------

__global__ __launch_bounds__(256) void sim_gemm(const float* __restrict__ A,
                                                const float* __restrict__ Bm,
                                                float* __restrict__ S) {
  int b = blockIdx.z;
  A += (size_t)b * 2304 * 256; Bm += (size_t)b * 2304 * 256; S += (size_t)b * 2304 * 2304;
  __shared__ float As[96][33], Bs[96][33];
  int tid = threadIdx.x;
  int tx = tid & 15, ty = tid >> 4;
  int rb = blockIdx.x * 96, cb = blockIdx.y * 96;
  float acc[6][6] = {};
  for (int k0 = 0; k0 < 256; k0 += 32) {
    #pragma unroll
    for (int s = 0; s < 3; ++s) {
      int slot = s * 256 + tid;
      int r = slot >> 3, cq = slot & 7;
      float4 va = *(const float4*)&A[(size_t)(rb + r) * 256 + k0 + 4 * cq];
      float4 vb = *(const float4*)&Bm[(size_t)(cb + r) * 256 + k0 + 4 * cq];
      As[r][4 * cq] = va.x; As[r][4 * cq + 1] = va.y; As[r][4 * cq + 2] = va.z; As[r][4 * cq + 3] = va.w;
      Bs[r][4 * cq] = vb.x; Bs[r][4 * cq + 1] = vb.y; Bs[r][4 * cq + 2] = vb.z; Bs[r][4 * cq + 3] = vb.w;
    }
    __syncthreads();
    #pragma unroll 4
    for (int k = 0; k < 32; ++k) {
      float av[6], bv[6];
      #pragma unroll
      for (int i = 0; i < 6; ++i) av[i] = As[ty + 16 * i][k];
      #pragma unroll
      for (int j = 0; j < 6; ++j) bv[j] = Bs[tx + 16 * j][k];
      #pragma unroll
      for (int i = 0; i < 6; ++i)
        #pragma unroll
        for (int j = 0; j < 6; ++j) acc[i][j] += av[i] * bv[j];
    }
    __syncthreads();
  }
  #pragma unroll
  for (int i = 0; i < 6; ++i)
    #pragma unroll
    for (int j = 0; j < 6; ++j) {
      float t = acc[i][j] * (1.0f / 65536.0f);
      S[(size_t)(rb + ty + 16 * i) * 2304 + cb + tx + 16 * j] = t / 0.1f;
    }
}

__global__ __launch_bounds__(256) void row_lse(const float* __restrict__ S, double* __restrict__ lnR) {
  int row = blockIdx.x;
  const float* Sp = S + (size_t)row * 2304;
  double a = 0;
  for (int m = threadIdx.x; m < 2304; m += 256) a += exp_small((double)Sp[m]);
  __shared__ double red[256];
  red[threadIdx.x] = a; __syncthreads();
  for (int s = 128; s > 0; s >>= 1) { if (threadIdx.x < (unsigned)s) red[threadIdx.x] += red[threadIdx.x + s]; __syncthreads(); }
  if (!threadIdx.x) lnR[row] = log(red[0]);
}

__global__ __launch_bounds__(256) void col_part(const float* __restrict__ S,
                                                const double* __restrict__ lnR,
                                                double* __restrict__ psum,
                                                double* __restrict__ pkey,
                                                int* __restrict__ pidx) {
  int bb = blockIdx.z;
  int c0 = blockIdx.x * 64;
  int rc = blockIdx.y;
  int col = c0 + (threadIdx.x & 63);
  int g = threadIdx.x >> 6;
  const float* Sp = S + (size_t)bb * 2304 * 2304;
  const double* lr = lnR + bb * 2304;
  double a = 0, best = -1e300; int bi = 1 << 30;
  int l0 = rc * 192;
  for (int t = g; t < 192; t += 4) {
    int l = l0 + t;
    double sv = (double)Sp[(size_t)l * 2304 + col];
    a += exp_small(sv);
    double k = 2.0 * sv - lr[l];
    if (k > best || (k == best && l < bi)) { best = k; bi = l; }
  }
  __shared__ double s_sum[256]; __shared__ double s_key[256]; __shared__ int s_idx[256];
  s_sum[threadIdx.x] = a; s_key[threadIdx.x] = best; s_idx[threadIdx.x] = bi;
  __syncthreads();
  if (g == 0) {
    double ts = a; double tk = best; int ti = bi;
    #pragma unroll
    for (int gg = 1; gg < 4; ++gg) {
      int o = threadIdx.x + gg * 64;
      ts += s_sum[o];
      if (s_key[o] > tk || (s_key[o] == tk && s_idx[o] < ti)) { tk = s_key[o]; ti = s_idx[o]; }
    }
    size_t off = ((size_t)bb * 12 + rc) * 2304 + col;
    psum[off] = ts; pkey[off] = tk; pidx[off] = ti;
  }
}

__global__ void col_reduce(const double* __restrict__ psum, const double* __restrict__ pkey,
                           const int* __restrict__ pidx, double* __restrict__ lnC,
                           int* __restrict__ CB) {
  int i = blockIdx.x * blockDim.x + threadIdx.x;
  if (i >= 4608) return;
  int bb = i / 2304, col = i - bb * 2304;
  double s = 0; double bk = -1e300; int bi = 1 << 30;
  for (int rc = 0; rc < 12; ++rc) {
    size_t off = ((size_t)bb * 12 + rc) * 2304 + col;
    s += psum[off];
    double k = pkey[off]; int ix = pidx[off];
    if (k > bk || (k == bk && ix < bi)) { bk = k; bi = ix; }
  }
  lnC[i] = log(s);
  CB[i] = bi;
}

__global__ __launch_bounds__(256) void row_argmax(const float* __restrict__ S,
                                                  const double* __restrict__ lnC,
                                                  int* __restrict__ J) {
  int row = blockIdx.x; int bb = row / 2304;
  const float* Sp = S + (size_t)row * 2304;
  const double* lc = lnC + bb * 2304;
  double best = -1e300; int bi = 1 << 30;
  for (int m = threadIdx.x; m < 2304; m += 256) {
    double k = 2.0 * (double)Sp[m] - lc[m];
    if (k > best || (k == best && m < bi)) { best = k; bi = m; }
  }
  __shared__ double bvs[256]; __shared__ int bis[256];
  bvs[threadIdx.x] = best; bis[threadIdx.x] = bi; __syncthreads();
  for (int s = 128; s > 0; s >>= 1) {
    if (threadIdx.x < (unsigned)s) {
      double ov = bvs[threadIdx.x + s]; int oi = bis[threadIdx.x + s];
      if (ov > bvs[threadIdx.x] || (ov == bvs[threadIdx.x] && oi < bis[threadIdx.x])) { bvs[threadIdx.x] = ov; bis[threadIdx.x] = oi; }
    }
    __syncthreads();
  }
  if (!threadIdx.x) J[row] = bis[0];
}

// ---------------- fine-feature path ----------------

__global__ __launch_bounds__(256) void transpose_fine(const float* __restrict__ src, short* __restrict__ dst) {
  __shared__ float t[64][65];
  int bb = blockIdx.z, p0 = blockIdx.x * 64, c0 = blockIdx.y * 64;
  for (int i = threadIdx.x; i < 1024; i += 256) {
    int cl = i >> 4, pl = (i & 15) * 4;
    float4 v = *(const float4*)&src[((size_t)(bb * 256 + c0 + cl)) * 36864 + p0 + pl];
    t[cl][pl] = v.x; t[cl][pl + 1] = v.y; t[cl][pl + 2] = v.z; t[cl][pl + 3] = v.w;
  }
  __syncthreads();
  for (int i = threadIdx.x; i < 1024; i += 256) {
    int pl = i >> 4, cg = (i & 15) * 4;
    unsigned w0 = (unsigned short)f2b(t[cg][pl]) | ((unsigned)(unsigned short)f2b(t[cg + 1][pl]) << 16);
    unsigned w1 = (unsigned short)f2b(t[cg + 2][pl]) | ((unsigned)(unsigned short)f2b(t[cg + 3][pl]) << 16);
    int2 v; v.x = (int)w0; v.y = (int)w1;
    *(int2*)&dst[((size_t)(bb * 36864 + p0 + pl)) * 256 + c0 + cg] = v;
  }
}

__global__ void cgather(const float* __restrict__ md0, const float* __restrict__ md1,
                        const int* __restrict__ J, short* __restrict__ cbuf) {
  int total = 9216 * 256;
  for (int i = blockIdx.x * blockDim.x + threadIdx.x; i < total; i += gridDim.x * blockDim.x) {
    int w = i >> 8, c = i & 255;
    const float* src;
    if (w < 4608) src = md0 + (size_t)w * 256;
    else {
      int n = w - 4608; int bb = n / 2304;
      src = md1 + (size_t)(bb * 2304 + J[n]) * 256;
    }
    cbuf[i] = f2b(src[c]);
  }
}

__global__ void build_tab(const int* __restrict__ J, const short* __restrict__ f0c,
                          const short* __restrict__ f1c, const short* __restrict__ zp,
                          unsigned long long* __restrict__ tab) {
  int total = 230400;
  for (int i = blockIdx.x * blockDim.x + threadIdx.x; i < total; i += gridDim.x * blockDim.x) {
    int w = i / 25, t = i - w * 25;
    int bb, cell; const short* fc;
    if (w < 4608) { bb = w / 2304; cell = w - bb * 2304; fc = f0c; }
    else { int n = w - 4608; bb = n / 2304; cell = J[n]; fc = f1c; }
    int cy = cell / 48, cx = cell - cy * 48;
    int y = cy * 4 - 2 + t / 5, x = cx * 4 - 2 + t % 5;
    const short* p = (y >= 0 && y < 192 && x >= 0 && x < 192)
                   ? fc + (size_t)((bb * 192 + y) * 192 + x) * 128 : zp;
    tab[i] = (unsigned long long)(uintptr_t)p;
  }
}

// ---------------- the bf16 MFMA GEMM workhorse (BK=64, 34KB LDS) ----------------

constexpr int AM_LIN = 0, AM_DUAL = 1, AM_TAB = 2, AM_CEN = 3;
constexpr int EP_BIAS = 0, EP_BF32 = 1, EP_RELU = 2, EP_LN = 3, EP_LNRES = 4, EP_MERGE = 5, EP_PART = 6, EP_F16 = 7;

template<int AMODE, int EPI>
__global__ __launch_bounds__(256)
void gemm_bf16(const short* __restrict__ A1, const short* __restrict__ A2,
               const unsigned long long* __restrict__ tab,
               const short* __restrict__ Wt, int M, int Kd, int kstr, int K1,
               const float* __restrict__ bias, int bstride,
               const float* __restrict__ lns, const float* __restrict__ lnb,
               const short* __restrict__ resid,
               const float* __restrict__ ccp, const float* __restrict__ pep,
               short* __restrict__ outb, float* __restrict__ outf, int ldc,
               long wstride, long ostride) {
  __shared__ __align__(16) short As[128 * 64];
  __shared__ __align__(16) short Bs[128 * 64];
  __shared__ float rsum[2][128], rsq[2][128];
  int tid = threadIdx.x, lane = tid & 63, wid = tid >> 6;
  int wr = wid >> 1, wc = wid & 1;
  int nwg = gridDim.x;
  int orig = blockIdx.x;
  int qd = nwg >> 3, rm = nwg & 7;
  int xcd = orig & 7, offx = orig >> 3;
  int bx = (xcd < rm ? xcd * (qd + 1) : rm * (qd + 1) + (xcd - rm) * qd) + offx;
  int rb = bx * 128;
  int by = blockIdx.y;
  int koff = blockIdx.z * Kd;
  const short* Wsel = Wt + (size_t)by * wstride;
  const float* bsel = bias ? bias + (size_t)by * bstride : nullptr;
  short* osel_b = outb ? outb + (size_t)by * ostride : nullptr;
  float* osel_f = outf ? outf + (size_t)by * ostride : nullptr;

  f32x4v acc[4][4];
  #pragma unroll
  for (int i = 0; i < 4; ++i)
    #pragma unroll
    for (int j = 0; j < 4; ++j) acc[i][j] = (f32x4v){0.f, 0.f, 0.f, 0.f};

  for (int k0 = 0; k0 < Kd; k0 += 64) {
    #pragma unroll
    for (int q = 0; q < 4; ++q) {
      int i = (wid * 4 + q) * 64 + lane;
      int r = i >> 3, pch = i & 7;
      int c = pch ^ (r & 7);
      const short* src;
      if (AMODE == AM_LIN) {
        src = A1 + (size_t)(rb + r) * kstr + koff + k0 + c * 8;
      } else if (AMODE == AM_DUAL) {
        if (k0 < K1) src = A1 + (size_t)(rb + r) * K1 + k0 + c * 8;
        else         src = A2 + (size_t)(rb + r) * (Kd - K1) + (k0 - K1) + c * 8;
      } else if (AMODE == AM_CEN) {
        int rg = rb + r;
        if (k0 < K1) src = A1 + (size_t)((rg / 25) * 25 + 12) * K1 + k0 + c * 8;
        else         src = A2 + (size_t)rg * (Kd - K1) + (k0 - K1) + c * 8;
      } else {
        src = (const short*)(uintptr_t)tab[rb + r] + k0 + c * 8;
      }
      gl_lds16(src, &As[(size_t)i * 8]);
    }
    #pragma unroll
    for (int q = 0; q < 4; ++q) {
      int i = (wid * 4 + q) * 64 + lane;
      int r = i >> 3, pch = i & 7;
      int c = pch ^ (r & 7);
      gl_lds16(Wsel + (size_t)r * kstr + koff + k0 + c * 8, &Bs[(size_t)i * 8]);
    }
    __syncthreads();
    #pragma unroll
    for (int kk = 0; kk < 2; ++kk) {
      bf16x8v af[4], bfr[4];
      #pragma unroll
      for (int mi = 0; mi < 4; ++mi) {
        int r = wr * 64 + mi * 16 + (lane & 15);
        int c = kk * 4 + (lane >> 4);
        int pch = c ^ (r & 7);
        af[mi] = *(const bf16x8v*)&As[r * 64 + pch * 8];
      }
      #pragma unroll
      for (int ni = 0; ni < 4; ++ni) {
        int r = wc * 64 + ni * 16 + (lane & 15);
        int c = kk * 4 + (lane >> 4);
        int pch = c ^ (r & 7);
        bfr[ni] = *(const bf16x8v*)&Bs[r * 64 + pch * 8];
      }
      #pragma unroll
      for (int mi = 0; mi < 4; ++mi)
        #pragma unroll
        for (int ni = 0; ni < 4; ++ni)
          acc[mi][ni] = __builtin_amdgcn_mfma_f32_16x16x32_bf16(af[mi], bfr[ni], acc[mi][ni], 0, 0, 0);
    }
    __syncthreads();
  }

  // ---- epilogue ----
  int colloc[4];
  #pragma unroll
  for (int ni = 0; ni < 4; ++ni) colloc[ni] = wc * 64 + ni * 16 + (lane & 15);
  float bv[4];
  #pragma unroll
  for (int ni = 0; ni < 4; ++ni)
    bv[ni] = (EPI == EP_MERGE || EPI == EP_PART) ? 0.f : (bsel ? bsel[colloc[ni]] : 0.f);

  #pragma unroll
  for (int mi = 0; mi < 4; ++mi)
    #pragma unroll
    for (int ni = 0; ni < 4; ++ni)
      #pragma unroll
      for (int q = 0; q < 4; ++q) {
        float v = acc[mi][ni][q] + bv[ni];
        if (EPI == EP_RELU) v = fmaxf(v, 0.f);
        acc[mi][ni][q] = v;
      }

  if (EPI == EP_LN || EPI == EP_LNRES) {
    #pragma unroll
    for (int mi = 0; mi < 4; ++mi)
      #pragma unroll
      for (int q = 0; q < 4; ++q) {
        float s = 0.f, ss = 0.f;
        #pragma unroll
        for (int ni = 0; ni < 4; ++ni) { float v = acc[mi][ni][q]; s += v; ss += v * v; }
        s += __shfl_xor(s, 1, 64); ss += __shfl_xor(ss, 1, 64);
        s += __shfl_xor(s, 2, 64); ss += __shfl_xor(ss, 2, 64);
        s += __shfl_xor(s, 4, 64); ss += __shfl_xor(ss, 4, 64);
        s += __shfl_xor(s, 8, 64); ss += __shfl_xor(ss, 8, 64);
        int rl = wr * 64 + mi * 16 + (lane >> 4) * 4 + q;
        if ((lane & 15) == 0) { rsum[wc][rl] = s; rsq[wc][rl] = ss; }
      }
    __syncthreads();
  }

  #pragma unroll
  for (int mi = 0; mi < 4; ++mi)
    #pragma unroll
    for (int q = 0; q < 4; ++q) {
      int rl = wr * 64 + mi * 16 + (lane >> 4) * 4 + q;
      long rg = rb + rl;
      float mean = 0.f, rstd = 0.f;
      if (EPI == EP_LN || EPI == EP_LNRES) {
        float s = rsum[0][rl] + rsum[1][rl];
        float ss = rsq[0][rl] + rsq[1][rl];
        mean = s * (1.f / 128.f);
        float var = ss * (1.f / 128.f) - mean * mean;
        rstd = 1.f / sqrtf(var + 1e-5f);
      }
      int wv_ = 0, tv_ = 0;
      if (EPI == EP_MERGE) { wv_ = (int)(rg / 25); tv_ = (int)(rg - (long)wv_ * 25); }
      #pragma unroll
      for (int ni = 0; ni < 4; ++ni) {
        int cg = colloc[ni];
        float v = acc[mi][ni][q];
        if (EPI == EP_MERGE) v += ccp[(size_t)wv_ * 128 + cg] + pep[tv_ * 128 + cg];
        if (EPI == EP_LN || EPI == EP_LNRES) {
          v = (v - mean) * rstd * lns[cg] + lnb[cg];
          if (EPI == EP_LNRES) v += b2f(resid[(size_t)rg * 128 + cg]);
        }
        if (EPI == EP_BF32) osel_f[(size_t)rg * ldc + cg] = v;
        else if (EPI == EP_PART) osel_f[((size_t)blockIdx.z * M + rg) * ldc + cg] = v;
        else if (EPI == EP_F16) osel_b[(size_t)rg * ldc + cg] = f2h(v);
        else osel_b[(size_t)rg * ldc + cg] = f2b(v);
      }
    }
}

__global__ void reduce_part(const float* __restrict__ part, const float* __restrict__ bias,
                            short* __restrict__ out) {
  int i = blockIdx.x * blockDim.x + threadIdx.x;
  if (i >= 4608 * 128) return;
  int c = i & 127;
  float s = bias[c];
  #pragma unroll
  for (int z = 0; z < 5; ++z) s += part[(size_t)z * 4608 * 128 + i];
  out[i] = f2b(s);
}

// ---------------- fused QKV v2: A staged once, FULL 128x128 B tile per weight ----------------

template<bool CROSS>
__global__ __launch_bounds__(256)
void qkv_fused(const short* __restrict__ xq, const short* __restrict__ xkv,
               const short* __restrict__ wqkv, short* __restrict__ out, long ostride) {
  __shared__ __align__(16) short As[128 * 128];   // 32 KB (full K=128)
  __shared__ __align__(16) short Bs[128 * 128];   // 32 KB (full K=128)
  int tid = threadIdx.x, lane = tid & 63, wid = tid >> 6;
  int wr = wid >> 1, wc = wid & 1;
  int nwg = gridDim.x;
  int orig = blockIdx.x;
  int qd = nwg >> 3, rm = nwg & 7;
  int xcd = orig & 7, offx = orig >> 3;
  int bx = (xcd < rm ? xcd * (qd + 1) : rm * (qd + 1) + (xcd - rm) * qd) + offx;
  int rb = bx * 128;

  auto stageA = [&](const short* src) {
    #pragma unroll
    for (int q = 0; q < 8; ++q) {
      int i = (wid * 8 + q) * 64 + lane;
      int r = i >> 4, pch = i & 15;
      int c = pch ^ (r & 15);
      gl_lds16(src + (size_t)(rb + r) * 128 + c * 8, &As[(size_t)i * 8]);
    }
  };
  auto stageB = [&](const short* src) {
    #pragma unroll
    for (int q = 0; q < 8; ++q) {
      int i = (wid * 8 + q) * 64 + lane;
      int r = i >> 4, pch = i & 15;
      int c = pch ^ (r & 15);
      gl_lds16(src + (size_t)r * 128 + c * 8, &Bs[(size_t)i * 8]);
    }
  };
  stageA(xq);

  #pragma unroll
  for (int w = 0; w < 3; ++w) {
    if (CROSS && w == 1) stageA(xkv);
    f32x4v acc[4][4];
    #pragma unroll
    for (int i = 0; i < 4; ++i)
      #pragma unroll
      for (int j = 0; j < 4; ++j) acc[i][j] = (f32x4v){0.f, 0.f, 0.f, 0.f};
    stageB(wqkv + (size_t)w * 16384);
    __syncthreads();
    #pragma unroll
    for (int kk = 0; kk < 4; ++kk) {
      bf16x8v af[4], bfr[4];
      #pragma unroll
      for (int mi = 0; mi < 4; ++mi) {
        int r = wr * 64 + mi * 16 + (lane & 15);
        int cg = kk * 4 + (lane >> 4);
        int pch = cg ^ (r & 15);
        af[mi] = *(const bf16x8v*)&As[r * 128 + pch * 8];
      }
      #pragma unroll
      for (int ni = 0; ni < 4; ++ni) {
        int r = wc * 64 + ni * 16 + (lane & 15);
        int cg = kk * 4 + (lane >> 4);
        int pch = cg ^ (r & 15);
        bfr[ni] = *(const bf16x8v*)&Bs[r * 128 + pch * 8];
      }
      #pragma unroll
      for (int mi = 0; mi < 4; ++mi)
        #pragma unroll
        for (int ni = 0; ni < 4; ++ni)
          acc[mi][ni] = __builtin_amdgcn_mfma_f32_16x16x32_bf16(af[mi], bfr[ni], acc[mi][ni], 0, 0, 0);
    }
    // C-write (registers only) before the trailing sync
    short* ow = out + (size_t)w * ostride;
    #pragma unroll
    for (int mi = 0; mi < 4; ++mi)
      #pragma unroll
      for (int q = 0; q < 4; ++q) {
        int rl = wr * 64 + mi * 16 + (lane >> 4) * 4 + q;
        long rg = rb + rl;
        #pragma unroll
        for (int ni = 0; ni < 4; ++ni) {
          int cg = wc * 64 + ni * 16 + (lane & 15);
          ow[(size_t)rg * 128 + cg] = f2h(acc[mi][ni][q]);
        }
      }
    __syncthreads();   // retire As/Bs reads before next w's restage
  }
}

// ---------------- fully fused block tail v3: deferred-h (x staged ONCE) ----------------
// msg = LN(attnout@wm); h = relu([x,msg]@m1+b1); out = LN(h@m2+b2)+x.
// All four m1 fat phases run first (acc1a/acc1b both live); then h half0 -> As region,
// h half1 -> Ms region (both dead); two m2 fat phases read them. Saves one 16KB stageA
// + 2 barriers vs v2; acc1/acc2 MFMA K-order identical -> bit-identical numerics.
// LDS: 16(AsHs) + 32(Bs) + 16(Ms) = 64 KB.

__global__ __launch_bounds__(256)
void mlp2_fused(const short* __restrict__ x, const short* __restrict__ attnout,
                const short* __restrict__ wmT,
                const short* __restrict__ m1wT, const short* __restrict__ m2wT,
                const float* __restrict__ n1s, const float* __restrict__ n1b,
                const float* __restrict__ b1, const float* __restrict__ b2,
                const float* __restrict__ lns, const float* __restrict__ lnb,
                short* __restrict__ out) {
  __shared__ __align__(16) short AsHs[64 * 128];  // 16 KB: attnout | x | h half0 | LN scratch
  __shared__ __align__(16) short Bs[128 * 128];   // 32 KB: full-K weight tile
  __shared__ __align__(16) short Ms[64 * 128];    // 16 KB: msg | h half1
  short* As = AsHs;
  float* rsum = (float*)AsHs;          // [2][64], live only when staging region dead
  float* rsq  = (float*)AsHs + 128;
  int tid = threadIdx.x, lane = tid & 63, wid = tid >> 6;
  int wr = wid >> 1, wc = wid & 1;
  int nwg = gridDim.x;
  int orig = blockIdx.x;
  int qd = nwg >> 3, rm = nwg & 7;
  int xcd = orig & 7, offx = orig >> 3;
  int bx = (xcd < rm ? xcd * (qd + 1) : rm * (qd + 1) + (xcd - rm) * qd) + offx;
  int rb = bx * 64;

  int colloc[4];
  #pragma unroll
  for (int ni = 0; ni < 4; ++ni) colloc[ni] = wc * 64 + ni * 16 + (lane & 15);

  // stage 64x128 A tile (full K), 1024 slots, 4/thread
  auto stageA = [&](const short* src) {
    #pragma unroll
    for (int q = 0; q < 4; ++q) {
      int i = (wid * 4 + q) * 64 + lane;
      int r = i >> 4, pch = i & 15;
      int c = pch ^ (r & 15);
      gl_lds16(src + (size_t)(rb + r) * 128 + c * 8, &As[(size_t)i * 8]);
    }
  };
  // stage 128x128 B tile, 2048 slots, 8/thread
  auto stageB = [&](const short* src, int kstr) {
    #pragma unroll
    for (int q = 0; q < 8; ++q) {
      int i = (wid * 8 + q) * 64 + lane;
      int r = i >> 4, pch = i & 15;
      int c = pch ^ (r & 15);
      gl_lds16(src + (size_t)r * kstr + c * 8, &Bs[(size_t)i * 8]);
    }
  };
  // 32-MFMA region: C[64x128] += A64x128 @ B128x128^T (A from any 64x128 swizzled tile)
  auto mfmaAB = [&](const short* Atile, f32x4v (*acc)[4]) {
    #pragma unroll
    for (int kk = 0; kk < 4; ++kk) {
      bf16x8v af[2], bfr[4];
      #pragma unroll
      for (int mi = 0; mi < 2; ++mi) {
        int r = wr * 32 + mi * 16 + (lane & 15);
        int c = kk * 4 + (lane >> 4);
        int pch = c ^ (r & 15);
        af[mi] = *(const bf16x8v*)&Atile[r * 128 + pch * 8];
      }
      #pragma unroll
      for (int ni = 0; ni < 4; ++ni) {
        int r = wc * 64 + ni * 16 + (lane & 15);
        int c = kk * 4 + (lane >> 4);
        int pch = c ^ (r & 15);
        bfr[ni] = *(const bf16x8v*)&Bs[r * 128 + pch * 8];
      }
      #pragma unroll
      for (int mi = 0; mi < 2; ++mi)
        #pragma unroll
        for (int ni = 0; ni < 4; ++ni)
          acc[mi][ni] = __builtin_amdgcn_mfma_f32_16x16x32_bf16(af[mi], bfr[ni], acc[mi][ni], 0, 0, 0);
    }
  };
  // write relu(acc + bias) as a 64x128 A-style swizzled tile into dst
  auto writeH = [&](short* dst, f32x4v (*acc)[4], const float* bptr) {
    #pragma unroll
    for (int mi = 0; mi < 2; ++mi)
      #pragma unroll
      for (int q = 0; q < 4; ++q) {
        int rl = wr * 32 + mi * 16 + (lane >> 4) * 4 + q;
        #pragma unroll
        for (int ni = 0; ni < 4; ++ni) {
          int cg = wc * 64 + ni * 16 + (lane & 15);
          float v = fmaxf(acc[mi][ni][q] + bptr[cg], 0.f);
          int c = cg >> 3, pch = c ^ (rl & 15);
          dst[rl * 128 + pch * 8 + (cg & 7)] = f2b(v);
        }
      }
  };

  // ---- phase 0: msg = LN(attnout @ wm) -> Ms ----
  {
    f32x4v acc0[2][4];
    #pragma unroll
    for (int i = 0; i < 2; ++i)
      #pragma unroll
      for (int j = 0; j < 4; ++j) acc0[i][j] = (f32x4v){0.f, 0.f, 0.f, 0.f};
    stageA(attnout);
    stageB(wmT, 128);
    __syncthreads();
    mfmaAB(As, acc0);
    __syncthreads();
    // LN stats (rsum aliases dead attnout staging)
    #pragma unroll
    for (int mi = 0; mi < 2; ++mi)
      #pragma unroll
      for (int q = 0; q < 4; ++q) {
        float s = 0.f, ss = 0.f;
        #pragma unroll
        for (int ni = 0; ni < 4; ++ni) { float v = acc0[mi][ni][q]; s += v; ss += v * v; }
        s += __shfl_xor(s, 1, 64); ss += __shfl_xor(ss, 1, 64);
        s += __shfl_xor(s, 2, 64); ss += __shfl_xor(ss, 2, 64);
        s += __shfl_xor(s, 4, 64); ss += __shfl_xor(ss, 4, 64);
        s += __shfl_xor(s, 8, 64); ss += __shfl_xor(ss, 8, 64);
        int rl = wr * 32 + mi * 16 + (lane >> 4) * 4 + q;
        if ((lane & 15) == 0) { rsum[wc * 64 + rl] = s; rsq[wc * 64 + rl] = ss; }
      }
    __syncthreads();
    #pragma unroll
    for (int mi = 0; mi < 2; ++mi)
      #pragma unroll
      for (int q = 0; q < 4; ++q) {
        int rl = wr * 32 + mi * 16 + (lane >> 4) * 4 + q;
        float s = rsum[rl] + rsum[64 + rl];
        float ss = rsq[rl] + rsq[64 + rl];
        float mean = s * (1.f / 128.f);
        float var = ss * (1.f / 128.f) - mean * mean;
        float rstd = 1.f / sqrtf(var + 1e-5f);
        #pragma unroll
        for (int ni = 0; ni < 4; ++ni) {
          int cg = colloc[ni];
          float v = (acc0[mi][ni][q] - mean) * rstd * n1s[cg] + n1b[cg];
          int c = cg >> 3, pch = c ^ (rl & 15);
          Ms[rl * 128 + pch * 8 + (cg & 7)] = f2b(v);
        }
      }
    __syncthreads();                 // Ms visible; rsum reads retired -> As reusable
  }

  // ---- phase 1: m1 (all four fat phases; x staged once) ----
  f32x4v acc1a[2][4], acc1b[2][4], acc2[2][4];
  #pragma unroll
  for (int i = 0; i < 2; ++i)
    #pragma unroll
    for (int j = 0; j < 4; ++j) {
      acc1a[i][j] = (f32x4v){0.f, 0.f, 0.f, 0.f};
      acc1b[i][j] = (f32x4v){0.f, 0.f, 0.f, 0.f};
      acc2[i][j]  = (f32x4v){0.f, 0.f, 0.f, 0.f};
    }

  stageA(x);
  stageB(m1wT, 256);                          // n-half0, K 0..127
  __syncthreads();
  mfmaAB(As, acc1a);
  __syncthreads();
  stageB(m1wT + 128, 256);                    // n-half0, K 128..255
  __syncthreads();
  mfmaAB(Ms, acc1a);
  __syncthreads();
  stageB(m1wT + (size_t)128 * 256, 256);      // n-half1, K 0..127
  __syncthreads();
  mfmaAB(As, acc1b);                          // last As(x) read
  __syncthreads();
  stageB(m1wT + (size_t)128 * 256 + 128, 256);// n-half1, K 128..255
  __syncthreads();
  mfmaAB(Ms, acc1b);                          // last Ms(msg) read
  __syncthreads();                            // retire all As/Ms/Bs reads

  // ---- h writes (As <- h cols 0..127, Ms <- h cols 128..255) + m2 K-half0 stage ----
  writeH(As, acc1a, b1);
  writeH(Ms, acc1b, b1 + 128);
  stageB(m2wT, 256);                          // m2 K 0..127
  __syncthreads();
  mfmaAB(As, acc2);                           // h0 @ m2 K0..127
  __syncthreads();
  stageB(m2wT + 128, 256);                    // m2 K 128..255
  __syncthreads();
  mfmaAB(Ms, acc2);                           // h1 @ m2 K128..255
  __syncthreads();                            // retire reads -> rsum alias safe

  // ---- epilogue: m2 bias + LN(n2) + residual(x) (rsum aliases dead As region) ----
  #pragma unroll
  for (int mi = 0; mi < 2; ++mi)
    #pragma unroll
    for (int ni = 0; ni < 4; ++ni)
      #pragma unroll
      for (int q = 0; q < 4; ++q)
        acc2[mi][ni][q] += b2[colloc[ni]];

  #pragma unroll
  for (int mi = 0; mi < 2; ++mi)
    #pragma unroll
    for (int q = 0; q < 4; ++q) {
      float s = 0.f, ss = 0.f;
      #pragma unroll
      for (int ni = 0; ni < 4; ++ni) { float v = acc2[mi][ni][q]; s += v; ss += v * v; }
      s += __shfl_xor(s, 1, 64); ss += __shfl_xor(ss, 1, 64);
      s += __shfl_xor(s, 2, 64); ss += __shfl_xor(ss, 2, 64);
      s += __shfl_xor(s, 4, 64); ss += __shfl_xor(ss, 4, 64);
      s += __shfl_xor(s, 8, 64); ss += __shfl_xor(ss, 8, 64);
      int rl = wr * 32 + mi * 16 + (lane >> 4) * 4 + q;
      if ((lane & 15) == 0) { rsum[wc * 64 + rl] = s; rsq[wc * 64 + rl] = ss; }
    }
  __syncthreads();

  #pragma unroll
  for (int mi = 0; mi < 2; ++mi)
    #pragma unroll
    for (int q = 0; q < 4; ++q) {
      int rl = wr * 32 + mi * 16 + (lane >> 4) * 4 + q;
      long rg = rb + rl;
      float s = rsum[rl] + rsum[64 + rl];
      float ss = rsq[rl] + rsq[64 + rl];
      float mean = s * (1.f / 128.f);
      float var = ss * (1.f / 128.f) - mean * mean;
      float rstd = 1.f / sqrtf(var + 1e-5f);
      #pragma unroll
      for (int ni = 0; ni < 4; ++ni) {
        int cg = colloc[ni];
        float v = (acc2[mi][ni][q] - mean) * rstd * lns[cg] + lnb[cg];
        v += b2f(x[(size_t)rg * 128 + cg]);
        out[(size_t)rg * 128 + cg] = f2b(v);
      }
    }
}

// ---------------- windowed attention v3: raw f16 LDS, fdot2 QK, pk_fma PV ----------------

__global__ __launch_bounds__(256) void attn_win(const short* __restrict__ Q,
                                                const short* __restrict__ K,
                                                const short* __restrict__ V,
                                                short* __restrict__ Mo) {
  int w = blockIdx.x;
  const short* Qg = Q + (size_t)w * 3200;
  const short* Kg = K + (size_t)w * 3200;
  const short* Vg = V + (size_t)w * 3200;
  __shared__ short Qs[25 * 136 + 8], Ks[25 * 136 + 8], Vs[25 * 136 + 8];
  int tid = threadIdx.x;
  for (int s = tid; s < 400; s += 256) {
    int r = s >> 4, ch = s & 15;
    *(int4*)&Qs[r * 136 + ch * 8] = ((const int4*)Qg)[s];
    *(int4*)&Ks[r * 136 + ch * 8] = ((const int4*)Kg)[s];
    *(int4*)&Vs[r * 136 + ch * 8] = ((const int4*)Vg)[s];
  }
  __syncthreads();

  int wid = tid >> 6, lane = tid & 63;
  int half = lane >> 5, li = lane & 31;
  int h = wid * 2 + half;
  if (li < 25) {
    int i = li;
    h2 qr[8];
    #pragma unroll
    for (int t = 0; t < 8; ++t) qr[t] = *(const h2*)&Qs[i * 136 + h * 16 + t * 2];
    float p[25];
    float mx = -1e30f;
    #pragma unroll
    for (int jx = 0; jx < 25; ++jx) {
      const short* kr = &Ks[jx * 136 + h * 16];
      float s = 0.f;
      #pragma unroll
      for (int t = 0; t < 8; ++t)
        s = __builtin_amdgcn_fdot2(qr[t], *(const h2*)&kr[t * 2], s, false);
      s *= 0.25f;
      p[jx] = s;
      mx = fmaxf(mx, s);
    }
    float sum = 0.f;
    #pragma unroll
    for (int jx = 0; jx < 25; ++jx) { float e = expf(p[jx] - mx); p[jx] = e; sum += e; }
    float inv = 1.f / sum;
    h2 o2[8];
    #pragma unroll
    for (int t = 0; t < 8; ++t) { o2[t][0] = (_Float16)0.f; o2[t][1] = (_Float16)0.f; }
    #pragma unroll
    for (int jx = 0; jx < 25; ++jx) {
      _Float16 ph = (_Float16)(p[jx] * inv);
      h2 pv; pv[0] = ph; pv[1] = ph;
      const short* vr = &Vs[jx * 136 + h * 16];
      #pragma unroll
      for (int t = 0; t < 8; ++t) o2[t] += pv * (*(const h2*)&vr[t * 2]);
    }
    int* outp = (int*)(Mo + (size_t)w * 3200 + i * 128 + h * 16);
    #pragma unroll
    for (int t = 0; t < 8; ++t) {
      unsigned lo = (unsigned short)f2b((float)o2[t][0]);
      unsigned hi = (unsigned short)f2b((float)o2[t][1]);
      outp[t] = (int)(lo | (hi << 16));
    }
  }
}

// ---------------- final regression + mask ----------------

__global__ void final_reg(const short* __restrict__ fv, const float* __restrict__ regw,
                          const float* __restrict__ regb, const int* __restrict__ J,
                          const int* __restrict__ CB, float* __restrict__ out) {
  int n = blockIdx.x * blockDim.x + threadIdx.x;
  if (n >= 4608) return;
  const short* f = fv + (size_t)n * 128;
  float c0 = regb[0], c1 = regb[1];
  for (int d = 0; d < 128; ++d) { float v = b2f(f[d]); c0 += v * regw[d * 2]; c1 += v * regw[d * 2 + 1]; }
  int jv = J[n]; int bb = n / 2304;
  int msk = (CB[bb * 2304 + jv] == (n - bb * 2304)) ? 1 : 0;
  float bx = (float)((jv % 48) * 8), by = (float)((jv / 48) * 8);
  out[n * 2] = msk ? (bx + c0) : 0.f;
  out[n * 2 + 1] = msk ? (by + c1) : 0.f;
}

// ---------------- host ----------------

extern "C" void kernel_launch(void* const* d_in, const int* in_sizes, int n_in,
                              void* d_out, int out_size, void* d_ws, size_t ws_size,
                              hipStream_t stream) {
  const float* md0 = (const float*)d_in[0];
  const float* md1 = (const float*)d_in[1];
  const float* fine0 = (const float*)d_in[2];
  const float* fine1 = (const float*)d_in[3];
  const float* conv_w = (const float*)d_in[4];
  const float* conv_b = (const float*)d_in[5];
  const float* proj_w = (const float*)d_in[6];
  const float* proj_b = (const float*)d_in[7];
  const float* merge_w = (const float*)d_in[8];
  const float* merge_b = (const float*)d_in[9];
  const float* reg1_w = (const float*)d_in[10];
  const float* reg1_b = (const float*)d_in[11];
  const float* reg2_w = (const float*)d_in[12];
  const float* reg2_b = (const float*)d_in[13];
  const float* reg_w = (const float*)d_in[14];
  const float* reg_b = (const float*)d_in[15];
  const float* wq_f = (const float*)d_in[16];
  const float* wk_f = (const float*)d_in[17];
  const float* wv_f = (const float*)d_in[18];
  const float* wm_f = (const float*)d_in[19];
  const float* m1w = (const float*)d_in[20];
  const float* m1b = (const float*)d_in[21];
  const float* m2w = (const float*)d_in[22];
  const float* m2b = (const float*)d_in[23];
  const float* n1s = (const float*)d_in[24];
  const float* n1b = (const float*)d_in[25];
  const float* n2s = (const float*)d_in[26];
  const float* n2b = (const float*)d_in[27];

  char* ws = (char*)d_ws;
  const size_t SZX = (size_t)230400 * 128 * 2;
  const size_t TAILSZ = 20 * 1024 * 1024;
  int CHM = 57600;
  if (SZX + 3ull * 230400 * 256 + TAILSZ <= ws_size)      CHM = 230400;
  else if (SZX + 3ull * 115200 * 256 + TAILSZ <= ws_size) CHM = 115200;
  const size_t CHR = (size_t)CHM * 256;

  short* X  = (short*)(ws);
  char*  Rb = ws + SZX;
  short* R0 = (short*)(Rb);
  short* R1 = (short*)(Rb + CHR);
  short* R2 = (short*)(Rb + 2 * CHR);
  float* S    = (float*)Rb;
  short* F0C  = (short*)Rb;
  short* F1C  = (short*)(Rb + (size_t)73728 * 128 * 2);
  short* FT   = X;
  short* FB   = (short*)Rb;
  float* PART = (float*)(Rb + 2 * CHR);

  char* p = ws + SZX + 3 * CHR;
  double* lnR = (double*)p; p += 4608 * 8;
  double* lnC = (double*)p; p += 4608 * 8;
  int* J = (int*)p; p += 4608 * 4;
  int* CBst = (int*)p; p += 4608 * 4;
  double* PSUM = (double*)p; p += (size_t)2 * 12 * 2304 * 8;
  double* PKEY = (double*)p; p += (size_t)2 * 12 * 2304 * 8;
  int* PIDX = (int*)p; p += (size_t)2 * 12 * 2304 * 4;
  short* CBUF = (short*)p; p += (size_t)9216 * 256 * 2;
  short* CEN = (short*)p; p += (size_t)9216 * 128 * 2;
  float* CC = (float*)p; p += (size_t)9216 * 128 * 4;
  unsigned long long* TAB = (unsigned long long*)p; p += (size_t)230400 * 8;
  float* PE = (float*)p; p += 3200 * 4;
  short* ZP = (short*)p; p += 256;
  short* convT = (short*)p; p += 128 * 256 * 2;
  short* projT = (short*)p; p += 128 * 256 * 2;
  short* mergeAT = (short*)p; p += 128 * 128 * 2;
  short* mergeBT = (short*)p; p += 128 * 128 * 2;
  short* reg1T = (short*)p; p += 128 * 256 * 2;
  short* reg2T = (short*)p; p += (size_t)128 * 3200 * 2;
  short* wqkvT = (short*)p; p += (size_t)4 * 3 * 128 * 128 * 2;
  short* wmT = (short*)p; p += 4 * 128 * 128 * 2;
  short* m1T = (short*)p; p += 4 * 256 * 256 * 2;
  short* m2T = (short*)p; p += (size_t)4 * 128 * 256 * 2;
  short* FV = (short*)p; p += (size_t)4608 * 128 * 2;

  const int TQ = 115200;

  prep_all<<<512, 256, 0, stream>>>(conv_w, proj_w, merge_w, reg1_w, reg2_w,
                                    wq_f, wk_f, wv_f, wm_f, m1w, m2w,
                                    convT, projT, mergeAT, mergeBT, reg1T, reg2T,
                                    wqkvT, wmT, m1T, m2T, PE, ZP);

  // matching
  sim_gemm<<<dim3(24, 24, 2), 256, 0, stream>>>(md0, md1, S);
  row_lse<<<4608, 256, 0, stream>>>(S, lnR);
  col_part<<<dim3(36, 12, 2), 256, 0, stream>>>(S, lnR, PSUM, PKEY, PIDX);
  col_reduce<<<18, 256, 0, stream>>>(PSUM, PKEY, PIDX, lnC, CBst);
  row_argmax<<<4608, 256, 0, stream>>>(S, lnC, J);

  auto gemm = [&](auto amode, auto epi, const short* A1, const short* A2,
                  const unsigned long long* tab, const short* Wt, int M, int Kd, int kstr, int K1,
                  const float* bias, int bstride, const float* lns, const float* lnb,
                  const short* resid, const float* cc, const float* pe,
                  short* outb, float* outf, int ldc, int NB, int NZ, long wstride, long ostride) {
    constexpr int AM = decltype(amode)::value, EP = decltype(epi)::value;
    gemm_bf16<AM, EP><<<dim3(M / 128, NB, NZ), 256, 0, stream>>>(
        A1, A2, tab, Wt, M, Kd, kstr, K1, bias, bstride, lns, lnb, resid, cc, pe,
        outb, outf, ldc, wstride, ostride);
  };
  using I0 = std::integral_constant<int, 0>; using I1 = std::integral_constant<int, 1>;
  using I2 = std::integral_constant<int, 2>; using I3 = std::integral_constant<int, 3>;
  using E0 = std::integral_constant<int, 0>; using E1 = std::integral_constant<int, 1>;
  using E5 = std::integral_constant<int, 5>; using E6 = std::integral_constant<int, 6>;

  // fine conv
  transpose_fine<<<dim3(576, 4, 2), 256, 0, stream>>>(fine0, FT);
  gemm(I0{}, E0{}, FT, nullptr, nullptr, convT, 73728, 256, 256, 0, conv_b, 0, nullptr, nullptr, nullptr, nullptr, nullptr, F0C, nullptr, 128, 1, 1, 0, 0);
  transpose_fine<<<dim3(576, 4, 2), 256, 0, stream>>>(fine1, FT);
  gemm(I0{}, E0{}, FT, nullptr, nullptr, convT, 73728, 256, 256, 0, conv_b, 0, nullptr, nullptr, nullptr, nullptr, nullptr, F1C, nullptr, 128, 1, 1, 0, 0);

  // center path + merge
  cgather<<<4608, 256, 0, stream>>>(md0, md1, J, CBUF);
  gemm(I0{}, E0{}, CBUF, nullptr, nullptr, projT, 9216, 256, 256, 0, proj_b, 0, nullptr, nullptr, nullptr, nullptr, nullptr, CEN, nullptr, 128, 1, 1, 0, 0);
  gemm(I0{}, E1{}, CEN, nullptr, nullptr, mergeBT, 9216, 128, 128, 0, merge_b, 0, nullptr, nullptr, nullptr, nullptr, nullptr, nullptr, CC, 128, 1, 1, 0, 0);
  build_tab<<<900, 256, 0, stream>>>(J, F0C, F1C, ZP, TAB);
  gemm(I2{}, E5{}, nullptr, nullptr, TAB, mergeAT, 230400, 128, 128, 0, nullptr, 0, nullptr, nullptr, nullptr, CC, PE, X, nullptr, 128, 1, 1, 0, 0);

  // transformer
  auto pass = [&](int i, const short* xq, const short* xkv, short* xout, int Mtotal, bool cross) {
    const short* wqkv = wqkvT + (size_t)i * 3 * 16384;
    const short* wm = wmT + i * 16384;
    const short* m1 = m1T + i * 65536;
    const short* m2 = m2T + i * 32768;
    for (int off = 0; off < Mtotal; off += CHM) {
      int Mc = (Mtotal - off < CHM) ? (Mtotal - off) : CHM;
      const short* xqc = xq + (size_t)off * 128;
      const short* xkvc = xkv + (size_t)off * 128;
      if (cross)
        qkv_fused<true><<<Mc / 128, 256, 0, stream>>>(xqc, xkvc, wqkv, R0, (long)CHM * 128);
      else
        qkv_fused<false><<<Mc / 128, 256, 0, stream>>>(xqc, xkvc, wqkv, R0, (long)CHM * 128);
      attn_win<<<Mc / 25, 256, 0, stream>>>(R0, R1, R2, R0);
      mlp2_fused<<<Mc / 64, 256, 0, stream>>>(xqc, R0, wm, m1, m2,
                                              n1s + i * 128, n1b + i * 128,
                                              m1b + i * 256, m2b + i * 128,
                                              n2s + i * 128, n2b + i * 128,
                                              xout + (size_t)off * 128);
    }
  };
  short* X1 = X + (size_t)TQ * 128;
  for (int i = 0; i < 4; ++i) {
    if ((i & 1) == 0) {
      pass(i, X, X, X, 230400, false);
    } else {
      pass(i, X, X1, X, TQ, true);
      pass(i, X1, X, X1, TQ, true);
    }
  }

  // regression head
  gemm(I3{}, E0{}, X, X1, nullptr, reg1T, TQ, 256, 256, 128, reg1_b, 0, nullptr, nullptr, nullptr, nullptr, nullptr, FB, nullptr, 128, 1, 1, 0, 0);
  gemm(I0{}, E6{}, FB, nullptr, nullptr, reg2T, 4608, 640, 3200, 0, nullptr, 0, nullptr, nullptr, nullptr, nullptr, nullptr, nullptr, PART, 128, 1, 5, 0, 0);
  reduce_part<<<2304, 256, 0, stream>>>(PART, reg2_b, FV);
  final_reg<<<18, 256, 0, stream>>>(FV, reg_w, reg_b, J, CBst, (float*)d_out);
}